// Round 9
// baseline (311.449 us; speedup 1.0000x reference)
//
#include <hip/hip_runtime.h>

#define BB 16
#define NO 512
#define NM 32
#define DOC 128
#define C8 1024
#define NH 64
#define KD 16

// ---------------- ws layout (float offsets), ~41 MiB total ----------------
#define OFF_X12   0          // [16*512,1024]  x1/x2 of ext-attn (in-place)
#define OFF_UO    0          // [8192,128] (alias: x12 dead by then)
#define OFF_LOG   1048576    // [16,16384] (alias, after Uo)
#define OFF_A1P   2000000    // [16384] bf16 (8192 floats) A1 pre-converted (alias, dead x12)
#define OFF_HOPES 8388608    // [8192,128] ext-attn output
#define OFF_HOPEG 9437184    // [8192,128] GAT h_ope
#define OFF_HMAC  10485760   // [512,128]  GAT h_mac (pre)
#define OFF_HMACS 10551296   // [512,128]  GAT output
#define OFF_AO    10616832   // [8192]
#define OFF_AM    10625024   // [512]
#define OFF_PO    10625536   // [16,128]
#define OFF_PM    10627584   // [16,128]
#define OFF_UM    10629632   // [512,128]  folded U_m + U_p + Ab0
#define OFF_FLAG  10695168   // int flag (mask dtype probe)

using f32x4  = __attribute__((ext_vector_type(4))) float;
using s16x4  = __attribute__((ext_vector_type(4))) short;
using bf16x8 = __attribute__((ext_vector_type(8))) short;   // 8 bf16 (4 VGPRs)

__device__ __forceinline__ float fast_tanh(float x) {
  x = fminf(15.0f, fmaxf(-15.0f, x));
  float e = __expf(2.0f * x);
  return 1.0f - 2.0f * __builtin_amdgcn_rcpf(e + 1.0f);
}

__device__ __forceinline__ short f2bf(float f) {          // RNE f32->bf16
  unsigned u = __builtin_bit_cast(unsigned, f);
  u += 0x7FFFu + ((u >> 16) & 1u);
  return (short)(u >> 16);
}

__device__ __forceinline__ bf16x8 pack8(f32x4 u0, f32x4 u1) {
  bf16x8 r;
  #pragma unroll
  for (int e = 0; e < 4; ++e) { r[e] = f2bf(u0[e]); r[4 + e] = f2bf(u1[e]); }
  return r;
}

// ---------------- mask dtype probe ----------------
__global__ void probe_mask_kernel(const unsigned int* __restrict__ mask,
                                  int* __restrict__ flag) {
  __shared__ int s[4];
  int bad = 0;
  for (int i = threadIdx.x; i < 4096; i += 256) {
    unsigned int v = mask[i];
    if (!(v == 0u || v == 1u || v == 0x3f800000u)) bad = 1;
  }
  unsigned long long any = __ballot(bad);
  int lane = threadIdx.x & 63, w = threadIdx.x >> 6;
  if (lane == 0) s[w] = (any != 0ull) ? 1 : 0;
  __syncthreads();
  if (threadIdx.x == 0) flag[0] = s[0] | s[1] | s[2] | s[3];
}

// ---------------- A1 f32 -> bf16, B-fragment layout: A1p[(k>>3)*128+col][e=k&7] ----------------
__global__ void convert_a1_kernel(const float* __restrict__ A1, short* __restrict__ A1p) {
  int tid = blockIdx.x * 256 + threadIdx.x;     // 64 blocks x 256 = 16384
  int col = tid >> 7, k = tid & 127;
  A1p[((k >> 3) * 128 + col) * 8 + (k & 7)] = f2bf(A1[tid]);
}

// ---------------- per-wave no-LDS bf16 MFMA GEMM ----------------
// C[m,n] = sum_k X[m,k]*W[n,k] (+bias[n]).  Per-wave tile (MT*16) x 64.
// Fragment layouts verified r6/r7. Register double-buffer k-pipeline.
template<int MT>
__device__ __forceinline__ void loadk(const float* xb, const float* wb,
                                      long sx, long sw, int k0,
                                      f32x4 (&xa)[MT][2], f32x4 (&wa)[4][2]) {
  #pragma unroll
  for (int mi = 0; mi < MT; ++mi) {
    xa[mi][0] = *(const f32x4*)(xb + mi * sx + k0);
    xa[mi][1] = *(const f32x4*)(xb + mi * sx + k0 + 4);
  }
  #pragma unroll
  for (int ni = 0; ni < 4; ++ni) {
    wa[ni][0] = *(const f32x4*)(wb + ni * sw + k0);
    wa[ni][1] = *(const f32x4*)(wb + ni * sw + k0 + 4);
  }
}

template<int MT>
__device__ __forceinline__ void consume(f32x4 (&xa)[MT][2], f32x4 (&wa)[4][2],
                                        f32x4 (&acc)[MT][4]) {
  bf16x8 bfr[4];
  #pragma unroll
  for (int ni = 0; ni < 4; ++ni) bfr[ni] = pack8(wa[ni][0], wa[ni][1]);
  #pragma unroll
  for (int mi = 0; mi < MT; ++mi) {
    bf16x8 af = pack8(xa[mi][0], xa[mi][1]);
    #pragma unroll
    for (int ni = 0; ni < 4; ++ni)
      acc[mi][ni] = __builtin_amdgcn_mfma_f32_16x16x32_bf16(af, bfr[ni], acc[mi][ni], 0, 0, 0);
  }
}

template<int MT>
__global__ __launch_bounds__(256) void gemm_wave(
    const float* __restrict__ X, const float* __restrict__ W,
    const float* __restrict__ bias, float* __restrict__ C,
    int N, int Kdim, int ldx, int ldw) {
  const int tid = threadIdx.x;
  const int lane = tid & 63, w = tid >> 6;
  const int rowl = lane & 15, kg = lane >> 4;
  const int n0 = blockIdx.x * 64;
  const int m0 = (blockIdx.y * 4 + w) * (MT * 16);
  const float* xb = X + (long)(m0 + rowl) * ldx + kg * 8;
  const float* wb = W + (long)(n0 + rowl) * ldw + kg * 8;
  const long sx = (long)16 * ldx, sw = (long)16 * ldw;
  f32x4 acc[MT][4] = {};
  f32x4 A0[MT][2], B0[4][2], A1[MT][2], B1[4][2];
  loadk<MT>(xb, wb, sx, sw, 0, A0, B0);
  for (int k = 0; k < Kdim; k += 64) {
    loadk<MT>(xb, wb, sx, sw, k + 32, A1, B1);
    consume<MT>(A0, B0, acc);
    if (k + 64 < Kdim) loadk<MT>(xb, wb, sx, sw, k + 64, A0, B0);
    consume<MT>(A1, B1, acc);
  }
  #pragma unroll
  for (int mi = 0; mi < MT; ++mi) {
    #pragma unroll
    for (int ni = 0; ni < 4; ++ni) {
      int col = n0 + ni * 16 + rowl;
      float bv = bias ? bias[col] : 0.0f;
      int rb = m0 + mi * 16 + kg * 4;
      #pragma unroll
      for (int r = 0; r < 4; ++r)
        C[(long)(rb + r) * N + col] = acc[mi][ni][r] + bv;
    }
  }
}

// ---------------- generic f32 GEMM (kept for the small hmac GEMM) ----------------
__global__ __launch_bounds__(256) void gemm_xt(
    const float* __restrict__ X, const float* __restrict__ W,
    const float* __restrict__ bias, float* __restrict__ C,
    int M, int N, int Kdim, int ldx, int ldw) {
  __shared__ float Xs[64][33];
  __shared__ float Ws[64][33];
  const int tid = threadIdx.x;
  const int tx = tid & 15, ty = tid >> 4;
  const int m0 = blockIdx.y * 64, n0 = blockIdx.x * 64;
  float acc[4][4] = {};
  for (int k0 = 0; k0 < Kdim; k0 += 32) {
    #pragma unroll
    for (int l = 0; l < 8; ++l) {
      int f = l * 256 + tid;
      int r = f >> 5, c = f & 31;
      Xs[r][c] = X[(m0 + r) * ldx + k0 + c];
      Ws[r][c] = W[(n0 + r) * ldw + k0 + c];
    }
    __syncthreads();
    #pragma unroll 8
    for (int kk = 0; kk < 32; ++kk) {
      float xr[4], wr[4];
      #pragma unroll
      for (int i = 0; i < 4; ++i) xr[i] = Xs[ty * 4 + i][kk];
      #pragma unroll
      for (int j = 0; j < 4; ++j) wr[j] = Ws[tx * 4 + j][kk];
      #pragma unroll
      for (int i = 0; i < 4; ++i)
        #pragma unroll
        for (int j = 0; j < 4; ++j)
          acc[i][j] = fmaf(xr[i], wr[j], acc[i][j]);
    }
    __syncthreads();
  }
  #pragma unroll
  for (int i = 0; i < 4; ++i) {
    int m = m0 + ty * 4 + i;
    #pragma unroll
    for (int j = 0; j < 4; ++j) {
      int n = n0 + tx * 4 + j;
      C[m * N + n] = acc[i][j] + (bias ? bias[n] : 0.0f);
    }
  }
}

// ---------------- external attention middle: per (b,h) slice, in place on x12 ----------------
__global__ __launch_bounds__(256) void attn_kernel(
    float* __restrict__ x12,
    const float* __restrict__ W0, const float* __restrict__ b0,
    const float* __restrict__ W1, const float* __restrict__ b1) {
  __shared__ float S[NO][KD + 1];
  __shared__ float red[16][17];
  __shared__ float colmax[16], colsum[16];
  __shared__ float rs[NO];
  const int b = blockIdx.y, h = blockIdx.x;
  const int tid = threadIdx.x;
  const int tk = tid & 15, tg = tid >> 4;
  float* base = x12 + (b * NO) * C8 + h * KD;
  #pragma unroll
  for (int l = 0; l < 32; ++l) {
    int f = l * 256 + tid;
    int n = f >> 4, k = f & 15;
    S[n][k] = base[n * C8 + k];
  }
  __syncthreads();
  float w0r[16];
  #pragma unroll
  for (int k = 0; k < 16; ++k) w0r[k] = W0[tk * 16 + k];
  const float b0v = b0[tk];
  float Areg[32];
  for (int i = 0; i < 32; ++i) {
    int n = tg + 16 * i;
    float acc = b0v;
    #pragma unroll
    for (int k = 0; k < 16; ++k) acc = fmaf(S[n][k], w0r[k], acc);
    Areg[i] = acc;
  }
  __syncthreads();
  for (int i = 0; i < 32; ++i) { int n = tg + 16 * i; S[n][tk] = Areg[i]; }
  __syncthreads();
  float mx = -1e30f;
  for (int i = 0; i < 32; ++i) mx = fmaxf(mx, Areg[i]);
  red[tg][tk] = mx;
  __syncthreads();
  if (tg == 0) {
    float mm = red[0][tk];
    for (int g = 1; g < 16; ++g) mm = fmaxf(mm, red[g][tk]);
    colmax[tk] = mm;
  }
  __syncthreads();
  const float cm = colmax[tk];
  float s = 0.f;
  for (int i = 0; i < 32; ++i) { float e = __expf(Areg[i] - cm); Areg[i] = e; s += e; }
  __syncthreads();
  red[tg][tk] = s;
  __syncthreads();
  if (tg == 0) {
    float ss = 0.f;
    for (int g = 0; g < 16; ++g) ss += red[g][tk];
    colsum[tk] = ss;
  }
  __syncthreads();
  const float inv = 1.0f / colsum[tk];
  for (int i = 0; i < 32; ++i) { int n = tg + 16 * i; S[n][tk] = Areg[i] * inv; }
  __syncthreads();
  #pragma unroll
  for (int rr = 0; rr < 2; ++rr) {
    int n = tid * 2 + rr;
    float t = 0.f;
    #pragma unroll
    for (int k = 0; k < 16; ++k) t += S[n][k];
    rs[n] = t;
  }
  __syncthreads();
  float w1r[16];
  #pragma unroll
  for (int k = 0; k < 16; ++k) w1r[k] = W1[tk * 16 + k];
  const float b1v = b1[tk];
  for (int i = 0; i < 32; ++i) {
    int n = tg + 16 * i;
    float rinv = 1.0f / (1e-10f + rs[n]);
    float acc = b1v;
    #pragma unroll
    for (int k = 0; k < 16; ++k) acc = fmaf(S[n][k] * rinv, w1r[k], acc);
    base[n * C8 + tk] = acc;
  }
}

// ---------------- row dot with alpha (a_o / a_m) ----------------
__global__ void rowdot(const float* __restrict__ X, const float* __restrict__ alpha,
                       float* __restrict__ out, int R) {
  int wid = (blockIdx.x * blockDim.x + threadIdx.x) >> 6;
  int lane = threadIdx.x & 63;
  if (wid >= R) return;
  const float* row = X + wid * 128;
  float v = fmaf(row[lane], alpha[lane], row[lane + 64] * alpha[lane + 64]);
  #pragma unroll
  for (int off = 32; off; off >>= 1) v += __shfl_down(v, off);
  if (lane == 0) out[wid] = v;
}

// ---------------- GAT per (b,m) ----------------
__global__ __launch_bounds__(128) void gat_kernel(
    const float* __restrict__ adj, const float* __restrict__ ao,
    const float* __restrict__ am, const float* __restrict__ hopeG,
    const float* __restrict__ hmac, float* __restrict__ hmacs) {
  __shared__ float al[NO];
  __shared__ float sc[2];
  const int b = blockIdx.y, m = blockIdx.x;
  const int tid = threadIdx.x;
  const int lane = tid & 63, w = tid >> 6;
  const float amv = am[b * NM + m];
  float ev[4], adjv[4];
  float mx = -1e30f;
  #pragma unroll
  for (int i = 0; i < 4; ++i) {
    int o = tid + i * 128;
    float a = adj[(b * NO + o) * NM + m];
    adjv[i] = a;
    float e = ao[b * NO + o] + amv;
    e = (e >= 0.f) ? e : 0.2f * e;
    ev[i] = e;
    if (a == 1.0f) mx = fmaxf(mx, e);
  }
  #pragma unroll
  for (int off = 32; off; off >>= 1) mx = fmaxf(mx, __shfl_down(mx, off));
  if (lane == 0) sc[w] = mx;
  __syncthreads();
  mx = fmaxf(sc[0], sc[1]);
  float s = 0.f;
  float pv[4];
  #pragma unroll
  for (int i = 0; i < 4; ++i) {
    float p = (adjv[i] == 1.0f) ? __expf(ev[i] - mx) : 0.f;
    pv[i] = p; s += p;
  }
  #pragma unroll
  for (int off = 32; off; off >>= 1) s += __shfl_down(s, off);
  __syncthreads();
  if (lane == 0) sc[w] = s;
  __syncthreads();
  s = sc[0] + sc[1];
  const float sinv = (s > 0.f) ? 1.0f / s : 0.f;
  #pragma unroll
  for (int i = 0; i < 4; ++i) al[tid + i * 128] = pv[i] * sinv;
  __syncthreads();
  float acc = 0.f;
  #pragma unroll 4
  for (int o = 0; o < NO; ++o) acc = fmaf(al[o], hopeG[(b * NO + o) * DOC + tid], acc);
  hmacs[(b * NM + m) * DOC + tid] = acc + hmac[(b * NM + m) * DOC + tid];
}

// ---------------- mean-pool over rows (512 threads: 4-way row split) ----------------
__global__ __launch_bounds__(512) void pool_kernel(const float* __restrict__ X,
                                                   float* __restrict__ out,
                                                   int R, float inv) {
  __shared__ float part[4][128];
  const int b = blockIdx.x;
  const int d = threadIdx.x & 127, g = threadIdx.x >> 7;
  const int per = R >> 2;
  float acc = 0.f;
  for (int r = g * per; r < (g + 1) * per; ++r) acc += X[(b * R + r) * 128 + d];
  part[g][d] = acc;
  __syncthreads();
  if (g == 0)
    out[b * 128 + d] = (part[0][d] + part[1][d] + part[2][d] + part[3][d]) * inv;
}

// ---------------- folded U_m ----------------
__global__ __launch_bounds__(128) void um_kernel(
    const float* __restrict__ hmacs, const float* __restrict__ po,
    const float* __restrict__ pm, const float* __restrict__ A0,
    const float* __restrict__ Ab0, float* __restrict__ um) {
  __shared__ float v[384];
  const int b = blockIdx.y, m = blockIdx.x;
  const int j = threadIdx.x;
  v[j] = hmacs[(b * NM + m) * 128 + j];
  v[128 + j] = po[b * 128 + j];
  v[256 + j] = pm[b * 128 + j];
  __syncthreads();
  const float* a = A0 + j * 512 + 128;
  float acc = Ab0[j];
  for (int k = 0; k < 384; ++k) acc = fmaf(a[k], v[k], acc);
  um[(b * NM + m) * 128 + j] = acc;
}

// ---------------- actor v2: no LDS, no barriers; A1 from pre-converted bf16 ----------------
// Per wave 16 rows. a-frag: row=lane&15, k=(lane>>4)*8+e (verified r6).
// B-frag from A1p[(kk*4+kg)*128+col][e] (L2-resident 32 KB).
// D: col=lane&15, row=(lane>>4)*4+reg.
__global__ __launch_bounds__(256) void actor_mfma2_kernel(
    const float* __restrict__ Uo, const float* __restrict__ Um,
    const short* __restrict__ A1p, const float* __restrict__ Ab1,
    const float* __restrict__ A2, const float* __restrict__ Ab2,
    float* __restrict__ logits) {
  const int tid = threadIdx.x;
  const int rbase = blockIdx.x * 64;       // flat row = b*16384 + m*512 + o
  const int b = rbase >> 14;
  const int m = (rbase & 16383) >> 9;
  const int lane = tid & 63, w = tid >> 6;
  const int rowl = lane & 15, kg = lane >> 4;
  const float* uo = Uo + (long)(rbase + w * 16 + rowl) * 128;
  const float* umb = Um + (b * NM + m) * 128;
  bf16x8 af[4];
  #pragma unroll
  for (int kk = 0; kk < 4; ++kk) {
    int kb = kk * 32 + kg * 8;
    f32x4 u0 = *(const f32x4*)(uo + kb);
    f32x4 u1 = *(const f32x4*)(uo + kb + 4);
    f32x4 m0 = *(const f32x4*)(umb + kb);
    f32x4 m1 = *(const f32x4*)(umb + kb + 4);
    #pragma unroll
    for (int e = 0; e < 4; ++e) af[kk][e]     = f2bf(fast_tanh(u0[e] + m0[e]));
    #pragma unroll
    for (int e = 0; e < 4; ++e) af[kk][4 + e] = f2bf(fast_tanh(u1[e] + m1[e]));
  }
  float partrow[4] = {0.f, 0.f, 0.f, 0.f};
  #pragma unroll
  for (int ct = 0; ct < 8; ++ct) {
    const int col = ct * 16 + rowl;
    f32x4 acc = {0.f, 0.f, 0.f, 0.f};
    #pragma unroll
    for (int kk = 0; kk < 4; ++kk) {
      bf16x8 bf = *(const bf16x8*)(A1p + ((kk * 4 + kg) * 128 + col) * 8);
      acc = __builtin_amdgcn_mfma_f32_16x16x32_bf16(af[kk], bf, acc, 0, 0, 0);
    }
    const float ab = Ab1[col], a2c = A2[col];
    #pragma unroll
    for (int r = 0; r < 4; ++r) {
      float z2 = fast_tanh(acc[r] + ab);
      partrow[r] = fmaf(a2c, z2, partrow[r]);
    }
  }
  const float ab2 = Ab2[0];
  #pragma unroll
  for (int r = 0; r < 4; ++r) {
    float v = partrow[r];
    #pragma unroll
    for (int off = 1; off < 16; off <<= 1) v += __shfl_xor(v, off);
    if (rowl == 0) logits[rbase + w * 16 + kg * 4 + r] = v + ab2;
  }
}

// ---------------- masked log-softmax + gather + entropy (1024 threads) ----------------
__global__ __launch_bounds__(1024) void final_kernel(
    const float* __restrict__ logits, const void* __restrict__ maskp,
    const int* __restrict__ aidx, const int* __restrict__ flag,
    float* __restrict__ out) {
  __shared__ float sc[16], sc2[16];
  const int b = blockIdx.x;
  const int tid = threadIdx.x;
  const int lane = tid & 63, w = tid >> 6;
  const bool word_mode = (flag[0] == 0);
  const unsigned int* mw = (const unsigned int*)maskp;
  const unsigned char* mb = (const unsigned char*)maskp;
  const float* lg = logits + b * (NM * NO);
  float mx = -1e30f;
  for (int s = 0; s < 16; ++s) {
    int i = s * 1024 + tid;
    int o = i & 511, mm = i >> 9;
    int mofs = (b * NO + o) * NM + mm;
    bool msk = word_mode ? (mw[mofs] != 0u) : (mb[mofs] != 0);
    if (msk) mx = fmaxf(mx, lg[i]);
  }
  #pragma unroll
  for (int off = 32; off; off >>= 1) mx = fmaxf(mx, __shfl_down(mx, off));
  if (lane == 0) sc[w] = mx;
  __syncthreads();
  if (tid == 0) {
    float m2 = sc[0];
    for (int k = 1; k < 16; ++k) m2 = fmaxf(m2, sc[k]);
    sc[0] = m2;
  }
  __syncthreads();
  mx = sc[0];
  __syncthreads();
  float S = 0.f, T = 0.f;
  for (int s = 0; s < 16; ++s) {
    int i = s * 1024 + tid;
    int o = i & 511, mm = i >> 9;
    int mofs = (b * NO + o) * NM + mm;
    bool msk = word_mode ? (mw[mofs] != 0u) : (mb[mofs] != 0);
    if (msk) {
      float d = lg[i] - mx;
      float e = __expf(d);
      S += e;
      T = fmaf(e, d, T);
    }
  }
  #pragma unroll
  for (int off = 32; off; off >>= 1) { S += __shfl_down(S, off); T += __shfl_down(T, off); }
  if (lane == 0) { sc[w] = S; sc2[w] = T; }
  __syncthreads();
  if (tid == 0) {
    float St = 0.f, Tt = 0.f;
    for (int k = 0; k < 16; ++k) { St += sc[k]; Tt += sc2[k]; }
    float lS = logf(St);
    out[b] = lg[aidx[b]] - mx - lS;          // action_logprobs
    out[32 + b] = lS - Tt / St;              // dist_entropys
  }
}

// ---------------- critic MLP (per batch) ----------------
__global__ __launch_bounds__(128) void critic_kernel(
    const float* __restrict__ po, const float* __restrict__ pm,
    const float* __restrict__ C0, const float* __restrict__ Cb0,
    const float* __restrict__ C1, const float* __restrict__ Cb1,
    const float* __restrict__ C2, const float* __restrict__ Cb2,
    float* __restrict__ out) {
  __shared__ float v[256];
  __shared__ float z[128];
  __shared__ float sc[2];
  const int b = blockIdx.x;
  const int j = threadIdx.x;
  v[j] = po[b * 128 + j];
  v[128 + j] = pm[b * 128 + j];
  __syncthreads();
  float acc = Cb0[j];
  for (int k = 0; k < 256; ++k) acc = fmaf(C0[j * 256 + k], v[k], acc);
  z[j] = fast_tanh(acc);
  __syncthreads();
  acc = Cb1[j];
  for (int k = 0; k < 128; ++k) acc = fmaf(C1[j * 128 + k], z[k], acc);
  float z2 = fast_tanh(acc);
  float p = C2[j] * z2;
  #pragma unroll
  for (int off = 32; off; off >>= 1) p += __shfl_down(p, off);
  const int lane = j & 63, w = j >> 6;
  if (lane == 0) sc[w] = p;
  __syncthreads();
  if (j == 0) out[16 + b] = sc[0] + sc[1] + Cb2[0];   // state_values
}

extern "C" void kernel_launch(void* const* d_in, const int* in_sizes, int n_in,
                              void* d_out, int out_size, void* d_ws, size_t ws_size,
                              hipStream_t stream) {
  (void)in_sizes; (void)n_in; (void)out_size; (void)ws_size;
  const float* adj  = (const float*)d_in[0];
  const float* nop  = (const float*)d_in[1];
  const float* nmac = (const float*)d_in[2];
  const void*  maskp = d_in[3];
  const int*   aidx = (const int*)d_in[4];
  const float* Wtr  = (const float*)d_in[5];
  const float* btr  = (const float*)d_in[6];
  const float* W0   = (const float*)d_in[7];
  const float* b0   = (const float*)d_in[8];
  const float* W1   = (const float*)d_in[9];
  const float* b1   = (const float*)d_in[10];
  const float* Wp   = (const float*)d_in[11];
  const float* bp   = (const float*)d_in[12];
  const float* Wo   = (const float*)d_in[13];
  const float* Wm   = (const float*)d_in[14];
  const float* alo  = (const float*)d_in[15];
  const float* alm  = (const float*)d_in[16];
  const float* A0   = (const float*)d_in[17];
  const float* Ab0  = (const float*)d_in[18];
  const float* A1   = (const float*)d_in[19];
  const float* Ab1  = (const float*)d_in[20];
  const float* A2   = (const float*)d_in[21];
  const float* Ab2  = (const float*)d_in[22];
  const float* C0   = (const float*)d_in[23];
  const float* Cb0  = (const float*)d_in[24];
  const float* C1   = (const float*)d_in[25];
  const float* Cb1  = (const float*)d_in[26];
  const float* C2   = (const float*)d_in[27];
  const float* Cb2  = (const float*)d_in[28];

  float* ws     = (float*)d_ws;        // needs ~41 MiB
  float* x12    = ws + OFF_X12;
  float* hopes  = ws + OFF_HOPES;
  float* hopeG  = ws + OFF_HOPEG;
  float* hmac   = ws + OFF_HMAC;
  float* hmacs  = ws + OFF_HMACS;
  float* ao     = ws + OFF_AO;
  float* am     = ws + OFF_AM;
  float* po     = ws + OFF_PO;
  float* pm     = ws + OFF_PM;
  float* Uo     = ws + OFF_UO;
  float* Um     = ws + OFF_UM;
  float* logits = ws + OFF_LOG;
  short* A1p    = (short*)(ws + OFF_A1P);
  int*   flag   = (int*)(ws + OFF_FLAG);
  float* outp   = (float*)d_out;

  probe_mask_kernel<<<1, 256, 0, stream>>>((const unsigned int*)maskp, flag);

  // external attention
  gemm_wave<2><<<dim3(16, 64), 256, 0, stream>>>(nop, Wtr, btr, x12, 1024, 128, 128, 128);
  attn_kernel<<<dim3(NH, BB), 256, 0, stream>>>(x12, W0, b0, W1, b1);
  gemm_wave<1><<<dim3(2, 128), 256, 0, stream>>>(x12, Wp, bp, hopes, 128, 1024, 1024, 1024);

  // A1 -> bf16 (after x12's last read; A1p lives in dead x12 region)
  convert_a1_kernel<<<64, 256, 0, stream>>>(A1, A1p);

  // GAT
  gemm_wave<1><<<dim3(2, 128), 256, 0, stream>>>(nop, Wo, nullptr, hopeG, 128, 128, 128, 128);
  gemm_xt<<<dim3(2, 8), 256, 0, stream>>>(nmac, Wm, nullptr, hmac, 512, 128, 64, 64, 64);
  rowdot<<<2048, 256, 0, stream>>>(hopeG, alo, ao, 8192);
  rowdot<<<128, 256, 0, stream>>>(hmac, alm, am, 512);
  gat_kernel<<<dim3(NM, BB), 128, 0, stream>>>(adj, ao, am, hopeG, hmac, hmacs);

  // pooling
  pool_kernel<<<16, 512, 0, stream>>>(hopes, po, 512, 1.0f / 512.0f);
  pool_kernel<<<16, 512, 0, stream>>>(hmacs, pm, 32, 1.0f / 32.0f);

  // actor (Uo aliases x12's region — x12 is dead after the proj GEMM above)
  gemm_wave<1><<<dim3(2, 128), 256, 0, stream>>>(hopes, A0, nullptr, Uo, 128, 128, 128, 512);
  um_kernel<<<dim3(NM, BB), 128, 0, stream>>>(hmacs, po, pm, A0, Ab0, Um);
  actor_mfma2_kernel<<<4096, 256, 0, stream>>>(Uo, Um, A1p, Ab1, A2, Ab2, logits);
  final_kernel<<<16, 1024, 0, stream>>>(logits, maskp, aidx, flag, outp);

  // critic
  critic_kernel<<<16, 128, 0, stream>>>(po, pm, C0, Cb0, C1, Cb1, C2, Cb2, outp);
}

// Round 11
// 309.434 us; speedup vs baseline: 1.0065x; 1.0065x over previous
//
#include <hip/hip_runtime.h>

#define BB 16
#define NO 512
#define NM 32
#define DOC 128
#define C8 1024
#define NH 64
#define KD 16

// ---------------- ws layout (float offsets), ~41 MiB total ----------------
#define OFF_X12   0          // [16*512,1024]  x1/x2 of ext-attn (in-place)
#define OFF_UO    0          // [8192,128] (alias: x12 dead by then)
#define OFF_LOG   1048576    // [16,16384] (alias, after Uo)
#define OFF_A1P   2000000    // [16384] bf16 (8192 floats) A1 pre-converted (alias, dead x12)
#define OFF_HOPES 8388608    // [8192,128] ext-attn output
#define OFF_HOPEG 9437184    // [8192,128] GAT h_ope
#define OFF_HMAC  10485760   // [512,128]  GAT h_mac (pre)
#define OFF_HMACS 10551296   // [512,128]  GAT output
#define OFF_AO    10616832   // [8192]
#define OFF_AM    10625024   // [512]
#define OFF_PO    10625536   // [16,128]
#define OFF_PM    10627584   // [16,128]
#define OFF_UM    10629632   // [512,128]  folded U_m + U_p + Ab0
#define OFF_FLAG  10695168   // int flag (mask dtype probe)

using f32x4  = __attribute__((ext_vector_type(4))) float;
using s16x4  = __attribute__((ext_vector_type(4))) short;
using bf16x8 = __attribute__((ext_vector_type(8))) short;   // 8 bf16 (4 VGPRs)

__device__ __forceinline__ float fast_tanh(float x) {
  x = fminf(15.0f, fmaxf(-15.0f, x));
  float e = __expf(2.0f * x);
  return 1.0f - 2.0f * __builtin_amdgcn_rcpf(e + 1.0f);
}

__device__ __forceinline__ short f2bf(float f) {          // RNE f32->bf16
  unsigned u = __builtin_bit_cast(unsigned, f);
  u += 0x7FFFu + ((u >> 16) & 1u);
  return (short)(u >> 16);
}

__device__ __forceinline__ bf16x8 pack8(f32x4 u0, f32x4 u1) {
  bf16x8 r;
  #pragma unroll
  for (int e = 0; e < 4; ++e) { r[e] = f2bf(u0[e]); r[4 + e] = f2bf(u1[e]); }
  return r;
}

// ---------------- mask dtype probe ----------------
__global__ void probe_mask_kernel(const unsigned int* __restrict__ mask,
                                  int* __restrict__ flag) {
  __shared__ int s[4];
  int bad = 0;
  for (int i = threadIdx.x; i < 4096; i += 256) {
    unsigned int v = mask[i];
    if (!(v == 0u || v == 1u || v == 0x3f800000u)) bad = 1;
  }
  unsigned long long any = __ballot(bad);
  int lane = threadIdx.x & 63, w = threadIdx.x >> 6;
  if (lane == 0) s[w] = (any != 0ull) ? 1 : 0;
  __syncthreads();
  if (threadIdx.x == 0) flag[0] = s[0] | s[1] | s[2] | s[3];
}

// ---------------- A1 f32 -> bf16, B-fragment layout: A1p[(k>>3)*128+col][e=k&7] ----------------
__global__ void convert_a1_kernel(const float* __restrict__ A1, short* __restrict__ A1p) {
  int tid = blockIdx.x * 256 + threadIdx.x;     // 64 blocks x 256 = 16384
  int col = tid >> 7, k = tid & 127;
  A1p[((k >> 3) * 128 + col) * 8 + (k & 7)] = f2bf(A1[tid]);
}

// ---------------- per-wave no-LDS bf16 MFMA GEMM ----------------
// C[m,n] = sum_k X[m,k]*W[n,k] (+bias[n]).  Per-wave tile (MT*16) x 64.
// Fragment layouts verified r6/r7. Register double-buffer k-pipeline.
template<int MT>
__device__ __forceinline__ void loadk(const float* xb, const float* wb,
                                      long sx, long sw, int k0,
                                      f32x4 (&xa)[MT][2], f32x4 (&wa)[4][2]) {
  #pragma unroll
  for (int mi = 0; mi < MT; ++mi) {
    xa[mi][0] = *(const f32x4*)(xb + mi * sx + k0);
    xa[mi][1] = *(const f32x4*)(xb + mi * sx + k0 + 4);
  }
  #pragma unroll
  for (int ni = 0; ni < 4; ++ni) {
    wa[ni][0] = *(const f32x4*)(wb + ni * sw + k0);
    wa[ni][1] = *(const f32x4*)(wb + ni * sw + k0 + 4);
  }
}

template<int MT>
__device__ __forceinline__ void consume(f32x4 (&xa)[MT][2], f32x4 (&wa)[4][2],
                                        f32x4 (&acc)[MT][4]) {
  bf16x8 bfr[4];
  #pragma unroll
  for (int ni = 0; ni < 4; ++ni) bfr[ni] = pack8(wa[ni][0], wa[ni][1]);
  #pragma unroll
  for (int mi = 0; mi < MT; ++mi) {
    bf16x8 af = pack8(xa[mi][0], xa[mi][1]);
    #pragma unroll
    for (int ni = 0; ni < 4; ++ni)
      acc[mi][ni] = __builtin_amdgcn_mfma_f32_16x16x32_bf16(af, bfr[ni], acc[mi][ni], 0, 0, 0);
  }
}

template<int MT>
__global__ __launch_bounds__(256) void gemm_wave(
    const float* __restrict__ X, const float* __restrict__ W,
    const float* __restrict__ bias, float* __restrict__ C,
    int N, int Kdim, int ldx, int ldw) {
  const int tid = threadIdx.x;
  const int lane = tid & 63, w = tid >> 6;
  const int rowl = lane & 15, kg = lane >> 4;
  const int n0 = blockIdx.x * 64;
  const int m0 = (blockIdx.y * 4 + w) * (MT * 16);
  const float* xb = X + (long)(m0 + rowl) * ldx + kg * 8;
  const float* wb = W + (long)(n0 + rowl) * ldw + kg * 8;
  const long sx = (long)16 * ldx, sw = (long)16 * ldw;
  f32x4 acc[MT][4] = {};
  f32x4 A0[MT][2], B0[4][2], A1[MT][2], B1[4][2];
  loadk<MT>(xb, wb, sx, sw, 0, A0, B0);
  for (int k = 0; k < Kdim; k += 64) {
    loadk<MT>(xb, wb, sx, sw, k + 32, A1, B1);
    consume<MT>(A0, B0, acc);
    if (k + 64 < Kdim) loadk<MT>(xb, wb, sx, sw, k + 64, A0, B0);
    consume<MT>(A1, B1, acc);
  }
  #pragma unroll
  for (int mi = 0; mi < MT; ++mi) {
    #pragma unroll
    for (int ni = 0; ni < 4; ++ni) {
      int col = n0 + ni * 16 + rowl;
      float bv = bias ? bias[col] : 0.0f;
      int rb = m0 + mi * 16 + kg * 4;
      #pragma unroll
      for (int r = 0; r < 4; ++r)
        C[(long)(rb + r) * N + col] = acc[mi][ni][r] + bv;
    }
  }
}

// ---------------- generic f32 GEMM (kept for the small hmac GEMM) ----------------
__global__ __launch_bounds__(256) void gemm_xt(
    const float* __restrict__ X, const float* __restrict__ W,
    const float* __restrict__ bias, float* __restrict__ C,
    int M, int N, int Kdim, int ldx, int ldw) {
  __shared__ float Xs[64][33];
  __shared__ float Ws[64][33];
  const int tid = threadIdx.x;
  const int tx = tid & 15, ty = tid >> 4;
  const int m0 = blockIdx.y * 64, n0 = blockIdx.x * 64;
  float acc[4][4] = {};
  for (int k0 = 0; k0 < Kdim; k0 += 32) {
    #pragma unroll
    for (int l = 0; l < 8; ++l) {
      int f = l * 256 + tid;
      int r = f >> 5, c = f & 31;
      Xs[r][c] = X[(m0 + r) * ldx + k0 + c];
      Ws[r][c] = W[(n0 + r) * ldw + k0 + c];
    }
    __syncthreads();
    #pragma unroll 8
    for (int kk = 0; kk < 32; ++kk) {
      float xr[4], wr[4];
      #pragma unroll
      for (int i = 0; i < 4; ++i) xr[i] = Xs[ty * 4 + i][kk];
      #pragma unroll
      for (int j = 0; j < 4; ++j) wr[j] = Ws[tx * 4 + j][kk];
      #pragma unroll
      for (int i = 0; i < 4; ++i)
        #pragma unroll
        for (int j = 0; j < 4; ++j)
          acc[i][j] = fmaf(xr[i], wr[j], acc[i][j]);
    }
    __syncthreads();
  }
  #pragma unroll
  for (int i = 0; i < 4; ++i) {
    int m = m0 + ty * 4 + i;
    #pragma unroll
    for (int j = 0; j < 4; ++j) {
      int n = n0 + tx * 4 + j;
      C[m * N + n] = acc[i][j] + (bias ? bias[n] : 0.0f);
    }
  }
}

// ---------------- external attention middle: per (b,h) slice, in place on x12 ----------------
__global__ __launch_bounds__(256) void attn_kernel(
    float* __restrict__ x12,
    const float* __restrict__ W0, const float* __restrict__ b0,
    const float* __restrict__ W1, const float* __restrict__ b1) {
  __shared__ float S[NO][KD + 1];
  __shared__ float red[16][17];
  __shared__ float colmax[16], colsum[16];
  __shared__ float rs[NO];
  const int b = blockIdx.y, h = blockIdx.x;
  const int tid = threadIdx.x;
  const int tk = tid & 15, tg = tid >> 4;
  float* base = x12 + (b * NO) * C8 + h * KD;
  #pragma unroll
  for (int l = 0; l < 32; ++l) {
    int f = l * 256 + tid;
    int n = f >> 4, k = f & 15;
    S[n][k] = base[n * C8 + k];
  }
  __syncthreads();
  float w0r[16];
  #pragma unroll
  for (int k = 0; k < 16; ++k) w0r[k] = W0[tk * 16 + k];
  const float b0v = b0[tk];
  float Areg[32];
  for (int i = 0; i < 32; ++i) {
    int n = tg + 16 * i;
    float acc = b0v;
    #pragma unroll
    for (int k = 0; k < 16; ++k) acc = fmaf(S[n][k], w0r[k], acc);
    Areg[i] = acc;
  }
  __syncthreads();
  for (int i = 0; i < 32; ++i) { int n = tg + 16 * i; S[n][tk] = Areg[i]; }
  __syncthreads();
  float mx = -1e30f;
  for (int i = 0; i < 32; ++i) mx = fmaxf(mx, Areg[i]);
  red[tg][tk] = mx;
  __syncthreads();
  if (tg == 0) {
    float mm = red[0][tk];
    for (int g = 1; g < 16; ++g) mm = fmaxf(mm, red[g][tk]);
    colmax[tk] = mm;
  }
  __syncthreads();
  const float cm = colmax[tk];
  float s = 0.f;
  for (int i = 0; i < 32; ++i) { float e = __expf(Areg[i] - cm); Areg[i] = e; s += e; }
  __syncthreads();
  red[tg][tk] = s;
  __syncthreads();
  if (tg == 0) {
    float ss = 0.f;
    for (int g = 0; g < 16; ++g) ss += red[g][tk];
    colsum[tk] = ss;
  }
  __syncthreads();
  const float inv = 1.0f / colsum[tk];
  for (int i = 0; i < 32; ++i) { int n = tg + 16 * i; S[n][tk] = Areg[i] * inv; }
  __syncthreads();
  #pragma unroll
  for (int rr = 0; rr < 2; ++rr) {
    int n = tid * 2 + rr;
    float t = 0.f;
    #pragma unroll
    for (int k = 0; k < 16; ++k) t += S[n][k];
    rs[n] = t;
  }
  __syncthreads();
  float w1r[16];
  #pragma unroll
  for (int k = 0; k < 16; ++k) w1r[k] = W1[tk * 16 + k];
  const float b1v = b1[tk];
  for (int i = 0; i < 32; ++i) {
    int n = tg + 16 * i;
    float rinv = 1.0f / (1e-10f + rs[n]);
    float acc = b1v;
    #pragma unroll
    for (int k = 0; k < 16; ++k) acc = fmaf(S[n][k] * rinv, w1r[k], acc);
    base[n * C8 + tk] = acc;
  }
}

// ---------------- row dot with alpha (a_o / a_m) ----------------
__global__ void rowdot(const float* __restrict__ X, const float* __restrict__ alpha,
                       float* __restrict__ out, int R) {
  int wid = (blockIdx.x * blockDim.x + threadIdx.x) >> 6;
  int lane = threadIdx.x & 63;
  if (wid >= R) return;
  const float* row = X + wid * 128;
  float v = fmaf(row[lane], alpha[lane], row[lane + 64] * alpha[lane + 64]);
  #pragma unroll
  for (int off = 32; off; off >>= 1) v += __shfl_down(v, off);
  if (lane == 0) out[wid] = v;
}

// ---------------- GAT per (b,m) ----------------
__global__ __launch_bounds__(128) void gat_kernel(
    const float* __restrict__ adj, const float* __restrict__ ao,
    const float* __restrict__ am, const float* __restrict__ hopeG,
    const float* __restrict__ hmac, float* __restrict__ hmacs) {
  __shared__ float al[NO];
  __shared__ float sc[2];
  const int b = blockIdx.y, m = blockIdx.x;
  const int tid = threadIdx.x;
  const int lane = tid & 63, w = tid >> 6;
  const float amv = am[b * NM + m];
  float ev[4], adjv[4];
  float mx = -1e30f;
  #pragma unroll
  for (int i = 0; i < 4; ++i) {
    int o = tid + i * 128;
    float a = adj[(b * NO + o) * NM + m];
    adjv[i] = a;
    float e = ao[b * NO + o] + amv;
    e = (e >= 0.f) ? e : 0.2f * e;
    ev[i] = e;
    if (a == 1.0f) mx = fmaxf(mx, e);
  }
  #pragma unroll
  for (int off = 32; off; off >>= 1) mx = fmaxf(mx, __shfl_down(mx, off));
  if (lane == 0) sc[w] = mx;
  __syncthreads();
  mx = fmaxf(sc[0], sc[1]);
  float s = 0.f;
  float pv[4];
  #pragma unroll
  for (int i = 0; i < 4; ++i) {
    float p = (adjv[i] == 1.0f) ? __expf(ev[i] - mx) : 0.f;
    pv[i] = p; s += p;
  }
  #pragma unroll
  for (int off = 32; off; off >>= 1) s += __shfl_down(s, off);
  __syncthreads();
  if (lane == 0) sc[w] = s;
  __syncthreads();
  s = sc[0] + sc[1];
  const float sinv = (s > 0.f) ? 1.0f / s : 0.f;
  #pragma unroll
  for (int i = 0; i < 4; ++i) al[tid + i * 128] = pv[i] * sinv;
  __syncthreads();
  float acc = 0.f;
  #pragma unroll 4
  for (int o = 0; o < NO; ++o) acc = fmaf(al[o], hopeG[(b * NO + o) * DOC + tid], acc);
  hmacs[(b * NM + m) * DOC + tid] = acc + hmac[(b * NM + m) * DOC + tid];
}

// ---------------- mean-pool over rows (512 threads: 4-way row split) ----------------
__global__ __launch_bounds__(512) void pool_kernel(const float* __restrict__ X,
                                                   float* __restrict__ out,
                                                   int R, float inv) {
  __shared__ float part[4][128];
  const int b = blockIdx.x;
  const int d = threadIdx.x & 127, g = threadIdx.x >> 7;
  const int per = R >> 2;
  float acc = 0.f;
  for (int r = g * per; r < (g + 1) * per; ++r) acc += X[(b * R + r) * 128 + d];
  part[g][d] = acc;
  __syncthreads();
  if (g == 0)
    out[b * 128 + d] = (part[0][d] + part[1][d] + part[2][d] + part[3][d]) * inv;
}

// ---------------- folded U_m ----------------
__global__ __launch_bounds__(128) void um_kernel(
    const float* __restrict__ hmacs, const float* __restrict__ po,
    const float* __restrict__ pm, const float* __restrict__ A0,
    const float* __restrict__ Ab0, float* __restrict__ um) {
  __shared__ float v[384];
  const int b = blockIdx.y, m = blockIdx.x;
  const int j = threadIdx.x;
  v[j] = hmacs[(b * NM + m) * 128 + j];
  v[128 + j] = po[b * 128 + j];
  v[256 + j] = pm[b * 128 + j];
  __syncthreads();
  const float* a = A0 + j * 512 + 128;
  float acc = Ab0[j];
  for (int k = 0; k < 384; ++k) acc = fmaf(a[k], v[k], acc);
  um[(b * NM + m) * 128 + j] = acc;
}

// ---------------- actor v3: no LDS/barriers; CORRECT Uo row = b*512 + o ----------------
// (r9 bug: used flat row b*16384+m*512+o -> 134 MB over-read, 67 MB HBM/dispatch)
// a-frag: row=lane&15, k=(lane>>4)*8+e; B-frag from A1p (L2-resident 32 KB);
// D: col=lane&15, row=(lane>>4)*4+reg (all verified r6).
__global__ __launch_bounds__(256) void actor_mfma3_kernel(
    const float* __restrict__ Uo, const float* __restrict__ Um,
    const short* __restrict__ A1p, const float* __restrict__ Ab1,
    const float* __restrict__ A2, const float* __restrict__ Ab2,
    float* __restrict__ logits) {
  const int tid = threadIdx.x;
  const int rbase = blockIdx.x * 64;       // flat row = b*16384 + m*512 + o
  const int b = rbase >> 14;
  const int m = (rbase & 16383) >> 9;
  const int obase = rbase & 511;
  const int lane = tid & 63, w = tid >> 6;
  const int rowl = lane & 15, kg = lane >> 4;
  const float* uo = Uo + (long)(b * NO + obase + w * 16 + rowl) * 128;
  const float* umb = Um + (b * NM + m) * 128;
  bf16x8 af[4];
  #pragma unroll
  for (int kk = 0; kk < 4; ++kk) {
    int kb = kk * 32 + kg * 8;
    f32x4 u0 = *(const f32x4*)(uo + kb);
    f32x4 u1 = *(const f32x4*)(uo + kb + 4);
    f32x4 m0 = *(const f32x4*)(umb + kb);
    f32x4 m1 = *(const f32x4*)(umb + kb + 4);
    #pragma unroll
    for (int e = 0; e < 4; ++e) af[kk][e]     = f2bf(fast_tanh(u0[e] + m0[e]));
    #pragma unroll
    for (int e = 0; e < 4; ++e) af[kk][4 + e] = f2bf(fast_tanh(u1[e] + m1[e]));
  }
  float partrow[4] = {0.f, 0.f, 0.f, 0.f};
  #pragma unroll
  for (int ct = 0; ct < 8; ++ct) {
    const int col = ct * 16 + rowl;
    f32x4 acc = {0.f, 0.f, 0.f, 0.f};
    #pragma unroll
    for (int kk = 0; kk < 4; ++kk) {
      bf16x8 bf = *(const bf16x8*)(A1p + ((kk * 4 + kg) * 128 + col) * 8);
      acc = __builtin_amdgcn_mfma_f32_16x16x32_bf16(af[kk], bf, acc, 0, 0, 0);
    }
    const float ab = Ab1[col], a2c = A2[col];
    #pragma unroll
    for (int r = 0; r < 4; ++r) {
      float z2 = fast_tanh(acc[r] + ab);
      partrow[r] = fmaf(a2c, z2, partrow[r]);
    }
  }
  const float ab2 = Ab2[0];
  #pragma unroll
  for (int r = 0; r < 4; ++r) {
    float v = partrow[r];
    #pragma unroll
    for (int off = 1; off < 16; off <<= 1) v += __shfl_xor(v, off);
    if (rowl == 0) logits[rbase + w * 16 + kg * 4 + r] = v + ab2;
  }
}

// ---------------- masked log-softmax + gather + entropy (1024 threads) ----------------
__global__ __launch_bounds__(1024) void final_kernel(
    const float* __restrict__ logits, const void* __restrict__ maskp,
    const int* __restrict__ aidx, const int* __restrict__ flag,
    float* __restrict__ out) {
  __shared__ float sc[16], sc2[16];
  const int b = blockIdx.x;
  const int tid = threadIdx.x;
  const int lane = tid & 63, w = tid >> 6;
  const bool word_mode = (flag[0] == 0);
  const unsigned int* mw = (const unsigned int*)maskp;
  const unsigned char* mb = (const unsigned char*)maskp;
  const float* lg = logits + b * (NM * NO);
  float mx = -1e30f;
  for (int s = 0; s < 16; ++s) {
    int i = s * 1024 + tid;
    int o = i & 511, mm = i >> 9;
    int mofs = (b * NO + o) * NM + mm;
    bool msk = word_mode ? (mw[mofs] != 0u) : (mb[mofs] != 0);
    if (msk) mx = fmaxf(mx, lg[i]);
  }
  #pragma unroll
  for (int off = 32; off; off >>= 1) mx = fmaxf(mx, __shfl_down(mx, off));
  if (lane == 0) sc[w] = mx;
  __syncthreads();
  if (tid == 0) {
    float m2 = sc[0];
    for (int k = 1; k < 16; ++k) m2 = fmaxf(m2, sc[k]);
    sc[0] = m2;
  }
  __syncthreads();
  mx = sc[0];
  __syncthreads();
  float S = 0.f, T = 0.f;
  for (int s = 0; s < 16; ++s) {
    int i = s * 1024 + tid;
    int o = i & 511, mm = i >> 9;
    int mofs = (b * NO + o) * NM + mm;
    bool msk = word_mode ? (mw[mofs] != 0u) : (mb[mofs] != 0);
    if (msk) {
      float d = lg[i] - mx;
      float e = __expf(d);
      S += e;
      T = fmaf(e, d, T);
    }
  }
  #pragma unroll
  for (int off = 32; off; off >>= 1) { S += __shfl_down(S, off); T += __shfl_down(T, off); }
  if (lane == 0) { sc[w] = S; sc2[w] = T; }
  __syncthreads();
  if (tid == 0) {
    float St = 0.f, Tt = 0.f;
    for (int k = 0; k < 16; ++k) { St += sc[k]; Tt += sc2[k]; }
    float lS = logf(St);
    out[b] = lg[aidx[b]] - mx - lS;          // action_logprobs
    out[32 + b] = lS - Tt / St;              // dist_entropys
  }
}

// ---------------- critic MLP (per batch) ----------------
__global__ __launch_bounds__(128) void critic_kernel(
    const float* __restrict__ po, const float* __restrict__ pm,
    const float* __restrict__ C0, const float* __restrict__ Cb0,
    const float* __restrict__ C1, const float* __restrict__ Cb1,
    const float* __restrict__ C2, const float* __restrict__ Cb2,
    float* __restrict__ out) {
  __shared__ float v[256];
  __shared__ float z[128];
  __shared__ float sc[2];
  const int b = blockIdx.x;
  const int j = threadIdx.x;
  v[j] = po[b * 128 + j];
  v[128 + j] = pm[b * 128 + j];
  __syncthreads();
  float acc = Cb0[j];
  for (int k = 0; k < 256; ++k) acc = fmaf(C0[j * 256 + k], v[k], acc);
  z[j] = fast_tanh(acc);
  __syncthreads();
  acc = Cb1[j];
  for (int k = 0; k < 128; ++k) acc = fmaf(C1[j * 128 + k], z[k], acc);
  float z2 = fast_tanh(acc);
  float p = C2[j] * z2;
  #pragma unroll
  for (int off = 32; off; off >>= 1) p += __shfl_down(p, off);
  const int lane = j & 63, w = j >> 6;
  if (lane == 0) sc[w] = p;
  __syncthreads();
  if (j == 0) out[16 + b] = sc[0] + sc[1] + Cb2[0];   // state_values
}

extern "C" void kernel_launch(void* const* d_in, const int* in_sizes, int n_in,
                              void* d_out, int out_size, void* d_ws, size_t ws_size,
                              hipStream_t stream) {
  (void)in_sizes; (void)n_in; (void)out_size; (void)ws_size;
  const float* adj  = (const float*)d_in[0];
  const float* nop  = (const float*)d_in[1];
  const float* nmac = (const float*)d_in[2];
  const void*  maskp = d_in[3];
  const int*   aidx = (const int*)d_in[4];
  const float* Wtr  = (const float*)d_in[5];
  const float* btr  = (const float*)d_in[6];
  const float* W0   = (const float*)d_in[7];
  const float* b0   = (const float*)d_in[8];
  const float* W1   = (const float*)d_in[9];
  const float* b1   = (const float*)d_in[10];
  const float* Wp   = (const float*)d_in[11];
  const float* bp   = (const float*)d_in[12];
  const float* Wo   = (const float*)d_in[13];
  const float* Wm   = (const float*)d_in[14];
  const float* alo  = (const float*)d_in[15];
  const float* alm  = (const float*)d_in[16];
  const float* A0   = (const float*)d_in[17];
  const float* Ab0  = (const float*)d_in[18];
  const float* A1   = (const float*)d_in[19];
  const float* Ab1  = (const float*)d_in[20];
  const float* A2   = (const float*)d_in[21];
  const float* Ab2  = (const float*)d_in[22];
  const float* C0   = (const float*)d_in[23];
  const float* Cb0  = (const float*)d_in[24];
  const float* C1   = (const float*)d_in[25];
  const float* Cb1  = (const float*)d_in[26];
  const float* C2   = (const float*)d_in[27];
  const float* Cb2  = (const float*)d_in[28];

  float* ws     = (float*)d_ws;        // needs ~41 MiB
  float* x12    = ws + OFF_X12;
  float* hopes  = ws + OFF_HOPES;
  float* hopeG  = ws + OFF_HOPEG;
  float* hmac   = ws + OFF_HMAC;
  float* hmacs  = ws + OFF_HMACS;
  float* ao     = ws + OFF_AO;
  float* am     = ws + OFF_AM;
  float* po     = ws + OFF_PO;
  float* pm     = ws + OFF_PM;
  float* Uo     = ws + OFF_UO;
  float* Um     = ws + OFF_UM;
  float* logits = ws + OFF_LOG;
  short* A1p    = (short*)(ws + OFF_A1P);
  int*   flag   = (int*)(ws + OFF_FLAG);
  float* outp   = (float*)d_out;

  probe_mask_kernel<<<1, 256, 0, stream>>>((const unsigned int*)maskp, flag);

  // external attention
  gemm_wave<2><<<dim3(16, 64), 256, 0, stream>>>(nop, Wtr, btr, x12, 1024, 128, 128, 128);
  attn_kernel<<<dim3(NH, BB), 256, 0, stream>>>(x12, W0, b0, W1, b1);
  gemm_wave<1><<<dim3(2, 128), 256, 0, stream>>>(x12, Wp, bp, hopes, 128, 1024, 1024, 1024);

  // A1 -> bf16 (after x12's last read; A1p lives in dead x12 region)
  convert_a1_kernel<<<64, 256, 0, stream>>>(A1, A1p);

  // GAT
  gemm_wave<1><<<dim3(2, 128), 256, 0, stream>>>(nop, Wo, nullptr, hopeG, 128, 128, 128, 128);
  gemm_xt<<<dim3(2, 8), 256, 0, stream>>>(nmac, Wm, nullptr, hmac, 512, 128, 64, 64, 64);
  rowdot<<<2048, 256, 0, stream>>>(hopeG, alo, ao, 8192);
  rowdot<<<128, 256, 0, stream>>>(hmac, alm, am, 512);
  gat_kernel<<<dim3(NM, BB), 128, 0, stream>>>(adj, ao, am, hopeG, hmac, hmacs);

  // pooling
  pool_kernel<<<16, 512, 0, stream>>>(hopes, po, 512, 1.0f / 512.0f);
  pool_kernel<<<16, 512, 0, stream>>>(hmacs, pm, 32, 1.0f / 32.0f);

  // actor (Uo aliases x12's region — x12 is dead after the proj GEMM above)
  gemm_wave<1><<<dim3(2, 128), 256, 0, stream>>>(hopes, A0, nullptr, Uo, 128, 128, 128, 512);
  um_kernel<<<dim3(NM, BB), 128, 0, stream>>>(hmacs, po, pm, A0, Ab0, Um);
  actor_mfma3_kernel<<<4096, 256, 0, stream>>>(Uo, Um, A1p, Ab1, A2, Ab2, logits);
  final_kernel<<<16, 1024, 0, stream>>>(logits, maskp, aidx, flag, outp);

  // critic
  critic_kernel<<<16, 128, 0, stream>>>(po, pm, C0, Cb0, C1, Cb1, C2, Cb2, outp);
}

// Round 12
// 284.940 us; speedup vs baseline: 1.0930x; 1.0860x over previous
//
#include <hip/hip_runtime.h>

#define BB 16
#define NO 512
#define NM 32
#define DOC 128
#define C8 1024
#define NH 64
#define KD 16

// ---------------- ws layout (float offsets), ~41 MiB total ----------------
#define OFF_X12   0          // [16*512,1024]  x1/x2 of ext-attn (in-place)
#define OFF_UO    0          // [8192,128] (alias: x12 dead by then)
#define OFF_LOG   1048576    // [16,16384] (alias, after Uo)
#define OFF_A1P   2000000    // [16384] bf16 (8192 floats) A1 pre-converted (alias, dead x12)
#define OFF_HOPES 8388608    // [8192,128] ext-attn output
#define OFF_HOPEG 9437184    // [8192,128] GAT h_ope
#define OFF_HMAC  10485760   // [512,128]  GAT h_mac (pre)
#define OFF_HMACS 10551296   // [512,128]  GAT output
#define OFF_AO    10616832   // [8192]
#define OFF_AM    10625024   // [512]
#define OFF_PO    10625536   // [16,128]
#define OFF_PM    10627584   // [16,128]
#define OFF_UM    10629632   // [512,128]  folded U_m + U_p + Ab0
#define OFF_FLAG  10695168   // int flag (mask dtype probe)

using f32x4  = __attribute__((ext_vector_type(4))) float;
using s16x4  = __attribute__((ext_vector_type(4))) short;
using bf16x8 = __attribute__((ext_vector_type(8))) short;   // 8 bf16 (4 VGPRs)

__device__ __forceinline__ float fast_tanh(float x) {
  x = fminf(15.0f, fmaxf(-15.0f, x));
  float e = __expf(2.0f * x);
  return 1.0f - 2.0f * __builtin_amdgcn_rcpf(e + 1.0f);
}

__device__ __forceinline__ short f2bf(float f) {          // RNE f32->bf16
  unsigned u = __builtin_bit_cast(unsigned, f);
  u += 0x7FFFu + ((u >> 16) & 1u);
  return (short)(u >> 16);
}

__device__ __forceinline__ bf16x8 pack8(f32x4 u0, f32x4 u1) {
  bf16x8 r;
  #pragma unroll
  for (int e = 0; e < 4; ++e) { r[e] = f2bf(u0[e]); r[4 + e] = f2bf(u1[e]); }
  return r;
}

// ---------------- mask dtype probe ----------------
__global__ void probe_mask_kernel(const unsigned int* __restrict__ mask,
                                  int* __restrict__ flag) {
  __shared__ int s[4];
  int bad = 0;
  for (int i = threadIdx.x; i < 4096; i += 256) {
    unsigned int v = mask[i];
    if (!(v == 0u || v == 1u || v == 0x3f800000u)) bad = 1;
  }
  unsigned long long any = __ballot(bad);
  int lane = threadIdx.x & 63, w = threadIdx.x >> 6;
  if (lane == 0) s[w] = (any != 0ull) ? 1 : 0;
  __syncthreads();
  if (threadIdx.x == 0) flag[0] = s[0] | s[1] | s[2] | s[3];
}

// ---------------- A1 f32 -> bf16, B-fragment layout: A1p[(k>>3)*128+col][e=k&7] ----------------
__global__ void convert_a1_kernel(const float* __restrict__ A1, short* __restrict__ A1p) {
  int tid = blockIdx.x * 256 + threadIdx.x;     // 64 blocks x 256 = 16384
  int col = tid >> 7, k = tid & 127;
  A1p[((k >> 3) * 128 + col) * 8 + (k & 7)] = f2bf(A1[tid]);
}

// ---------------- per-wave no-LDS bf16 MFMA GEMM ----------------
template<int MT>
__device__ __forceinline__ void loadk(const float* xb, const float* wb,
                                      long sx, long sw, int k0,
                                      f32x4 (&xa)[MT][2], f32x4 (&wa)[4][2]) {
  #pragma unroll
  for (int mi = 0; mi < MT; ++mi) {
    xa[mi][0] = *(const f32x4*)(xb + mi * sx + k0);
    xa[mi][1] = *(const f32x4*)(xb + mi * sx + k0 + 4);
  }
  #pragma unroll
  for (int ni = 0; ni < 4; ++ni) {
    wa[ni][0] = *(const f32x4*)(wb + ni * sw + k0);
    wa[ni][1] = *(const f32x4*)(wb + ni * sw + k0 + 4);
  }
}

template<int MT>
__device__ __forceinline__ void consume(f32x4 (&xa)[MT][2], f32x4 (&wa)[4][2],
                                        f32x4 (&acc)[MT][4]) {
  bf16x8 bfr[4];
  #pragma unroll
  for (int ni = 0; ni < 4; ++ni) bfr[ni] = pack8(wa[ni][0], wa[ni][1]);
  #pragma unroll
  for (int mi = 0; mi < MT; ++mi) {
    bf16x8 af = pack8(xa[mi][0], xa[mi][1]);
    #pragma unroll
    for (int ni = 0; ni < 4; ++ni)
      acc[mi][ni] = __builtin_amdgcn_mfma_f32_16x16x32_bf16(af, bfr[ni], acc[mi][ni], 0, 0, 0);
  }
}

template<int MT>
__global__ __launch_bounds__(256) void gemm_wave(
    const float* __restrict__ X, const float* __restrict__ W,
    const float* __restrict__ bias, float* __restrict__ C,
    int N, int Kdim, int ldx, int ldw) {
  const int tid = threadIdx.x;
  const int lane = tid & 63, w = tid >> 6;
  const int rowl = lane & 15, kg = lane >> 4;
  const int n0 = blockIdx.x * 64;
  const int m0 = (blockIdx.y * 4 + w) * (MT * 16);
  const float* xb = X + (long)(m0 + rowl) * ldx + kg * 8;
  const float* wb = W + (long)(n0 + rowl) * ldw + kg * 8;
  const long sx = (long)16 * ldx, sw = (long)16 * ldw;
  f32x4 acc[MT][4] = {};
  f32x4 A0[MT][2], B0[4][2], A1[MT][2], B1[4][2];
  loadk<MT>(xb, wb, sx, sw, 0, A0, B0);
  for (int k = 0; k < Kdim; k += 64) {
    loadk<MT>(xb, wb, sx, sw, k + 32, A1, B1);
    consume<MT>(A0, B0, acc);
    if (k + 64 < Kdim) loadk<MT>(xb, wb, sx, sw, k + 64, A0, B0);
    consume<MT>(A1, B1, acc);
  }
  #pragma unroll
  for (int mi = 0; mi < MT; ++mi) {
    #pragma unroll
    for (int ni = 0; ni < 4; ++ni) {
      int col = n0 + ni * 16 + rowl;
      float bv = bias ? bias[col] : 0.0f;
      int rb = m0 + mi * 16 + kg * 4;
      #pragma unroll
      for (int r = 0; r < 4; ++r)
        C[(long)(rb + r) * N + col] = acc[mi][ni][r] + bv;
    }
  }
}

// ---------------- generic f32 GEMM (kept for the small hmac GEMM) ----------------
__global__ __launch_bounds__(256) void gemm_xt(
    const float* __restrict__ X, const float* __restrict__ W,
    const float* __restrict__ bias, float* __restrict__ C,
    int M, int N, int Kdim, int ldx, int ldw) {
  __shared__ float Xs[64][33];
  __shared__ float Ws[64][33];
  const int tid = threadIdx.x;
  const int tx = tid & 15, ty = tid >> 4;
  const int m0 = blockIdx.y * 64, n0 = blockIdx.x * 64;
  float acc[4][4] = {};
  for (int k0 = 0; k0 < Kdim; k0 += 32) {
    #pragma unroll
    for (int l = 0; l < 8; ++l) {
      int f = l * 256 + tid;
      int r = f >> 5, c = f & 31;
      Xs[r][c] = X[(m0 + r) * ldx + k0 + c];
      Ws[r][c] = W[(n0 + r) * ldw + k0 + c];
    }
    __syncthreads();
    #pragma unroll 8
    for (int kk = 0; kk < 32; ++kk) {
      float xr[4], wr[4];
      #pragma unroll
      for (int i = 0; i < 4; ++i) xr[i] = Xs[ty * 4 + i][kk];
      #pragma unroll
      for (int j = 0; j < 4; ++j) wr[j] = Ws[tx * 4 + j][kk];
      #pragma unroll
      for (int i = 0; i < 4; ++i)
        #pragma unroll
        for (int j = 0; j < 4; ++j)
          acc[i][j] = fmaf(xr[i], wr[j], acc[i][j]);
    }
    __syncthreads();
  }
  #pragma unroll
  for (int i = 0; i < 4; ++i) {
    int m = m0 + ty * 4 + i;
    #pragma unroll
    for (int j = 0; j < 4; ++j) {
      int n = n0 + tx * 4 + j;
      C[m * N + n] = acc[i][j] + (bias ? bias[n] : 0.0f);
    }
  }
}

// ---------------- external attention middle: per (b,h) slice, in place on x12 ----------------
__global__ __launch_bounds__(256) void attn_kernel(
    float* __restrict__ x12,
    const float* __restrict__ W0, const float* __restrict__ b0,
    const float* __restrict__ W1, const float* __restrict__ b1) {
  __shared__ float S[NO][KD + 1];
  __shared__ float red[16][17];
  __shared__ float colmax[16], colsum[16];
  __shared__ float rs[NO];
  const int b = blockIdx.y, h = blockIdx.x;
  const int tid = threadIdx.x;
  const int tk = tid & 15, tg = tid >> 4;
  float* base = x12 + (b * NO) * C8 + h * KD;
  #pragma unroll
  for (int l = 0; l < 32; ++l) {
    int f = l * 256 + tid;
    int n = f >> 4, k = f & 15;
    S[n][k] = base[n * C8 + k];
  }
  __syncthreads();
  float w0r[16];
  #pragma unroll
  for (int k = 0; k < 16; ++k) w0r[k] = W0[tk * 16 + k];
  const float b0v = b0[tk];
  float Areg[32];
  for (int i = 0; i < 32; ++i) {
    int n = tg + 16 * i;
    float acc = b0v;
    #pragma unroll
    for (int k = 0; k < 16; ++k) acc = fmaf(S[n][k], w0r[k], acc);
    Areg[i] = acc;
  }
  __syncthreads();
  for (int i = 0; i < 32; ++i) { int n = tg + 16 * i; S[n][tk] = Areg[i]; }
  __syncthreads();
  float mx = -1e30f;
  for (int i = 0; i < 32; ++i) mx = fmaxf(mx, Areg[i]);
  red[tg][tk] = mx;
  __syncthreads();
  if (tg == 0) {
    float mm = red[0][tk];
    for (int g = 1; g < 16; ++g) mm = fmaxf(mm, red[g][tk]);
    colmax[tk] = mm;
  }
  __syncthreads();
  const float cm = colmax[tk];
  float s = 0.f;
  for (int i = 0; i < 32; ++i) { float e = __expf(Areg[i] - cm); Areg[i] = e; s += e; }
  __syncthreads();
  red[tg][tk] = s;
  __syncthreads();
  if (tg == 0) {
    float ss = 0.f;
    for (int g = 0; g < 16; ++g) ss += red[g][tk];
    colsum[tk] = ss;
  }
  __syncthreads();
  const float inv = 1.0f / colsum[tk];
  for (int i = 0; i < 32; ++i) { int n = tg + 16 * i; S[n][tk] = Areg[i] * inv; }
  __syncthreads();
  #pragma unroll
  for (int rr = 0; rr < 2; ++rr) {
    int n = tid * 2 + rr;
    float t = 0.f;
    #pragma unroll
    for (int k = 0; k < 16; ++k) t += S[n][k];
    rs[n] = t;
  }
  __syncthreads();
  float w1r[16];
  #pragma unroll
  for (int k = 0; k < 16; ++k) w1r[k] = W1[tk * 16 + k];
  const float b1v = b1[tk];
  for (int i = 0; i < 32; ++i) {
    int n = tg + 16 * i;
    float rinv = 1.0f / (1e-10f + rs[n]);
    float acc = b1v;
    #pragma unroll
    for (int k = 0; k < 16; ++k) acc = fmaf(S[n][k] * rinv, w1r[k], acc);
    base[n * C8 + tk] = acc;
  }
}

// ---------------- fused row dots: a_o (8192 rows) then a_m (512 rows) ----------------
__global__ void rowdot2(const float* __restrict__ X1, const float* __restrict__ a1,
                        float* __restrict__ o1, int R1,
                        const float* __restrict__ X2, const float* __restrict__ a2,
                        float* __restrict__ o2, int R2) {
  int wid = (blockIdx.x * blockDim.x + threadIdx.x) >> 6;
  int lane = threadIdx.x & 63;
  const float* X; const float* al; float* out; int r;
  if (wid < R1)            { X = X1; al = a1; out = o1; r = wid; }
  else if (wid < R1 + R2)  { X = X2; al = a2; out = o2; r = wid - R1; }
  else return;
  const float* row = X + (long)r * 128;
  float v = fmaf(row[lane], al[lane], row[lane + 64] * al[lane + 64]);
  #pragma unroll
  for (int off = 32; off; off >>= 1) v += __shfl_down(v, off);
  if (lane == 0) out[r] = v;
}

// ---------------- GAT per (b,m): 512 threads, one o per thread; 4-way agg split ----------------
__global__ __launch_bounds__(512) void gat_kernel(
    const float* __restrict__ adj, const float* __restrict__ ao,
    const float* __restrict__ am, const float* __restrict__ hopeG,
    const float* __restrict__ hmac, float* __restrict__ hmacs) {
  __shared__ float al[NO];
  __shared__ float red8[8];
  __shared__ float part[4][128];
  const int b = blockIdx.y, m = blockIdx.x;
  const int tid = threadIdx.x;            // 512 = 8 waves; o = tid
  const int lane = tid & 63, w = tid >> 6;
  const float amv = am[b * NM + m];
  const float a = adj[(b * NO + tid) * NM + m];
  float e = ao[b * NO + tid] + amv;
  e = (e >= 0.f) ? e : 0.2f * e;
  float mx = (a == 1.0f) ? e : -1e30f;
  #pragma unroll
  for (int off = 32; off; off >>= 1) mx = fmaxf(mx, __shfl_down(mx, off));
  if (lane == 0) red8[w] = mx;
  __syncthreads();
  if (tid == 0) {
    float mm2 = red8[0];
    #pragma unroll
    for (int k = 1; k < 8; ++k) mm2 = fmaxf(mm2, red8[k]);
    red8[0] = mm2;
  }
  __syncthreads();
  mx = red8[0];
  __syncthreads();
  const float p = (a == 1.0f) ? __expf(e - mx) : 0.f;
  float s = p;
  #pragma unroll
  for (int off = 32; off; off >>= 1) s += __shfl_down(s, off);
  if (lane == 0) red8[w] = s;
  __syncthreads();
  if (tid == 0) {
    float ss = 0.f;
    #pragma unroll
    for (int k = 0; k < 8; ++k) ss += red8[k];
    red8[0] = ss;
  }
  __syncthreads();
  s = red8[0];
  const float sinv = (s > 0.f) ? 1.0f / s : 0.f;
  al[tid] = p * sinv;
  __syncthreads();
  // aggregation: og-quarter of o-range, d = channel
  const int d = tid & 127, og = tid >> 7;
  float acc = 0.f;
  const float* hb = hopeG + ((long)(b * NO) + og * 128) * DOC + d;
  #pragma unroll 4
  for (int i = 0; i < 128; ++i)
    acc = fmaf(al[og * 128 + i], hb[(long)i * DOC], acc);
  part[og][d] = acc;
  __syncthreads();
  if (og == 0)
    hmacs[(b * NM + m) * DOC + d] = part[0][d] + part[1][d] + part[2][d] + part[3][d]
                                   + hmac[(b * NM + m) * DOC + d];
}

// ---------------- fused mean-pools (blocks 0-15: hopes->po, 16-31: hmacs->pm) ----------------
__global__ __launch_bounds__(512) void pool2_kernel(const float* __restrict__ hopes,
                                                    const float* __restrict__ hmacs,
                                                    float* __restrict__ po,
                                                    float* __restrict__ pm) {
  __shared__ float part[4][128];
  int bb = blockIdx.x;
  const float* X; float* out; int R; float inv;
  if (bb < 16) { X = hopes; out = po; R = 512; inv = 1.0f / 512.0f; }
  else         { X = hmacs; out = pm; R = 32;  inv = 1.0f / 32.0f; bb -= 16; }
  const int d = threadIdx.x & 127, g = threadIdx.x >> 7;
  const int per = R >> 2;
  float acc = 0.f;
  for (int r = g * per; r < (g + 1) * per; ++r) acc += X[(bb * R + r) * 128 + d];
  part[g][d] = acc;
  __syncthreads();
  if (g == 0)
    out[bb * 128 + d] = (part[0][d] + part[1][d] + part[2][d] + part[3][d]) * inv;
}

// ---------------- folded U_m ----------------
__global__ __launch_bounds__(128) void um_kernel(
    const float* __restrict__ hmacs, const float* __restrict__ po,
    const float* __restrict__ pm, const float* __restrict__ A0,
    const float* __restrict__ Ab0, float* __restrict__ um) {
  __shared__ float v[384];
  const int b = blockIdx.y, m = blockIdx.x;
  const int j = threadIdx.x;
  v[j] = hmacs[(b * NM + m) * 128 + j];
  v[128 + j] = po[b * 128 + j];
  v[256 + j] = pm[b * 128 + j];
  __syncthreads();
  const float* a = A0 + j * 512 + 128;
  float acc = Ab0[j];
  for (int k = 0; k < 384; ++k) acc = fmaf(a[k], v[k], acc);
  um[(b * NM + m) * 128 + j] = acc;
}

// ---------------- actor v4: B-frags/Uo/Ab1/A2 register-resident, AMG m per block ----------------
// a-frag: row=lane&15, k=(lane>>4)*8+e; B-frag col=lane&15; D col=lane&15,
// row=(lane>>4)*4+reg (all verified r6/r11).  m-loop is reg-reg: only Um reloads.
#define AMG 4
__global__ __launch_bounds__(256) void actor_mfma4_kernel(
    const float* __restrict__ Uo, const float* __restrict__ Um,
    const short* __restrict__ A1p, const float* __restrict__ Ab1,
    const float* __restrict__ A2, const float* __restrict__ Ab2,
    float* __restrict__ logits) {
  const int tid = threadIdx.x;
  const int mg = blockIdx.x;           // 0..(32/AMG-1)
  const int rg = blockIdx.y;           // 0..127, 64 rows each
  const int row0 = rg * 64;
  const int b = row0 >> 9;
  const int obase = row0 & 511;
  const int lane = tid & 63, w = tid >> 6;
  const int rowl = lane & 15, kg = lane >> 4;
  // B-fragments, register-resident (128 VGPRs)
  bf16x8 Bf[8][4];
  #pragma unroll
  for (int ct = 0; ct < 8; ++ct)
    #pragma unroll
    for (int kk = 0; kk < 4; ++kk)
      Bf[ct][kk] = *(const bf16x8*)(A1p + ((kk * 4 + kg) * 128 + ct * 16 + rowl) * 8);
  // Uo row slice, register-resident (32 VGPRs)
  const float* uo = Uo + (long)(b * NO + obase + w * 16 + rowl) * 128;
  f32x4 uor[8];
  #pragma unroll
  for (int kk = 0; kk < 4; ++kk) {
    uor[kk * 2]     = *(const f32x4*)(uo + kk * 32 + kg * 8);
    uor[kk * 2 + 1] = *(const f32x4*)(uo + kk * 32 + kg * 8 + 4);
  }
  float ab1c[8], a2c[8];
  #pragma unroll
  for (int ct = 0; ct < 8; ++ct) {
    ab1c[ct] = Ab1[ct * 16 + rowl];
    a2c[ct]  = A2[ct * 16 + rowl];
  }
  const float ab2 = Ab2[0];
  #pragma unroll
  for (int mi = 0; mi < AMG; ++mi) {
    const int m = mg * AMG + mi;
    const float* umb = Um + (b * NM + m) * 128;
    bf16x8 af[4];
    #pragma unroll
    for (int kk = 0; kk < 4; ++kk) {
      int kb = kk * 32 + kg * 8;
      f32x4 m0 = *(const f32x4*)(umb + kb);
      f32x4 m1 = *(const f32x4*)(umb + kb + 4);
      #pragma unroll
      for (int e = 0; e < 4; ++e) af[kk][e]     = f2bf(fast_tanh(uor[kk * 2][e] + m0[e]));
      #pragma unroll
      for (int e = 0; e < 4; ++e) af[kk][4 + e] = f2bf(fast_tanh(uor[kk * 2 + 1][e] + m1[e]));
    }
    float partrow[4] = {0.f, 0.f, 0.f, 0.f};
    #pragma unroll
    for (int ct = 0; ct < 8; ++ct) {
      f32x4 acc = {0.f, 0.f, 0.f, 0.f};
      #pragma unroll
      for (int kk = 0; kk < 4; ++kk)
        acc = __builtin_amdgcn_mfma_f32_16x16x32_bf16(af[kk], Bf[ct][kk], acc, 0, 0, 0);
      #pragma unroll
      for (int r = 0; r < 4; ++r) {
        float z2 = fast_tanh(acc[r] + ab1c[ct]);
        partrow[r] = fmaf(a2c[ct], z2, partrow[r]);
      }
    }
    #pragma unroll
    for (int r = 0; r < 4; ++r) {
      float v = partrow[r];
      #pragma unroll
      for (int off = 1; off < 16; off <<= 1) v += __shfl_xor(v, off);
      if (rowl == 0)
        logits[((long)b << 14) + m * 512 + obase + w * 16 + kg * 4 + r] = v + ab2;
    }
  }
}

// ---------------- masked log-softmax + gather + entropy (1024 threads) ----------------
__global__ __launch_bounds__(1024) void final_kernel(
    const float* __restrict__ logits, const void* __restrict__ maskp,
    const int* __restrict__ aidx, const int* __restrict__ flag,
    float* __restrict__ out) {
  __shared__ float sc[16], sc2[16];
  const int b = blockIdx.x;
  const int tid = threadIdx.x;
  const int lane = tid & 63, w = tid >> 6;
  const bool word_mode = (flag[0] == 0);
  const unsigned int* mw = (const unsigned int*)maskp;
  const unsigned char* mb = (const unsigned char*)maskp;
  const float* lg = logits + b * (NM * NO);
  float mx = -1e30f;
  for (int s = 0; s < 16; ++s) {
    int i = s * 1024 + tid;
    int o = i & 511, mm = i >> 9;
    int mofs = (b * NO + o) * NM + mm;
    bool msk = word_mode ? (mw[mofs] != 0u) : (mb[mofs] != 0);
    if (msk) mx = fmaxf(mx, lg[i]);
  }
  #pragma unroll
  for (int off = 32; off; off >>= 1) mx = fmaxf(mx, __shfl_down(mx, off));
  if (lane == 0) sc[w] = mx;
  __syncthreads();
  if (tid == 0) {
    float m2 = sc[0];
    for (int k = 1; k < 16; ++k) m2 = fmaxf(m2, sc[k]);
    sc[0] = m2;
  }
  __syncthreads();
  mx = sc[0];
  __syncthreads();
  float S = 0.f, T = 0.f;
  for (int s = 0; s < 16; ++s) {
    int i = s * 1024 + tid;
    int o = i & 511, mm = i >> 9;
    int mofs = (b * NO + o) * NM + mm;
    bool msk = word_mode ? (mw[mofs] != 0u) : (mb[mofs] != 0);
    if (msk) {
      float d = lg[i] - mx;
      float e = __expf(d);
      S += e;
      T = fmaf(e, d, T);
    }
  }
  #pragma unroll
  for (int off = 32; off; off >>= 1) { S += __shfl_down(S, off); T += __shfl_down(T, off); }
  if (lane == 0) { sc[w] = S; sc2[w] = T; }
  __syncthreads();
  if (tid == 0) {
    float St = 0.f, Tt = 0.f;
    for (int k = 0; k < 16; ++k) { St += sc[k]; Tt += sc2[k]; }
    float lS = logf(St);
    out[b] = lg[aidx[b]] - mx - lS;          // action_logprobs
    out[32 + b] = lS - Tt / St;              // dist_entropys
  }
}

// ---------------- critic MLP (per batch) ----------------
__global__ __launch_bounds__(128) void critic_kernel(
    const float* __restrict__ po, const float* __restrict__ pm,
    const float* __restrict__ C0, const float* __restrict__ Cb0,
    const float* __restrict__ C1, const float* __restrict__ Cb1,
    const float* __restrict__ C2, const float* __restrict__ Cb2,
    float* __restrict__ out) {
  __shared__ float v[256];
  __shared__ float z[128];
  __shared__ float sc[2];
  const int b = blockIdx.x;
  const int j = threadIdx.x;
  v[j] = po[b * 128 + j];
  v[128 + j] = pm[b * 128 + j];
  __syncthreads();
  float acc = Cb0[j];
  for (int k = 0; k < 256; ++k) acc = fmaf(C0[j * 256 + k], v[k], acc);
  z[j] = fast_tanh(acc);
  __syncthreads();
  acc = Cb1[j];
  for (int k = 0; k < 128; ++k) acc = fmaf(C1[j * 128 + k], z[k], acc);
  float z2 = fast_tanh(acc);
  float p = C2[j] * z2;
  #pragma unroll
  for (int off = 32; off; off >>= 1) p += __shfl_down(p, off);
  const int lane = j & 63, w = j >> 6;
  if (lane == 0) sc[w] = p;
  __syncthreads();
  if (j == 0) out[16 + b] = sc[0] + sc[1] + Cb2[0];   // state_values
}

extern "C" void kernel_launch(void* const* d_in, const int* in_sizes, int n_in,
                              void* d_out, int out_size, void* d_ws, size_t ws_size,
                              hipStream_t stream) {
  (void)in_sizes; (void)n_in; (void)out_size; (void)ws_size;
  const float* adj  = (const float*)d_in[0];
  const float* nop  = (const float*)d_in[1];
  const float* nmac = (const float*)d_in[2];
  const void*  maskp = d_in[3];
  const int*   aidx = (const int*)d_in[4];
  const float* Wtr  = (const float*)d_in[5];
  const float* btr  = (const float*)d_in[6];
  const float* W0   = (const float*)d_in[7];
  const float* b0   = (const float*)d_in[8];
  const float* W1   = (const float*)d_in[9];
  const float* b1   = (const float*)d_in[10];
  const float* Wp   = (const float*)d_in[11];
  const float* bp   = (const float*)d_in[12];
  const float* Wo   = (const float*)d_in[13];
  const float* Wm   = (const float*)d_in[14];
  const float* alo  = (const float*)d_in[15];
  const float* alm  = (const float*)d_in[16];
  const float* A0   = (const float*)d_in[17];
  const float* Ab0  = (const float*)d_in[18];
  const float* A1   = (const float*)d_in[19];
  const float* Ab1  = (const float*)d_in[20];
  const float* A2   = (const float*)d_in[21];
  const float* Ab2  = (const float*)d_in[22];
  const float* C0   = (const float*)d_in[23];
  const float* Cb0  = (const float*)d_in[24];
  const float* C1   = (const float*)d_in[25];
  const float* Cb1  = (const float*)d_in[26];
  const float* C2   = (const float*)d_in[27];
  const float* Cb2  = (const float*)d_in[28];

  float* ws     = (float*)d_ws;        // needs ~41 MiB
  float* x12    = ws + OFF_X12;
  float* hopes  = ws + OFF_HOPES;
  float* hopeG  = ws + OFF_HOPEG;
  float* hmac   = ws + OFF_HMAC;
  float* hmacs  = ws + OFF_HMACS;
  float* ao     = ws + OFF_AO;
  float* am     = ws + OFF_AM;
  float* po     = ws + OFF_PO;
  float* pm     = ws + OFF_PM;
  float* Uo     = ws + OFF_UO;
  float* Um     = ws + OFF_UM;
  float* logits = ws + OFF_LOG;
  short* A1p    = (short*)(ws + OFF_A1P);
  int*   flag   = (int*)(ws + OFF_FLAG);
  float* outp   = (float*)d_out;

  probe_mask_kernel<<<1, 256, 0, stream>>>((const unsigned int*)maskp, flag);

  // external attention
  gemm_wave<2><<<dim3(16, 64), 256, 0, stream>>>(nop, Wtr, btr, x12, 1024, 128, 128, 128);
  attn_kernel<<<dim3(NH, BB), 256, 0, stream>>>(x12, W0, b0, W1, b1);
  gemm_wave<1><<<dim3(2, 128), 256, 0, stream>>>(x12, Wp, bp, hopes, 128, 1024, 1024, 1024);

  // A1 -> bf16 (after x12's last read; A1p lives in dead x12 region)
  convert_a1_kernel<<<64, 256, 0, stream>>>(A1, A1p);

  // GAT
  gemm_wave<1><<<dim3(2, 128), 256, 0, stream>>>(nop, Wo, nullptr, hopeG, 128, 128, 128, 128);
  gemm_xt<<<dim3(2, 8), 256, 0, stream>>>(nmac, Wm, nullptr, hmac, 512, 128, 64, 64, 64);
  rowdot2<<<2176, 256, 0, stream>>>(hopeG, alo, ao, 8192, hmac, alm, am, 512);
  gat_kernel<<<dim3(NM, BB), 512, 0, stream>>>(adj, ao, am, hopeG, hmac, hmacs);

  // pooling (fused)
  pool2_kernel<<<32, 512, 0, stream>>>(hopes, hmacs, po, pm);

  // actor (Uo aliases x12's region — x12 is dead after the proj GEMM above)
  gemm_wave<1><<<dim3(2, 128), 256, 0, stream>>>(hopes, A0, nullptr, Uo, 128, 128, 128, 512);
  um_kernel<<<dim3(NM, BB), 128, 0, stream>>>(hmacs, po, pm, A0, Ab0, Um);
  actor_mfma4_kernel<<<dim3(32 / AMG, 128), 256, 0, stream>>>(Uo, Um, A1p, Ab1, A2, Ab2, logits);
  final_kernel<<<16, 1024, 0, stream>>>(logits, maskp, aidx, flag, outp);

  // critic
  critic_kernel<<<16, 128, 0, stream>>>(po, pm, C0, Cb0, C1, Cb1, C2, Cb2, outp);
}

// Round 13
// 277.102 us; speedup vs baseline: 1.1240x; 1.0283x over previous
//
#include <hip/hip_runtime.h>

#define BB 16
#define NO 512
#define NM 32
#define DOC 128
#define C8 1024
#define NH 64
#define KD 16

// ---------------- ws layout (float offsets), ~41 MiB total ----------------
#define OFF_X12   0          // [16*512,1024]  x1/x2 of ext-attn (in-place)
#define OFF_UO    0          // [8192,128] (alias: x12 dead by then)
#define OFF_LOG   1048576    // [16,16384] (alias, after Uo)
#define OFF_A1P   2000000    // [16384] bf16 (8192 floats) A1 pre-converted (alias, dead x12)
#define OFF_HOPES 8388608    // [8192,128] ext-attn output
#define OFF_HOPEG 9437184    // [8192,128] GAT h_ope
#define OFF_HMAC  10485760   // [512,128]  GAT h_mac (pre)
#define OFF_HMACS 10551296   // [512,128]  GAT output
#define OFF_AO    10616832   // [8192]
#define OFF_AM    10625024   // [512]
#define OFF_PO    10625536   // [16,128]
#define OFF_PM    10627584   // [16,128]
#define OFF_UM    10629632   // [512,128]  folded U_m + U_p + Ab0
#define OFF_FLAG  10695168   // int flag (mask dtype probe)

using f32x4  = __attribute__((ext_vector_type(4))) float;
using s16x4  = __attribute__((ext_vector_type(4))) short;
using bf16x8 = __attribute__((ext_vector_type(8))) short;   // 8 bf16 (4 VGPRs)

__device__ __forceinline__ float fast_tanh(float x) {
  x = fminf(15.0f, fmaxf(-15.0f, x));
  float e = __expf(2.0f * x);
  return 1.0f - 2.0f * __builtin_amdgcn_rcpf(e + 1.0f);
}

__device__ __forceinline__ short f2bf(float f) {          // RNE f32->bf16 (host-side-ish use)
  unsigned u = __builtin_bit_cast(unsigned, f);
  u += 0x7FFFu + ((u >> 16) & 1u);
  return (short)(u >> 16);
}

// packed bf16 convert via HW op: dword = {lo=cvt(a), hi=cvt(b)}
__device__ __forceinline__ unsigned cvtpk(float a, float b) {
  unsigned r;
  asm("v_cvt_pk_bf16_f32 %0, %1, %2" : "=v"(r) : "v"(a), "v"(b));
  return r;
}

__device__ __forceinline__ bf16x8 pack8(f32x4 u0, f32x4 u1) {
  union { unsigned u[4]; bf16x8 v; } cv;
  cv.u[0] = cvtpk(u0[0], u0[1]);
  cv.u[1] = cvtpk(u0[2], u0[3]);
  cv.u[2] = cvtpk(u1[0], u1[1]);
  cv.u[3] = cvtpk(u1[2], u1[3]);
  return cv.v;
}

__device__ __forceinline__ bf16x8 pack8f(const float* t) {
  union { unsigned u[4]; bf16x8 v; } cv;
  cv.u[0] = cvtpk(t[0], t[1]);
  cv.u[1] = cvtpk(t[2], t[3]);
  cv.u[2] = cvtpk(t[4], t[5]);
  cv.u[3] = cvtpk(t[6], t[7]);
  return cv.v;
}

// ---------------- mask dtype probe ----------------
__global__ void probe_mask_kernel(const unsigned int* __restrict__ mask,
                                  int* __restrict__ flag) {
  __shared__ int s[4];
  int bad = 0;
  for (int i = threadIdx.x; i < 4096; i += 256) {
    unsigned int v = mask[i];
    if (!(v == 0u || v == 1u || v == 0x3f800000u)) bad = 1;
  }
  unsigned long long any = __ballot(bad);
  int lane = threadIdx.x & 63, w = threadIdx.x >> 6;
  if (lane == 0) s[w] = (any != 0ull) ? 1 : 0;
  __syncthreads();
  if (threadIdx.x == 0) flag[0] = s[0] | s[1] | s[2] | s[3];
}

// ---------------- A1 f32 -> bf16, B-fragment layout: A1p[(k>>3)*128+col][e=k&7] ----------------
__global__ void convert_a1_kernel(const float* __restrict__ A1, short* __restrict__ A1p) {
  int tid = blockIdx.x * 256 + threadIdx.x;     // 64 blocks x 256 = 16384
  int col = tid >> 7, k = tid & 127;
  A1p[((k >> 3) * 128 + col) * 8 + (k & 7)] = f2bf(A1[tid]);
}

// ---------------- per-wave no-LDS bf16 MFMA GEMM ----------------
template<int MT>
__device__ __forceinline__ void loadk(const float* xb, const float* wb,
                                      long sx, long sw, int k0,
                                      f32x4 (&xa)[MT][2], f32x4 (&wa)[4][2]) {
  #pragma unroll
  for (int mi = 0; mi < MT; ++mi) {
    xa[mi][0] = *(const f32x4*)(xb + mi * sx + k0);
    xa[mi][1] = *(const f32x4*)(xb + mi * sx + k0 + 4);
  }
  #pragma unroll
  for (int ni = 0; ni < 4; ++ni) {
    wa[ni][0] = *(const f32x4*)(wb + ni * sw + k0);
    wa[ni][1] = *(const f32x4*)(wb + ni * sw + k0 + 4);
  }
}

template<int MT>
__device__ __forceinline__ void consume(f32x4 (&xa)[MT][2], f32x4 (&wa)[4][2],
                                        f32x4 (&acc)[MT][4]) {
  bf16x8 bfr[4];
  #pragma unroll
  for (int ni = 0; ni < 4; ++ni) bfr[ni] = pack8(wa[ni][0], wa[ni][1]);
  #pragma unroll
  for (int mi = 0; mi < MT; ++mi) {
    bf16x8 af = pack8(xa[mi][0], xa[mi][1]);
    #pragma unroll
    for (int ni = 0; ni < 4; ++ni)
      acc[mi][ni] = __builtin_amdgcn_mfma_f32_16x16x32_bf16(af, bfr[ni], acc[mi][ni], 0, 0, 0);
  }
}

template<int MT>
__global__ __launch_bounds__(256) void gemm_wave(
    const float* __restrict__ X, const float* __restrict__ W,
    const float* __restrict__ bias, float* __restrict__ C,
    int N, int Kdim, int ldx, int ldw) {
  const int tid = threadIdx.x;
  const int lane = tid & 63, w = tid >> 6;
  const int rowl = lane & 15, kg = lane >> 4;
  const int n0 = blockIdx.x * 64;
  const int m0 = (blockIdx.y * 4 + w) * (MT * 16);
  const float* xb = X + (long)(m0 + rowl) * ldx + kg * 8;
  const float* wb = W + (long)(n0 + rowl) * ldw + kg * 8;
  const long sx = (long)16 * ldx, sw = (long)16 * ldw;
  f32x4 acc[MT][4] = {};
  f32x4 A0[MT][2], B0[4][2], A1[MT][2], B1[4][2];
  loadk<MT>(xb, wb, sx, sw, 0, A0, B0);
  for (int k = 0; k < Kdim; k += 64) {
    loadk<MT>(xb, wb, sx, sw, k + 32, A1, B1);
    consume<MT>(A0, B0, acc);
    if (k + 64 < Kdim) loadk<MT>(xb, wb, sx, sw, k + 64, A0, B0);
    consume<MT>(A1, B1, acc);
  }
  #pragma unroll
  for (int mi = 0; mi < MT; ++mi) {
    #pragma unroll
    for (int ni = 0; ni < 4; ++ni) {
      int col = n0 + ni * 16 + rowl;
      float bv = bias ? bias[col] : 0.0f;
      int rb = m0 + mi * 16 + kg * 4;
      #pragma unroll
      for (int r = 0; r < 4; ++r)
        C[(long)(rb + r) * N + col] = acc[mi][ni][r] + bv;
    }
  }
}

// ---------------- generic f32 GEMM (kept for the small hmac GEMM) ----------------
__global__ __launch_bounds__(256) void gemm_xt(
    const float* __restrict__ X, const float* __restrict__ W,
    const float* __restrict__ bias, float* __restrict__ C,
    int M, int N, int Kdim, int ldx, int ldw) {
  __shared__ float Xs[64][33];
  __shared__ float Ws[64][33];
  const int tid = threadIdx.x;
  const int tx = tid & 15, ty = tid >> 4;
  const int m0 = blockIdx.y * 64, n0 = blockIdx.x * 64;
  float acc[4][4] = {};
  for (int k0 = 0; k0 < Kdim; k0 += 32) {
    #pragma unroll
    for (int l = 0; l < 8; ++l) {
      int f = l * 256 + tid;
      int r = f >> 5, c = f & 31;
      Xs[r][c] = X[(m0 + r) * ldx + k0 + c];
      Ws[r][c] = W[(n0 + r) * ldw + k0 + c];
    }
    __syncthreads();
    #pragma unroll 8
    for (int kk = 0; kk < 32; ++kk) {
      float xr[4], wr[4];
      #pragma unroll
      for (int i = 0; i < 4; ++i) xr[i] = Xs[ty * 4 + i][kk];
      #pragma unroll
      for (int j = 0; j < 4; ++j) wr[j] = Ws[tx * 4 + j][kk];
      #pragma unroll
      for (int i = 0; i < 4; ++i)
        #pragma unroll
        for (int j = 0; j < 4; ++j)
          acc[i][j] = fmaf(xr[i], wr[j], acc[i][j]);
    }
    __syncthreads();
  }
  #pragma unroll
  for (int i = 0; i < 4; ++i) {
    int m = m0 + ty * 4 + i;
    #pragma unroll
    for (int j = 0; j < 4; ++j) {
      int n = n0 + tx * 4 + j;
      C[m * N + n] = acc[i][j] + (bias ? bias[n] : 0.0f);
    }
  }
}

// ---------------- external attention middle: per (b,h) slice, in place on x12 ----------------
__global__ __launch_bounds__(256) void attn_kernel(
    float* __restrict__ x12,
    const float* __restrict__ W0, const float* __restrict__ b0,
    const float* __restrict__ W1, const float* __restrict__ b1) {
  __shared__ float S[NO][KD + 1];
  __shared__ float red[16][17];
  __shared__ float colmax[16], colsum[16];
  __shared__ float rs[NO];
  const int b = blockIdx.y, h = blockIdx.x;
  const int tid = threadIdx.x;
  const int tk = tid & 15, tg = tid >> 4;
  float* base = x12 + (b * NO) * C8 + h * KD;
  #pragma unroll
  for (int l = 0; l < 32; ++l) {
    int f = l * 256 + tid;
    int n = f >> 4, k = f & 15;
    S[n][k] = base[n * C8 + k];
  }
  __syncthreads();
  float w0r[16];
  #pragma unroll
  for (int k = 0; k < 16; ++k) w0r[k] = W0[tk * 16 + k];
  const float b0v = b0[tk];
  float Areg[32];
  for (int i = 0; i < 32; ++i) {
    int n = tg + 16 * i;
    float acc = b0v;
    #pragma unroll
    for (int k = 0; k < 16; ++k) acc = fmaf(S[n][k], w0r[k], acc);
    Areg[i] = acc;
  }
  __syncthreads();
  for (int i = 0; i < 32; ++i) { int n = tg + 16 * i; S[n][tk] = Areg[i]; }
  __syncthreads();
  float mx = -1e30f;
  for (int i = 0; i < 32; ++i) mx = fmaxf(mx, Areg[i]);
  red[tg][tk] = mx;
  __syncthreads();
  if (tg == 0) {
    float mm = red[0][tk];
    for (int g = 1; g < 16; ++g) mm = fmaxf(mm, red[g][tk]);
    colmax[tk] = mm;
  }
  __syncthreads();
  const float cm = colmax[tk];
  float s = 0.f;
  for (int i = 0; i < 32; ++i) { float e = __expf(Areg[i] - cm); Areg[i] = e; s += e; }
  __syncthreads();
  red[tg][tk] = s;
  __syncthreads();
  if (tg == 0) {
    float ss = 0.f;
    for (int g = 0; g < 16; ++g) ss += red[g][tk];
    colsum[tk] = ss;
  }
  __syncthreads();
  const float inv = 1.0f / colsum[tk];
  for (int i = 0; i < 32; ++i) { int n = tg + 16 * i; S[n][tk] = Areg[i] * inv; }
  __syncthreads();
  #pragma unroll
  for (int rr = 0; rr < 2; ++rr) {
    int n = tid * 2 + rr;
    float t = 0.f;
    #pragma unroll
    for (int k = 0; k < 16; ++k) t += S[n][k];
    rs[n] = t;
  }
  __syncthreads();
  float w1r[16];
  #pragma unroll
  for (int k = 0; k < 16; ++k) w1r[k] = W1[tk * 16 + k];
  const float b1v = b1[tk];
  for (int i = 0; i < 32; ++i) {
    int n = tg + 16 * i;
    float rinv = 1.0f / (1e-10f + rs[n]);
    float acc = b1v;
    #pragma unroll
    for (int k = 0; k < 16; ++k) acc = fmaf(S[n][k] * rinv, w1r[k], acc);
    base[n * C8 + tk] = acc;
  }
}

// ---------------- fused row dots: a_o (8192 rows) then a_m (512 rows) ----------------
__global__ void rowdot2(const float* __restrict__ X1, const float* __restrict__ a1,
                        float* __restrict__ o1, int R1,
                        const float* __restrict__ X2, const float* __restrict__ a2,
                        float* __restrict__ o2, int R2) {
  int wid = (blockIdx.x * blockDim.x + threadIdx.x) >> 6;
  int lane = threadIdx.x & 63;
  const float* X; const float* al; float* out; int r;
  if (wid < R1)            { X = X1; al = a1; out = o1; r = wid; }
  else if (wid < R1 + R2)  { X = X2; al = a2; out = o2; r = wid - R1; }
  else return;
  const float* row = X + (long)r * 128;
  float v = fmaf(row[lane], al[lane], row[lane + 64] * al[lane + 64]);
  #pragma unroll
  for (int off = 32; off; off >>= 1) v += __shfl_down(v, off);
  if (lane == 0) out[r] = v;
}

// ---------------- GAT per (b,m): 512 threads, one o per thread; 4-way agg split ----------------
__global__ __launch_bounds__(512) void gat_kernel(
    const float* __restrict__ adj, const float* __restrict__ ao,
    const float* __restrict__ am, const float* __restrict__ hopeG,
    const float* __restrict__ hmac, float* __restrict__ hmacs) {
  __shared__ float al[NO];
  __shared__ float red8[8];
  __shared__ float part[4][128];
  const int b = blockIdx.y, m = blockIdx.x;
  const int tid = threadIdx.x;            // 512 = 8 waves; o = tid
  const int lane = tid & 63, w = tid >> 6;
  const float amv = am[b * NM + m];
  const float a = adj[(b * NO + tid) * NM + m];
  float e = ao[b * NO + tid] + amv;
  e = (e >= 0.f) ? e : 0.2f * e;
  float mx = (a == 1.0f) ? e : -1e30f;
  #pragma unroll
  for (int off = 32; off; off >>= 1) mx = fmaxf(mx, __shfl_down(mx, off));
  if (lane == 0) red8[w] = mx;
  __syncthreads();
  if (tid == 0) {
    float mm2 = red8[0];
    #pragma unroll
    for (int k = 1; k < 8; ++k) mm2 = fmaxf(mm2, red8[k]);
    red8[0] = mm2;
  }
  __syncthreads();
  mx = red8[0];
  __syncthreads();
  const float p = (a == 1.0f) ? __expf(e - mx) : 0.f;
  float s = p;
  #pragma unroll
  for (int off = 32; off; off >>= 1) s += __shfl_down(s, off);
  if (lane == 0) red8[w] = s;
  __syncthreads();
  if (tid == 0) {
    float ss = 0.f;
    #pragma unroll
    for (int k = 0; k < 8; ++k) ss += red8[k];
    red8[0] = ss;
  }
  __syncthreads();
  s = red8[0];
  const float sinv = (s > 0.f) ? 1.0f / s : 0.f;
  al[tid] = p * sinv;
  __syncthreads();
  // aggregation: og-quarter of o-range, d = channel
  const int d = tid & 127, og = tid >> 7;
  float acc = 0.f;
  const float* hb = hopeG + ((long)(b * NO) + og * 128) * DOC + d;
  #pragma unroll 4
  for (int i = 0; i < 128; ++i)
    acc = fmaf(al[og * 128 + i], hb[(long)i * DOC], acc);
  part[og][d] = acc;
  __syncthreads();
  if (og == 0)
    hmacs[(b * NM + m) * DOC + d] = part[0][d] + part[1][d] + part[2][d] + part[3][d]
                                   + hmac[(b * NM + m) * DOC + d];
}

// ---------------- fused mean-pools (blocks 0-15: hopes->po, 16-31: hmacs->pm) ----------------
__global__ __launch_bounds__(512) void pool2_kernel(const float* __restrict__ hopes,
                                                    const float* __restrict__ hmacs,
                                                    float* __restrict__ po,
                                                    float* __restrict__ pm) {
  __shared__ float part[4][128];
  int bb = blockIdx.x;
  const float* X; float* out; int R; float inv;
  if (bb < 16) { X = hopes; out = po; R = 512; inv = 1.0f / 512.0f; }
  else         { X = hmacs; out = pm; R = 32;  inv = 1.0f / 32.0f; bb -= 16; }
  const int d = threadIdx.x & 127, g = threadIdx.x >> 7;
  const int per = R >> 2;
  float acc = 0.f;
  for (int r = g * per; r < (g + 1) * per; ++r) acc += X[(bb * R + r) * 128 + d];
  part[g][d] = acc;
  __syncthreads();
  if (g == 0)
    out[bb * 128 + d] = (part[0][d] + part[1][d] + part[2][d] + part[3][d]) * inv;
}

// ---------------- folded U_m ----------------
__global__ __launch_bounds__(128) void um_kernel(
    const float* __restrict__ hmacs, const float* __restrict__ po,
    const float* __restrict__ pm, const float* __restrict__ A0,
    const float* __restrict__ Ab0, float* __restrict__ um) {
  __shared__ float v[384];
  const int b = blockIdx.y, m = blockIdx.x;
  const int j = threadIdx.x;
  v[j] = hmacs[(b * NM + m) * 128 + j];
  v[128 + j] = po[b * 128 + j];
  v[256 + j] = pm[b * 128 + j];
  __syncthreads();
  const float* a = A0 + j * 512 + 128;
  float acc = Ab0[j];
  for (int k = 0; k < 384; ++k) acc = fmaf(a[k], v[k], acc);
  um[(b * NM + m) * 128 + j] = acc;
}

// ---------------- actor v5: v3 structure (proven XCD locality) + cvt_pk packing ----------------
// a-frag: row=lane&15, k=(lane>>4)*8+e; B-frag from A1p (L2-resident 32 KB);
// D: col=lane&15, row=(lane>>4)*4+reg (all verified r6/r11).
__global__ __launch_bounds__(256) void actor_mfma5_kernel(
    const float* __restrict__ Uo, const float* __restrict__ Um,
    const short* __restrict__ A1p, const float* __restrict__ Ab1,
    const float* __restrict__ A2, const float* __restrict__ Ab2,
    float* __restrict__ logits) {
  const int tid = threadIdx.x;
  const int rbase = blockIdx.x * 64;       // flat row = b*16384 + m*512 + o
  const int b = rbase >> 14;
  const int m = (rbase & 16383) >> 9;
  const int obase = rbase & 511;
  const int lane = tid & 63, w = tid >> 6;
  const int rowl = lane & 15, kg = lane >> 4;
  const float* uo = Uo + (long)(b * NO + obase + w * 16 + rowl) * 128;
  const float* umb = Um + (b * NM + m) * 128;
  bf16x8 af[4];
  #pragma unroll
  for (int kk = 0; kk < 4; ++kk) {
    int kb = kk * 32 + kg * 8;
    f32x4 u0 = *(const f32x4*)(uo + kb);
    f32x4 u1 = *(const f32x4*)(uo + kb + 4);
    f32x4 m0 = *(const f32x4*)(umb + kb);
    f32x4 m1 = *(const f32x4*)(umb + kb + 4);
    float t[8];
    #pragma unroll
    for (int e = 0; e < 4; ++e) t[e]     = fast_tanh(u0[e] + m0[e]);
    #pragma unroll
    for (int e = 0; e < 4; ++e) t[4 + e] = fast_tanh(u1[e] + m1[e]);
    af[kk] = pack8f(t);
  }
  float partrow[4] = {0.f, 0.f, 0.f, 0.f};
  #pragma unroll
  for (int ct = 0; ct < 8; ++ct) {
    const int col = ct * 16 + rowl;
    f32x4 acc = {0.f, 0.f, 0.f, 0.f};
    #pragma unroll
    for (int kk = 0; kk < 4; ++kk) {
      bf16x8 bf = *(const bf16x8*)(A1p + ((kk * 4 + kg) * 128 + col) * 8);
      acc = __builtin_amdgcn_mfma_f32_16x16x32_bf16(af[kk], bf, acc, 0, 0, 0);
    }
    const float ab = Ab1[col], a2c = A2[col];
    #pragma unroll
    for (int r = 0; r < 4; ++r) {
      float z2 = fast_tanh(acc[r] + ab);
      partrow[r] = fmaf(a2c, z2, partrow[r]);
    }
  }
  const float ab2 = Ab2[0];
  #pragma unroll
  for (int r = 0; r < 4; ++r) {
    float v = partrow[r];
    #pragma unroll
    for (int off = 1; off < 16; off <<= 1) v += __shfl_xor(v, off);
    if (rowl == 0) logits[rbase + w * 16 + kg * 4 + r] = v + ab2;
  }
}

// ---------------- masked log-softmax + gather + entropy (1024 threads) ----------------
__global__ __launch_bounds__(1024) void final_kernel(
    const float* __restrict__ logits, const void* __restrict__ maskp,
    const int* __restrict__ aidx, const int* __restrict__ flag,
    float* __restrict__ out) {
  __shared__ float sc[16], sc2[16];
  const int b = blockIdx.x;
  const int tid = threadIdx.x;
  const int lane = tid & 63, w = tid >> 6;
  const bool word_mode = (flag[0] == 0);
  const unsigned int* mw = (const unsigned int*)maskp;
  const unsigned char* mb = (const unsigned char*)maskp;
  const float* lg = logits + b * (NM * NO);
  float mx = -1e30f;
  for (int s = 0; s < 16; ++s) {
    int i = s * 1024 + tid;
    int o = i & 511, mm = i >> 9;
    int mofs = (b * NO + o) * NM + mm;
    bool msk = word_mode ? (mw[mofs] != 0u) : (mb[mofs] != 0);
    if (msk) mx = fmaxf(mx, lg[i]);
  }
  #pragma unroll
  for (int off = 32; off; off >>= 1) mx = fmaxf(mx, __shfl_down(mx, off));
  if (lane == 0) sc[w] = mx;
  __syncthreads();
  if (tid == 0) {
    float m2 = sc[0];
    for (int k = 1; k < 16; ++k) m2 = fmaxf(m2, sc[k]);
    sc[0] = m2;
  }
  __syncthreads();
  mx = sc[0];
  __syncthreads();
  float S = 0.f, T = 0.f;
  for (int s = 0; s < 16; ++s) {
    int i = s * 1024 + tid;
    int o = i & 511, mm = i >> 9;
    int mofs = (b * NO + o) * NM + mm;
    bool msk = word_mode ? (mw[mofs] != 0u) : (mb[mofs] != 0);
    if (msk) {
      float d = lg[i] - mx;
      float e = __expf(d);
      S += e;
      T = fmaf(e, d, T);
    }
  }
  #pragma unroll
  for (int off = 32; off; off >>= 1) { S += __shfl_down(S, off); T += __shfl_down(T, off); }
  if (lane == 0) { sc[w] = S; sc2[w] = T; }
  __syncthreads();
  if (tid == 0) {
    float St = 0.f, Tt = 0.f;
    for (int k = 0; k < 16; ++k) { St += sc[k]; Tt += sc2[k]; }
    float lS = logf(St);
    out[b] = lg[aidx[b]] - mx - lS;          // action_logprobs
    out[32 + b] = lS - Tt / St;              // dist_entropys
  }
}

// ---------------- critic MLP (per batch) ----------------
__global__ __launch_bounds__(128) void critic_kernel(
    const float* __restrict__ po, const float* __restrict__ pm,
    const float* __restrict__ C0, const float* __restrict__ Cb0,
    const float* __restrict__ C1, const float* __restrict__ Cb1,
    const float* __restrict__ C2, const float* __restrict__ Cb2,
    float* __restrict__ out) {
  __shared__ float v[256];
  __shared__ float z[128];
  __shared__ float sc[2];
  const int b = blockIdx.x;
  const int j = threadIdx.x;
  v[j] = po[b * 128 + j];
  v[128 + j] = pm[b * 128 + j];
  __syncthreads();
  float acc = Cb0[j];
  for (int k = 0; k < 256; ++k) acc = fmaf(C0[j * 256 + k], v[k], acc);
  z[j] = fast_tanh(acc);
  __syncthreads();
  acc = Cb1[j];
  for (int k = 0; k < 128; ++k) acc = fmaf(C1[j * 128 + k], z[k], acc);
  float z2 = fast_tanh(acc);
  float p = C2[j] * z2;
  #pragma unroll
  for (int off = 32; off; off >>= 1) p += __shfl_down(p, off);
  const int lane = j & 63, w = j >> 6;
  if (lane == 0) sc[w] = p;
  __syncthreads();
  if (j == 0) out[16 + b] = sc[0] + sc[1] + Cb2[0];   // state_values
}

extern "C" void kernel_launch(void* const* d_in, const int* in_sizes, int n_in,
                              void* d_out, int out_size, void* d_ws, size_t ws_size,
                              hipStream_t stream) {
  (void)in_sizes; (void)n_in; (void)out_size; (void)ws_size;
  const float* adj  = (const float*)d_in[0];
  const float* nop  = (const float*)d_in[1];
  const float* nmac = (const float*)d_in[2];
  const void*  maskp = d_in[3];
  const int*   aidx = (const int*)d_in[4];
  const float* Wtr  = (const float*)d_in[5];
  const float* btr  = (const float*)d_in[6];
  const float* W0   = (const float*)d_in[7];
  const float* b0   = (const float*)d_in[8];
  const float* W1   = (const float*)d_in[9];
  const float* b1   = (const float*)d_in[10];
  const float* Wp   = (const float*)d_in[11];
  const float* bp   = (const float*)d_in[12];
  const float* Wo   = (const float*)d_in[13];
  const float* Wm   = (const float*)d_in[14];
  const float* alo  = (const float*)d_in[15];
  const float* alm  = (const float*)d_in[16];
  const float* A0   = (const float*)d_in[17];
  const float* Ab0  = (const float*)d_in[18];
  const float* A1   = (const float*)d_in[19];
  const float* Ab1  = (const float*)d_in[20];
  const float* A2   = (const float*)d_in[21];
  const float* Ab2  = (const float*)d_in[22];
  const float* C0   = (const float*)d_in[23];
  const float* Cb0  = (const float*)d_in[24];
  const float* C1   = (const float*)d_in[25];
  const float* Cb1  = (const float*)d_in[26];
  const float* C2   = (const float*)d_in[27];
  const float* Cb2  = (const float*)d_in[28];

  float* ws     = (float*)d_ws;        // needs ~41 MiB
  float* x12    = ws + OFF_X12;
  float* hopes  = ws + OFF_HOPES;
  float* hopeG  = ws + OFF_HOPEG;
  float* hmac   = ws + OFF_HMAC;
  float* hmacs  = ws + OFF_HMACS;
  float* ao     = ws + OFF_AO;
  float* am     = ws + OFF_AM;
  float* po     = ws + OFF_PO;
  float* pm     = ws + OFF_PM;
  float* Uo     = ws + OFF_UO;
  float* Um     = ws + OFF_UM;
  float* logits = ws + OFF_LOG;
  short* A1p    = (short*)(ws + OFF_A1P);
  int*   flag   = (int*)(ws + OFF_FLAG);
  float* outp   = (float*)d_out;

  probe_mask_kernel<<<1, 256, 0, stream>>>((const unsigned int*)maskp, flag);

  // external attention
  gemm_wave<2><<<dim3(16, 64), 256, 0, stream>>>(nop, Wtr, btr, x12, 1024, 128, 128, 128);
  attn_kernel<<<dim3(NH, BB), 256, 0, stream>>>(x12, W0, b0, W1, b1);
  gemm_wave<1><<<dim3(2, 128), 256, 0, stream>>>(x12, Wp, bp, hopes, 128, 1024, 1024, 1024);

  // A1 -> bf16 (after x12's last read; A1p lives in dead x12 region)
  convert_a1_kernel<<<64, 256, 0, stream>>>(A1, A1p);

  // GAT
  gemm_wave<1><<<dim3(2, 128), 256, 0, stream>>>(nop, Wo, nullptr, hopeG, 128, 128, 128, 128);
  gemm_xt<<<dim3(2, 8), 256, 0, stream>>>(nmac, Wm, nullptr, hmac, 512, 128, 64, 64, 64);
  rowdot2<<<2176, 256, 0, stream>>>(hopeG, alo, ao, 8192, hmac, alm, am, 512);
  gat_kernel<<<dim3(NM, BB), 512, 0, stream>>>(adj, ao, am, hopeG, hmac, hmacs);

  // pooling (fused)
  pool2_kernel<<<32, 512, 0, stream>>>(hopes, hmacs, po, pm);

  // actor (Uo aliases x12's region — x12 is dead after the proj GEMM above)
  gemm_wave<1><<<dim3(2, 128), 256, 0, stream>>>(hopes, A0, nullptr, Uo, 128, 128, 128, 512);
  um_kernel<<<dim3(NM, BB), 128, 0, stream>>>(hmacs, po, pm, A0, Ab0, Um);
  actor_mfma5_kernel<<<4096, 256, 0, stream>>>(Uo, Um, A1p, Ab1, A2, Ab2, logits);
  final_kernel<<<16, 1024, 0, stream>>>(logits, maskp, aidx, flag, outp);

  // critic
  critic_kernel<<<16, 128, 0, stream>>>(po, pm, C0, Cb0, C1, Cb1, C2, Cb2, outp);
}

// Round 14
// 242.141 us; speedup vs baseline: 1.2862x; 1.1444x over previous
//
#include <hip/hip_runtime.h>

#define BB 16
#define NO 512
#define NM 32
#define DOC 128
#define C8 1024
#define NH 64
#define KD 16

// ---------------- ws layout (float offsets), ~41 MiB total ----------------
#define OFF_X12   0          // [16*512,1024]  x1/x2 of ext-attn (in-place)
#define OFF_UO    0          // [8192,128] (alias: x12 dead by then)
#define OFF_LOG   1048576    // [16,16384] (alias, after Uo)
#define OFF_A1P   2000000    // [16384] bf16 (8192 floats) A1 pre-converted (alias, dead x12)
#define OFF_HOPES 8388608    // [8192,128] ext-attn output
#define OFF_HOPEG 9437184    // [8192,128] GAT h_ope
#define OFF_HMAC  10485760   // [512,128]  GAT h_mac (pre)
#define OFF_HMACS 10551296   // [512,128]  GAT output
#define OFF_AO    10616832   // [8192]
#define OFF_AM    10625024   // [512]
#define OFF_PO    10625536   // [16,128]
#define OFF_PM    10627584   // [16,128]
#define OFF_UM    10629632   // [512,128]  folded U_m + U_p + Ab0
#define OFF_FLAG  10695168   // int flag (mask dtype probe)
#define OFF_PART  10695680   // [16,16,3]  final-softmax partials (M,S,T)

using f32x4  = __attribute__((ext_vector_type(4))) float;
using s16x4  = __attribute__((ext_vector_type(4))) short;
using bf16x8 = __attribute__((ext_vector_type(8))) short;   // 8 bf16 (4 VGPRs)

__device__ __forceinline__ float fast_tanh(float x) {
  x = fminf(15.0f, fmaxf(-15.0f, x));
  float e = __expf(2.0f * x);
  return 1.0f - 2.0f * __builtin_amdgcn_rcpf(e + 1.0f);
}

__device__ __forceinline__ short f2bf(float f) {          // RNE f32->bf16
  unsigned u = __builtin_bit_cast(unsigned, f);
  u += 0x7FFFu + ((u >> 16) & 1u);
  return (short)(u >> 16);
}

// packed bf16 convert via HW op: dword = {lo=cvt(a), hi=cvt(b)}
__device__ __forceinline__ unsigned cvtpk(float a, float b) {
  unsigned r;
  asm("v_cvt_pk_bf16_f32 %0, %1, %2" : "=v"(r) : "v"(a), "v"(b));
  return r;
}

__device__ __forceinline__ bf16x8 pack8(f32x4 u0, f32x4 u1) {
  union { unsigned u[4]; bf16x8 v; } cv;
  cv.u[0] = cvtpk(u0[0], u0[1]);
  cv.u[1] = cvtpk(u0[2], u0[3]);
  cv.u[2] = cvtpk(u1[0], u1[1]);
  cv.u[3] = cvtpk(u1[2], u1[3]);
  return cv.v;
}

__device__ __forceinline__ bf16x8 pack8f(const float* t) {
  union { unsigned u[4]; bf16x8 v; } cv;
  cv.u[0] = cvtpk(t[0], t[1]);
  cv.u[1] = cvtpk(t[2], t[3]);
  cv.u[2] = cvtpk(t[4], t[5]);
  cv.u[3] = cvtpk(t[6], t[7]);
  return cv.v;
}

// ---------------- mask dtype probe ----------------
__global__ void probe_mask_kernel(const unsigned int* __restrict__ mask,
                                  int* __restrict__ flag) {
  __shared__ int s[4];
  int bad = 0;
  for (int i = threadIdx.x; i < 4096; i += 256) {
    unsigned int v = mask[i];
    if (!(v == 0u || v == 1u || v == 0x3f800000u)) bad = 1;
  }
  unsigned long long any = __ballot(bad);
  int lane = threadIdx.x & 63, w = threadIdx.x >> 6;
  if (lane == 0) s[w] = (any != 0ull) ? 1 : 0;
  __syncthreads();
  if (threadIdx.x == 0) flag[0] = s[0] | s[1] | s[2] | s[3];
}

// ---------------- A1 f32 -> bf16, B-fragment layout: A1p[(k>>3)*128+col][e=k&7] ----------------
__global__ void convert_a1_kernel(const float* __restrict__ A1, short* __restrict__ A1p) {
  int tid = blockIdx.x * 256 + threadIdx.x;     // 64 blocks x 256 = 16384
  int col = tid >> 7, k = tid & 127;
  A1p[((k >> 3) * 128 + col) * 8 + (k & 7)] = f2bf(A1[tid]);
}

// ---------------- per-wave no-LDS bf16 MFMA GEMM ----------------
template<int MT>
__device__ __forceinline__ void loadk(const float* xb, const float* wb,
                                      long sx, long sw, int k0,
                                      f32x4 (&xa)[MT][2], f32x4 (&wa)[4][2]) {
  #pragma unroll
  for (int mi = 0; mi < MT; ++mi) {
    xa[mi][0] = *(const f32x4*)(xb + mi * sx + k0);
    xa[mi][1] = *(const f32x4*)(xb + mi * sx + k0 + 4);
  }
  #pragma unroll
  for (int ni = 0; ni < 4; ++ni) {
    wa[ni][0] = *(const f32x4*)(wb + ni * sw + k0);
    wa[ni][1] = *(const f32x4*)(wb + ni * sw + k0 + 4);
  }
}

template<int MT>
__device__ __forceinline__ void consume(f32x4 (&xa)[MT][2], f32x4 (&wa)[4][2],
                                        f32x4 (&acc)[MT][4]) {
  bf16x8 bfr[4];
  #pragma unroll
  for (int ni = 0; ni < 4; ++ni) bfr[ni] = pack8(wa[ni][0], wa[ni][1]);
  #pragma unroll
  for (int mi = 0; mi < MT; ++mi) {
    bf16x8 af = pack8(xa[mi][0], xa[mi][1]);
    #pragma unroll
    for (int ni = 0; ni < 4; ++ni)
      acc[mi][ni] = __builtin_amdgcn_mfma_f32_16x16x32_bf16(af, bfr[ni], acc[mi][ni], 0, 0, 0);
  }
}

template<int MT>
__global__ __launch_bounds__(256) void gemm_wave(
    const float* __restrict__ X, const float* __restrict__ W,
    const float* __restrict__ bias, float* __restrict__ C,
    int N, int Kdim, int ldx, int ldw) {
  const int tid = threadIdx.x;
  const int lane = tid & 63, w = tid >> 6;
  const int rowl = lane & 15, kg = lane >> 4;
  const int n0 = blockIdx.x * 64;
  const int m0 = (blockIdx.y * 4 + w) * (MT * 16);
  const float* xb = X + (long)(m0 + rowl) * ldx + kg * 8;
  const float* wb = W + (long)(n0 + rowl) * ldw + kg * 8;
  const long sx = (long)16 * ldx, sw = (long)16 * ldw;
  f32x4 acc[MT][4] = {};
  f32x4 A0[MT][2], B0[4][2], A1[MT][2], B1[4][2];
  loadk<MT>(xb, wb, sx, sw, 0, A0, B0);
  for (int k = 0; k < Kdim; k += 64) {
    loadk<MT>(xb, wb, sx, sw, k + 32, A1, B1);
    consume<MT>(A0, B0, acc);
    if (k + 64 < Kdim) loadk<MT>(xb, wb, sx, sw, k + 64, A0, B0);
    consume<MT>(A1, B1, acc);
  }
  #pragma unroll
  for (int mi = 0; mi < MT; ++mi) {
    #pragma unroll
    for (int ni = 0; ni < 4; ++ni) {
      int col = n0 + ni * 16 + rowl;
      float bv = bias ? bias[col] : 0.0f;
      int rb = m0 + mi * 16 + kg * 4;
      #pragma unroll
      for (int r = 0; r < 4; ++r)
        C[(long)(rb + r) * N + col] = acc[mi][ni][r] + bv;
    }
  }
}

// ---------------- external attention middle: per (b,h) slice, in place on x12 ----------------
__global__ __launch_bounds__(256) void attn_kernel(
    float* __restrict__ x12,
    const float* __restrict__ W0, const float* __restrict__ b0,
    const float* __restrict__ W1, const float* __restrict__ b1) {
  __shared__ float S[NO][KD + 1];
  __shared__ float red[16][17];
  __shared__ float colmax[16], colsum[16];
  __shared__ float rs[NO];
  const int b = blockIdx.y, h = blockIdx.x;
  const int tid = threadIdx.x;
  const int tk = tid & 15, tg = tid >> 4;
  float* base = x12 + (b * NO) * C8 + h * KD;
  #pragma unroll
  for (int l = 0; l < 32; ++l) {
    int f = l * 256 + tid;
    int n = f >> 4, k = f & 15;
    S[n][k] = base[n * C8 + k];
  }
  __syncthreads();
  float w0r[16];
  #pragma unroll
  for (int k = 0; k < 16; ++k) w0r[k] = W0[tk * 16 + k];
  const float b0v = b0[tk];
  float Areg[32];
  for (int i = 0; i < 32; ++i) {
    int n = tg + 16 * i;
    float acc = b0v;
    #pragma unroll
    for (int k = 0; k < 16; ++k) acc = fmaf(S[n][k], w0r[k], acc);
    Areg[i] = acc;
  }
  __syncthreads();
  for (int i = 0; i < 32; ++i) { int n = tg + 16 * i; S[n][tk] = Areg[i]; }
  __syncthreads();
  float mx = -1e30f;
  for (int i = 0; i < 32; ++i) mx = fmaxf(mx, Areg[i]);
  red[tg][tk] = mx;
  __syncthreads();
  if (tg == 0) {
    float mm = red[0][tk];
    for (int g = 1; g < 16; ++g) mm = fmaxf(mm, red[g][tk]);
    colmax[tk] = mm;
  }
  __syncthreads();
  const float cm = colmax[tk];
  float s = 0.f;
  for (int i = 0; i < 32; ++i) { float e = __expf(Areg[i] - cm); Areg[i] = e; s += e; }
  __syncthreads();
  red[tg][tk] = s;
  __syncthreads();
  if (tg == 0) {
    float ss = 0.f;
    for (int g = 0; g < 16; ++g) ss += red[g][tk];
    colsum[tk] = ss;
  }
  __syncthreads();
  const float inv = 1.0f / colsum[tk];
  for (int i = 0; i < 32; ++i) { int n = tg + 16 * i; S[n][tk] = Areg[i] * inv; }
  __syncthreads();
  #pragma unroll
  for (int rr = 0; rr < 2; ++rr) {
    int n = tid * 2 + rr;
    float t = 0.f;
    #pragma unroll
    for (int k = 0; k < 16; ++k) t += S[n][k];
    rs[n] = t;
  }
  __syncthreads();
  float w1r[16];
  #pragma unroll
  for (int k = 0; k < 16; ++k) w1r[k] = W1[tk * 16 + k];
  const float b1v = b1[tk];
  for (int i = 0; i < 32; ++i) {
    int n = tg + 16 * i;
    float rinv = 1.0f / (1e-10f + rs[n]);
    float acc = b1v;
    #pragma unroll
    for (int k = 0; k < 16; ++k) acc = fmaf(S[n][k] * rinv, w1r[k], acc);
    base[n * C8 + tk] = acc;
  }
}

// ---------------- fused row dots: a_o (8192 rows) then a_m (512 rows) ----------------
__global__ void rowdot2(const float* __restrict__ X1, const float* __restrict__ a1,
                        float* __restrict__ o1, int R1,
                        const float* __restrict__ X2, const float* __restrict__ a2,
                        float* __restrict__ o2, int R2) {
  int wid = (blockIdx.x * blockDim.x + threadIdx.x) >> 6;
  int lane = threadIdx.x & 63;
  const float* X; const float* al; float* out; int r;
  if (wid < R1)            { X = X1; al = a1; out = o1; r = wid; }
  else if (wid < R1 + R2)  { X = X2; al = a2; out = o2; r = wid - R1; }
  else return;
  const float* row = X + (long)r * 128;
  float v = fmaf(row[lane], al[lane], row[lane + 64] * al[lane + 64]);
  #pragma unroll
  for (int off = 32; off; off >>= 1) v += __shfl_down(v, off);
  if (lane == 0) out[r] = v;
}

// ---------------- GAT per (b,m): 512 threads, one o per thread; 4-way agg split ----------------
__global__ __launch_bounds__(512) void gat_kernel(
    const float* __restrict__ adj, const float* __restrict__ ao,
    const float* __restrict__ am, const float* __restrict__ hopeG,
    const float* __restrict__ hmac, float* __restrict__ hmacs) {
  __shared__ float al[NO];
  __shared__ float red8[8];
  __shared__ float part[4][128];
  const int b = blockIdx.y, m = blockIdx.x;
  const int tid = threadIdx.x;            // 512 = 8 waves; o = tid
  const int lane = tid & 63, w = tid >> 6;
  const float amv = am[b * NM + m];
  const float a = adj[(b * NO + tid) * NM + m];
  float e = ao[b * NO + tid] + amv;
  e = (e >= 0.f) ? e : 0.2f * e;
  float mx = (a == 1.0f) ? e : -1e30f;
  #pragma unroll
  for (int off = 32; off; off >>= 1) mx = fmaxf(mx, __shfl_down(mx, off));
  if (lane == 0) red8[w] = mx;
  __syncthreads();
  if (tid == 0) {
    float mm2 = red8[0];
    #pragma unroll
    for (int k = 1; k < 8; ++k) mm2 = fmaxf(mm2, red8[k]);
    red8[0] = mm2;
  }
  __syncthreads();
  mx = red8[0];
  __syncthreads();
  const float p = (a == 1.0f) ? __expf(e - mx) : 0.f;
  float s = p;
  #pragma unroll
  for (int off = 32; off; off >>= 1) s += __shfl_down(s, off);
  if (lane == 0) red8[w] = s;
  __syncthreads();
  if (tid == 0) {
    float ss = 0.f;
    #pragma unroll
    for (int k = 0; k < 8; ++k) ss += red8[k];
    red8[0] = ss;
  }
  __syncthreads();
  s = red8[0];
  const float sinv = (s > 0.f) ? 1.0f / s : 0.f;
  al[tid] = p * sinv;
  __syncthreads();
  // aggregation: og-quarter of o-range, d = channel
  const int d = tid & 127, og = tid >> 7;
  float acc = 0.f;
  const float* hb = hopeG + ((long)(b * NO) + og * 128) * DOC + d;
  #pragma unroll 4
  for (int i = 0; i < 128; ++i)
    acc = fmaf(al[og * 128 + i], hb[(long)i * DOC], acc);
  part[og][d] = acc;
  __syncthreads();
  if (og == 0)
    hmacs[(b * NM + m) * DOC + d] = part[0][d] + part[1][d] + part[2][d] + part[3][d]
                                   + hmac[(b * NM + m) * DOC + d];
}

// ---------------- fused mean-pools (blocks 0-15: hopes->po, 16-31: hmacs->pm) ----------------
__global__ __launch_bounds__(512) void pool2_kernel(const float* __restrict__ hopes,
                                                    const float* __restrict__ hmacs,
                                                    float* __restrict__ po,
                                                    float* __restrict__ pm) {
  __shared__ float part[4][128];
  int bb = blockIdx.x;
  const float* X; float* out; int R; float inv;
  if (bb < 16) { X = hopes; out = po; R = 512; inv = 1.0f / 512.0f; }
  else         { X = hmacs; out = pm; R = 32;  inv = 1.0f / 32.0f; bb -= 16; }
  const int d = threadIdx.x & 127, g = threadIdx.x >> 7;
  const int per = R >> 2;
  float acc = 0.f;
  for (int r = g * per; r < (g + 1) * per; ++r) acc += X[(bb * R + r) * 128 + d];
  part[g][d] = acc;
  __syncthreads();
  if (g == 0)
    out[bb * 128 + d] = (part[0][d] + part[1][d] + part[2][d] + part[3][d]) * inv;
}

// ---------------- folded U_m ----------------
__global__ __launch_bounds__(128) void um_kernel(
    const float* __restrict__ hmacs, const float* __restrict__ po,
    const float* __restrict__ pm, const float* __restrict__ A0,
    const float* __restrict__ Ab0, float* __restrict__ um) {
  __shared__ float v[384];
  const int b = blockIdx.y, m = blockIdx.x;
  const int j = threadIdx.x;
  v[j] = hmacs[(b * NM + m) * 128 + j];
  v[128 + j] = po[b * 128 + j];
  v[256 + j] = pm[b * 128 + j];
  __syncthreads();
  const float* a = A0 + j * 512 + 128;
  float acc = Ab0[j];
  for (int k = 0; k < 384; ++k) acc = fmaf(a[k], v[k], acc);
  um[(b * NM + m) * 128 + j] = acc;
}

// ---------------- actor v6: 2-m interleave (2x tanh ILP, B-frag reuse) ----------------
// grid 2048 = (b*16+mp)*8 + oc  -> oc in low 3 bits preserves v3/v5 XCD locality.
// a-frag: row=lane&15, k=(lane>>4)*8+e; B-frag col=lane&15; D col=lane&15,
// row=(lane>>4)*4+reg (verified r6/r11).
__global__ __launch_bounds__(256) void actor_mfma6_kernel(
    const float* __restrict__ Uo, const float* __restrict__ Um,
    const short* __restrict__ A1p, const float* __restrict__ Ab1,
    const float* __restrict__ A2, const float* __restrict__ Ab2,
    float* __restrict__ logits) {
  const int tid = threadIdx.x;
  const int blk = blockIdx.x;
  const int oc = blk & 7;
  const int mp = (blk >> 3) & 15;
  const int b  = blk >> 7;
  const int obase = oc * 64;
  const int m0 = mp * 2;
  const int lane = tid & 63, w = tid >> 6;
  const int rowl = lane & 15, kg = lane >> 4;
  const float* uo = Uo + (long)(b * NO + obase + w * 16 + rowl) * 128;
  // Uo slice -> registers (reused for both m)
  f32x4 uor[8];
  #pragma unroll
  for (int kk = 0; kk < 4; ++kk) {
    uor[kk * 2]     = *(const f32x4*)(uo + kk * 32 + kg * 8);
    uor[kk * 2 + 1] = *(const f32x4*)(uo + kk * 32 + kg * 8 + 4);
  }
  const float* um0 = Um + (b * NM + m0) * 128;
  const float* um1 = um0 + 128;
  bf16x8 af0[4], af1[4];
  #pragma unroll
  for (int kk = 0; kk < 4; ++kk) {
    int kb = kk * 32 + kg * 8;
    f32x4 a0 = *(const f32x4*)(um0 + kb);
    f32x4 a1 = *(const f32x4*)(um0 + kb + 4);
    f32x4 c0 = *(const f32x4*)(um1 + kb);
    f32x4 c1 = *(const f32x4*)(um1 + kb + 4);
    float t0[8], t1[8];
    #pragma unroll
    for (int e = 0; e < 4; ++e) {           // interleave the two chains
      t0[e]     = fast_tanh(uor[kk * 2][e] + a0[e]);
      t1[e]     = fast_tanh(uor[kk * 2][e] + c0[e]);
      t0[4 + e] = fast_tanh(uor[kk * 2 + 1][e] + a1[e]);
      t1[4 + e] = fast_tanh(uor[kk * 2 + 1][e] + c1[e]);
    }
    af0[kk] = pack8f(t0);
    af1[kk] = pack8f(t1);
  }
  float pr0[4] = {0.f, 0.f, 0.f, 0.f};
  float pr1[4] = {0.f, 0.f, 0.f, 0.f};
  #pragma unroll
  for (int ct = 0; ct < 8; ++ct) {
    const int col = ct * 16 + rowl;
    bf16x8 bf[4];
    #pragma unroll
    for (int kk = 0; kk < 4; ++kk)
      bf[kk] = *(const bf16x8*)(A1p + ((kk * 4 + kg) * 128 + col) * 8);
    f32x4 ac0 = {0.f, 0.f, 0.f, 0.f};
    f32x4 ac1 = {0.f, 0.f, 0.f, 0.f};
    #pragma unroll
    for (int kk = 0; kk < 4; ++kk) {
      ac0 = __builtin_amdgcn_mfma_f32_16x16x32_bf16(af0[kk], bf[kk], ac0, 0, 0, 0);
      ac1 = __builtin_amdgcn_mfma_f32_16x16x32_bf16(af1[kk], bf[kk], ac1, 0, 0, 0);
    }
    const float ab = Ab1[col], a2c = A2[col];
    #pragma unroll
    for (int r = 0; r < 4; ++r) {
      float z0 = fast_tanh(ac0[r] + ab);
      float z1 = fast_tanh(ac1[r] + ab);
      pr0[r] = fmaf(a2c, z0, pr0[r]);
      pr1[r] = fmaf(a2c, z1, pr1[r]);
    }
  }
  const float ab2 = Ab2[0];
  const long base0 = ((long)b << 14) + (long)m0 * 512 + obase + w * 16 + kg * 4;
  #pragma unroll
  for (int r = 0; r < 4; ++r) {
    float v0 = pr0[r], v1 = pr1[r];
    #pragma unroll
    for (int off = 1; off < 16; off <<= 1) {
      v0 += __shfl_xor(v0, off);
      v1 += __shfl_xor(v1, off);
    }
    if (rowl == 0) {
      logits[base0 + r] = v0 + ab2;
      logits[base0 + 512 + r] = v1 + ab2;
    }
  }
}

// ---------------- masked softmax phase 1: per (b, chunk) partial {M, S, T} ----------------
__global__ __launch_bounds__(1024) void final_part1(
    const float* __restrict__ logits, const void* __restrict__ maskp,
    const int* __restrict__ flag, float* __restrict__ part) {
  __shared__ float sm[16];
  const int b = blockIdx.x, c = blockIdx.y;
  const int tid = threadIdx.x;
  const int lane = tid & 63, w = tid >> 6;
  const bool word_mode = (flag[0] == 0);
  const unsigned int* mw = (const unsigned int*)maskp;
  const unsigned char* mb = (const unsigned char*)maskp;
  const int i = c * 1024 + tid;              // flat m*512+o index
  const int o = i & 511, mm = i >> 9;
  const int mofs = (b * NO + o) * NM + mm;
  const bool msk = word_mode ? (mw[mofs] != 0u) : (mb[mofs] != 0);
  const float x = logits[b * (NM * NO) + i];
  float mx = msk ? x : -1e30f;
  #pragma unroll
  for (int off = 32; off; off >>= 1) mx = fmaxf(mx, __shfl_down(mx, off));
  if (lane == 0) sm[w] = mx;
  __syncthreads();
  if (tid == 0) {
    float m2 = sm[0];
    #pragma unroll
    for (int k = 1; k < 16; ++k) m2 = fmaxf(m2, sm[k]);
    sm[0] = m2;
  }
  __syncthreads();
  const float M = sm[0];
  float S = 0.f, T = 0.f;
  if (msk) {
    float d = x - M;
    float e = __expf(d);
    S = e; T = e * d;
  }
  #pragma unroll
  for (int off = 32; off; off >>= 1) { S += __shfl_down(S, off); T += __shfl_down(T, off); }
  __syncthreads();                      // reuse sm
  __shared__ float ss[16], st[16];
  if (lane == 0) { ss[w] = S; st[w] = T; }
  __syncthreads();
  if (tid == 0) {
    float St = 0.f, Tt = 0.f;
    #pragma unroll
    for (int k = 0; k < 16; ++k) { St += ss[k]; Tt += st[k]; }
    float* pp = part + (b * 16 + c) * 3;
    pp[0] = M; pp[1] = St; pp[2] = Tt;
  }
}

// ---------------- masked softmax phase 2: combine 16 partials per b ----------------
__global__ __launch_bounds__(64) void final_part2(
    const float* __restrict__ part, const float* __restrict__ logits,
    const int* __restrict__ aidx, float* __restrict__ out) {
  const int b = blockIdx.x;
  const int lane = threadIdx.x;              // 1 wave
  float lm = -3e30f, lS = 0.f, lT = 0.f;
  if (lane < 16) {
    const float* pp = part + (b * 16 + lane) * 3;
    lm = pp[0]; lS = pp[1]; lT = pp[2];
  }
  float M = lm;
  #pragma unroll
  for (int off = 8; off; off >>= 1) M = fmaxf(M, __shfl_xor(M, off, 16));
  // w = exp(lm - M); rescale
  float wgt = (lane < 16) ? __expf(lm - M) : 0.f;
  float S = wgt * lS;
  float T = wgt * (lT + (lm - M) * lS);
  #pragma unroll
  for (int off = 8; off; off >>= 1) {
    S += __shfl_xor(S, off, 16);
    T += __shfl_xor(T, off, 16);
  }
  if (lane == 0) {
    float lSm = logf(S);
    out[b] = logits[b * (NM * NO) + aidx[b]] - M - lSm;   // action_logprobs
    out[32 + b] = lSm - T / S;                            // dist_entropys
  }
}

// ---------------- critic MLP (per batch) ----------------
__global__ __launch_bounds__(128) void critic_kernel(
    const float* __restrict__ po, const float* __restrict__ pm,
    const float* __restrict__ C0, const float* __restrict__ Cb0,
    const float* __restrict__ C1, const float* __restrict__ Cb1,
    const float* __restrict__ C2, const float* __restrict__ Cb2,
    float* __restrict__ out) {
  __shared__ float v[256];
  __shared__ float z[128];
  __shared__ float sc[2];
  const int b = blockIdx.x;
  const int j = threadIdx.x;
  v[j] = po[b * 128 + j];
  v[128 + j] = pm[b * 128 + j];
  __syncthreads();
  float acc = Cb0[j];
  for (int k = 0; k < 256; ++k) acc = fmaf(C0[j * 256 + k], v[k], acc);
  z[j] = fast_tanh(acc);
  __syncthreads();
  acc = Cb1[j];
  for (int k = 0; k < 128; ++k) acc = fmaf(C1[j * 128 + k], z[k], acc);
  float z2 = fast_tanh(acc);
  float p = C2[j] * z2;
  #pragma unroll
  for (int off = 32; off; off >>= 1) p += __shfl_down(p, off);
  const int lane = j & 63, w = j >> 6;
  if (lane == 0) sc[w] = p;
  __syncthreads();
  if (j == 0) out[16 + b] = sc[0] + sc[1] + Cb2[0];   // state_values
}

extern "C" void kernel_launch(void* const* d_in, const int* in_sizes, int n_in,
                              void* d_out, int out_size, void* d_ws, size_t ws_size,
                              hipStream_t stream) {
  (void)in_sizes; (void)n_in; (void)out_size; (void)ws_size;
  const float* adj  = (const float*)d_in[0];
  const float* nop  = (const float*)d_in[1];
  const float* nmac = (const float*)d_in[2];
  const void*  maskp = d_in[3];
  const int*   aidx = (const int*)d_in[4];
  const float* Wtr  = (const float*)d_in[5];
  const float* btr  = (const float*)d_in[6];
  const float* W0   = (const float*)d_in[7];
  const float* b0   = (const float*)d_in[8];
  const float* W1   = (const float*)d_in[9];
  const float* b1   = (const float*)d_in[10];
  const float* Wp   = (const float*)d_in[11];
  const float* bp   = (const float*)d_in[12];
  const float* Wo   = (const float*)d_in[13];
  const float* Wm   = (const float*)d_in[14];
  const float* alo  = (const float*)d_in[15];
  const float* alm  = (const float*)d_in[16];
  const float* A0   = (const float*)d_in[17];
  const float* Ab0  = (const float*)d_in[18];
  const float* A1   = (const float*)d_in[19];
  const float* Ab1  = (const float*)d_in[20];
  const float* A2   = (const float*)d_in[21];
  const float* Ab2  = (const float*)d_in[22];
  const float* C0   = (const float*)d_in[23];
  const float* Cb0  = (const float*)d_in[24];
  const float* C1   = (const float*)d_in[25];
  const float* Cb1  = (const float*)d_in[26];
  const float* C2   = (const float*)d_in[27];
  const float* Cb2  = (const float*)d_in[28];

  float* ws     = (float*)d_ws;        // needs ~41 MiB
  float* x12    = ws + OFF_X12;
  float* hopes  = ws + OFF_HOPES;
  float* hopeG  = ws + OFF_HOPEG;
  float* hmac   = ws + OFF_HMAC;
  float* hmacs  = ws + OFF_HMACS;
  float* ao     = ws + OFF_AO;
  float* am     = ws + OFF_AM;
  float* po     = ws + OFF_PO;
  float* pm     = ws + OFF_PM;
  float* Uo     = ws + OFF_UO;
  float* Um     = ws + OFF_UM;
  float* logits = ws + OFF_LOG;
  short* A1p    = (short*)(ws + OFF_A1P);
  int*   flag   = (int*)(ws + OFF_FLAG);
  float* partb  = ws + OFF_PART;
  float* outp   = (float*)d_out;

  probe_mask_kernel<<<1, 256, 0, stream>>>((const unsigned int*)maskp, flag);

  // external attention
  gemm_wave<2><<<dim3(16, 64), 256, 0, stream>>>(nop, Wtr, btr, x12, 1024, 128, 128, 128);
  attn_kernel<<<dim3(NH, BB), 256, 0, stream>>>(x12, W0, b0, W1, b1);
  gemm_wave<1><<<dim3(2, 128), 256, 0, stream>>>(x12, Wp, bp, hopes, 128, 1024, 1024, 1024);

  // A1 -> bf16 (after x12's last read; A1p lives in dead x12 region)
  convert_a1_kernel<<<64, 256, 0, stream>>>(A1, A1p);

  // GAT
  gemm_wave<1><<<dim3(2, 128), 256, 0, stream>>>(nop, Wo, nullptr, hopeG, 128, 128, 128, 128);
  gemm_wave<1><<<dim3(2, 8), 256, 0, stream>>>(nmac, Wm, nullptr, hmac, 128, 64, 64, 64);
  rowdot2<<<2176, 256, 0, stream>>>(hopeG, alo, ao, 8192, hmac, alm, am, 512);
  gat_kernel<<<dim3(NM, BB), 512, 0, stream>>>(adj, ao, am, hopeG, hmac, hmacs);

  // pooling (fused)
  pool2_kernel<<<32, 512, 0, stream>>>(hopes, hmacs, po, pm);

  // actor (Uo aliases x12's region — x12 is dead after the proj GEMM above)
  gemm_wave<1><<<dim3(2, 128), 256, 0, stream>>>(hopes, A0, nullptr, Uo, 128, 128, 128, 512);
  um_kernel<<<dim3(NM, BB), 128, 0, stream>>>(hmacs, po, pm, A0, Ab0, Um);
  actor_mfma6_kernel<<<2048, 256, 0, stream>>>(Uo, Um, A1p, Ab1, A2, Ab2, logits);
  final_part1<<<dim3(16, 16), 1024, 0, stream>>>(logits, maskp, flag, partb);
  final_part2<<<16, 64, 0, stream>>>(partb, logits, aidx, outp);

  // critic
  critic_kernel<<<16, 128, 0, stream>>>(po, pm, C0, Cb0, C1, Cb1, C2, Cb2, outp);
}

// Round 15
// 231.471 us; speedup vs baseline: 1.3455x; 1.0461x over previous
//
#include <hip/hip_runtime.h>

#define BB 16
#define NO 512
#define NM 32
#define DOC 128
#define C8 1024
#define NH 64
#define KD 16

// ---------------- ws layout (float offsets), ~41 MiB total ----------------
// x12h (bf16 h-sliced, 16 MB = float-slots [0, 4,194,304)) dies after proj;
// Uo/logits/A1p alias inside that region afterwards.
#define OFF_X12   0          // [16][64][512][16] bf16 h-sliced x1/x2 (in-place)
#define OFF_UO    0          // [8192,128] f32 (alias: x12h dead by then)
#define OFF_LOG   1048576    // [16,16384] (alias, after Uo)
#define OFF_A1P   2000000    // [16384] bf16 A1 pre-converted (alias, dead x12h)
#define OFF_HOPES 8388608    // [8192,128] ext-attn output
#define OFF_HOPEG 9437184    // [8192,128] GAT h_ope
#define OFF_HMAC  10485760   // [512,128]  GAT h_mac (pre)
#define OFF_HMACS 10551296   // [512,128]  GAT output
#define OFF_AO    10616832   // [8192]
#define OFF_AM    10625024   // [512]
#define OFF_PO    10625536   // [16,128]
#define OFF_PM    10627584   // [16,128]
#define OFF_UM    10629632   // [512,128]  folded U_m + U_p + Ab0
#define OFF_FLAG  10695168   // int flag (mask dtype probe)
#define OFF_PART  10695680   // [16,16,3]  final-softmax partials (M,S,T)

using f32x4  = __attribute__((ext_vector_type(4))) float;
using s16x4  = __attribute__((ext_vector_type(4))) short;
using bf16x8 = __attribute__((ext_vector_type(8))) short;   // 8 bf16 (4 VGPRs)

__device__ __forceinline__ float fast_tanh(float x) {
  x = fminf(15.0f, fmaxf(-15.0f, x));
  float e = __expf(2.0f * x);
  return 1.0f - 2.0f * __builtin_amdgcn_rcpf(e + 1.0f);
}

__device__ __forceinline__ short f2bf(float f) {          // RNE f32->bf16
  unsigned u = __builtin_bit_cast(unsigned, f);
  u += 0x7FFFu + ((u >> 16) & 1u);
  return (short)(u >> 16);
}

__device__ __forceinline__ float bf2f(short s) {
  return __builtin_bit_cast(float, ((unsigned)(unsigned short)s) << 16);
}

// packed bf16 convert via HW op: dword = {lo=cvt(a), hi=cvt(b)}
__device__ __forceinline__ unsigned cvtpk(float a, float b) {
  unsigned r;
  asm("v_cvt_pk_bf16_f32 %0, %1, %2" : "=v"(r) : "v"(a), "v"(b));
  return r;
}

__device__ __forceinline__ bf16x8 pack8(f32x4 u0, f32x4 u1) {
  union { unsigned u[4]; bf16x8 v; } cv;
  cv.u[0] = cvtpk(u0[0], u0[1]);
  cv.u[1] = cvtpk(u0[2], u0[3]);
  cv.u[2] = cvtpk(u1[0], u1[1]);
  cv.u[3] = cvtpk(u1[2], u1[3]);
  return cv.v;
}

__device__ __forceinline__ bf16x8 pack8f(const float* t) {
  union { unsigned u[4]; bf16x8 v; } cv;
  cv.u[0] = cvtpk(t[0], t[1]);
  cv.u[1] = cvtpk(t[2], t[3]);
  cv.u[2] = cvtpk(t[4], t[5]);
  cv.u[3] = cvtpk(t[6], t[7]);
  return cv.v;
}

// ---------------- mask dtype probe ----------------
__global__ void probe_mask_kernel(const unsigned int* __restrict__ mask,
                                  int* __restrict__ flag) {
  __shared__ int s[4];
  int bad = 0;
  for (int i = threadIdx.x; i < 4096; i += 256) {
    unsigned int v = mask[i];
    if (!(v == 0u || v == 1u || v == 0x3f800000u)) bad = 1;
  }
  unsigned long long any = __ballot(bad);
  int lane = threadIdx.x & 63, w = threadIdx.x >> 6;
  if (lane == 0) s[w] = (any != 0ull) ? 1 : 0;
  __syncthreads();
  if (threadIdx.x == 0) flag[0] = s[0] | s[1] | s[2] | s[3];
}

// ---------------- A1 f32 -> bf16, B-fragment layout: A1p[(k>>3)*128+col][e=k&7] ----------------
__global__ void convert_a1_kernel(const float* __restrict__ A1, short* __restrict__ A1p) {
  int tid = blockIdx.x * 256 + threadIdx.x;     // 64 blocks x 256 = 16384
  int col = tid >> 7, k = tid & 127;
  A1p[((k >> 3) * 128 + col) * 8 + (k & 7)] = f2bf(A1[tid]);
}

// ---------------- per-wave no-LDS bf16 MFMA GEMM (f32 in, f32 out) ----------------
template<int MT>
__device__ __forceinline__ void loadk(const float* xb, const float* wb,
                                      long sx, long sw, int k0,
                                      f32x4 (&xa)[MT][2], f32x4 (&wa)[4][2]) {
  #pragma unroll
  for (int mi = 0; mi < MT; ++mi) {
    xa[mi][0] = *(const f32x4*)(xb + mi * sx + k0);
    xa[mi][1] = *(const f32x4*)(xb + mi * sx + k0 + 4);
  }
  #pragma unroll
  for (int ni = 0; ni < 4; ++ni) {
    wa[ni][0] = *(const f32x4*)(wb + ni * sw + k0);
    wa[ni][1] = *(const f32x4*)(wb + ni * sw + k0 + 4);
  }
}

template<int MT>
__device__ __forceinline__ void consume(f32x4 (&xa)[MT][2], f32x4 (&wa)[4][2],
                                        f32x4 (&acc)[MT][4]) {
  bf16x8 bfr[4];
  #pragma unroll
  for (int ni = 0; ni < 4; ++ni) bfr[ni] = pack8(wa[ni][0], wa[ni][1]);
  #pragma unroll
  for (int mi = 0; mi < MT; ++mi) {
    bf16x8 af = pack8(xa[mi][0], xa[mi][1]);
    #pragma unroll
    for (int ni = 0; ni < 4; ++ni)
      acc[mi][ni] = __builtin_amdgcn_mfma_f32_16x16x32_bf16(af, bfr[ni], acc[mi][ni], 0, 0, 0);
  }
}

template<int MT>
__global__ __launch_bounds__(256) void gemm_wave(
    const float* __restrict__ X, const float* __restrict__ W,
    const float* __restrict__ bias, float* __restrict__ C,
    int N, int Kdim, int ldx, int ldw) {
  const int tid = threadIdx.x;
  const int lane = tid & 63, w = tid >> 6;
  const int rowl = lane & 15, kg = lane >> 4;
  const int n0 = blockIdx.x * 64;
  const int m0 = (blockIdx.y * 4 + w) * (MT * 16);
  const float* xb = X + (long)(m0 + rowl) * ldx + kg * 8;
  const float* wb = W + (long)(n0 + rowl) * ldw + kg * 8;
  const long sx = (long)16 * ldx, sw = (long)16 * ldw;
  f32x4 acc[MT][4] = {};
  f32x4 A0[MT][2], B0[4][2], A1[MT][2], B1[4][2];
  loadk<MT>(xb, wb, sx, sw, 0, A0, B0);
  for (int k = 0; k < Kdim; k += 64) {
    loadk<MT>(xb, wb, sx, sw, k + 32, A1, B1);
    consume<MT>(A0, B0, acc);
    if (k + 64 < Kdim) loadk<MT>(xb, wb, sx, sw, k + 64, A0, B0);
    consume<MT>(A1, B1, acc);
  }
  #pragma unroll
  for (int mi = 0; mi < MT; ++mi) {
    #pragma unroll
    for (int ni = 0; ni < 4; ++ni) {
      int col = n0 + ni * 16 + rowl;
      float bv = bias ? bias[col] : 0.0f;
      int rb = m0 + mi * 16 + kg * 4;
      #pragma unroll
      for (int r = 0; r < 4; ++r)
        C[(long)(rb + r) * N + col] = acc[mi][ni][r] + bv;
    }
  }
}

// ---------------- trans GEMM: f32 in, bf16 h-sliced out (x12h) ----------------
// Ch[((b*64+h)*512+n)*16+e], b=row>>9, n=row&511, h=col>>4, e=col&15.
template<int MT>
__global__ __launch_bounds__(256) void gemm_ht(
    const float* __restrict__ X, const float* __restrict__ W,
    const float* __restrict__ bias, short* __restrict__ Ch,
    int Kdim, int ldx, int ldw) {
  const int tid = threadIdx.x;
  const int lane = tid & 63, w = tid >> 6;
  const int rowl = lane & 15, kg = lane >> 4;
  const int n0 = blockIdx.x * 64;
  const int m0 = (blockIdx.y * 4 + w) * (MT * 16);
  const float* xb = X + (long)(m0 + rowl) * ldx + kg * 8;
  const float* wb = W + (long)(n0 + rowl) * ldw + kg * 8;
  const long sx = (long)16 * ldx, sw = (long)16 * ldw;
  f32x4 acc[MT][4] = {};
  f32x4 A0[MT][2], B0[4][2], A1[MT][2], B1[4][2];
  loadk<MT>(xb, wb, sx, sw, 0, A0, B0);
  for (int k = 0; k < Kdim; k += 64) {
    loadk<MT>(xb, wb, sx, sw, k + 32, A1, B1);
    consume<MT>(A0, B0, acc);
    if (k + 64 < Kdim) loadk<MT>(xb, wb, sx, sw, k + 64, A0, B0);
    consume<MT>(A1, B1, acc);
  }
  #pragma unroll
  for (int mi = 0; mi < MT; ++mi) {
    #pragma unroll
    for (int ni = 0; ni < 4; ++ni) {
      int col = n0 + ni * 16 + rowl;
      float bv = bias ? bias[col] : 0.0f;
      int h = col >> 4, e = col & 15;
      int rb = m0 + mi * 16 + kg * 4;
      #pragma unroll
      for (int r = 0; r < 4; ++r) {
        int rowI = rb + r;
        int b = rowI >> 9, n = rowI & 511;
        Ch[((long)(b * 64 + h) * 512 + n) * 16 + e] = f2bf(acc[mi][ni][r] + bv);
      }
    }
  }
}

// ---------------- proj GEMM: bf16 h-sliced X in, f32 out ----------------
// A-frags read directly as bf16 (no pack). M=8192, N=128, K=1024, ldw=1024.
__global__ __launch_bounds__(256) void gemm_hx(
    const short* __restrict__ Xh, const float* __restrict__ W,
    const float* __restrict__ bias, float* __restrict__ C) {
  const int tid = threadIdx.x;
  const int lane = tid & 63, w = tid >> 6;
  const int rowl = lane & 15, kg = lane >> 4;
  const int n0 = blockIdx.x * 64;
  const int m0 = (blockIdx.y * 4 + w) * 16;
  const int row = m0 + rowl, b = row >> 9, n = row & 511;
  const short* xb = Xh + (long)b * 524288 + (long)n * 16 + (kg & 1) * 8;
  const long hofs = kg >> 1;          // h = (k>>4) + hofs for k multiple of 32
  const float* wb = W + (long)(n0 + rowl) * 1024 + kg * 8;
  const long sw = 16 * 1024L;
  f32x4 acc[4] = {};
  bf16x8 A0, A1;
  f32x4 Wb0[4][2], Wb1[4][2];
  A0 = *(const bf16x8*)(xb + hofs * 8192);
  #pragma unroll
  for (int ni = 0; ni < 4; ++ni) {
    Wb0[ni][0] = *(const f32x4*)(wb + ni * sw);
    Wb0[ni][1] = *(const f32x4*)(wb + ni * sw + 4);
  }
  for (int k = 0; k < 1024; k += 64) {
    A1 = *(const bf16x8*)(xb + (((k + 32) >> 4) + hofs) * 8192);
    #pragma unroll
    for (int ni = 0; ni < 4; ++ni) {
      Wb1[ni][0] = *(const f32x4*)(wb + ni * sw + k + 32);
      Wb1[ni][1] = *(const f32x4*)(wb + ni * sw + k + 36);
    }
    #pragma unroll
    for (int ni = 0; ni < 4; ++ni) {
      bf16x8 bfr = pack8(Wb0[ni][0], Wb0[ni][1]);
      acc[ni] = __builtin_amdgcn_mfma_f32_16x16x32_bf16(A0, bfr, acc[ni], 0, 0, 0);
    }
    if (k + 64 < 1024) {
      A0 = *(const bf16x8*)(xb + (((k + 64) >> 4) + hofs) * 8192);
      #pragma unroll
      for (int ni = 0; ni < 4; ++ni) {
        Wb0[ni][0] = *(const f32x4*)(wb + ni * sw + k + 64);
        Wb0[ni][1] = *(const f32x4*)(wb + ni * sw + k + 68);
      }
    }
    #pragma unroll
    for (int ni = 0; ni < 4; ++ni) {
      bf16x8 bfr = pack8(Wb1[ni][0], Wb1[ni][1]);
      acc[ni] = __builtin_amdgcn_mfma_f32_16x16x32_bf16(A1, bfr, acc[ni], 0, 0, 0);
    }
  }
  #pragma unroll
  for (int ni = 0; ni < 4; ++ni) {
    int col = n0 + ni * 16 + rowl;
    float bv = bias ? bias[col] : 0.0f;
    int rb = m0 + kg * 4;
    #pragma unroll
    for (int r = 0; r < 4; ++r)
      C[(long)(rb + r) * 128 + col] = acc[ni][r] + bv;
  }
}

// ---------------- external attention middle: bf16 h-sliced slice, in place ----------------
__global__ __launch_bounds__(256) void attn2_kernel(
    short* __restrict__ x12h,
    const float* __restrict__ W0, const float* __restrict__ b0,
    const float* __restrict__ W1, const float* __restrict__ b1) {
  __shared__ float S[NO][KD + 1];
  __shared__ float red[16][17];
  __shared__ float colmax[16], colsum[16];
  __shared__ float rs[NO];
  const int b = blockIdx.y, h = blockIdx.x;
  const int tid = threadIdx.x;
  const int tk = tid & 15, tg = tid >> 4;
  short* slice = x12h + (long)(b * 64 + h) * 8192;
  #pragma unroll
  for (int it = 0; it < 4; ++it) {
    int idx = it * 2048 + tid * 8;
    bf16x8 v = *(const bf16x8*)(slice + idx);
    int n = idx >> 4, k = idx & 15;
    #pragma unroll
    for (int j = 0; j < 8; ++j) S[n][k + j] = bf2f(v[j]);
  }
  __syncthreads();
  float w0r[16];
  #pragma unroll
  for (int k = 0; k < 16; ++k) w0r[k] = W0[tk * 16 + k];
  const float b0v = b0[tk];
  float Areg[32];
  for (int i = 0; i < 32; ++i) {
    int n = tg + 16 * i;
    float acc = b0v;
    #pragma unroll
    for (int k = 0; k < 16; ++k) acc = fmaf(S[n][k], w0r[k], acc);
    Areg[i] = acc;
  }
  __syncthreads();
  for (int i = 0; i < 32; ++i) { int n = tg + 16 * i; S[n][tk] = Areg[i]; }
  __syncthreads();
  float mx = -1e30f;
  for (int i = 0; i < 32; ++i) mx = fmaxf(mx, Areg[i]);
  red[tg][tk] = mx;
  __syncthreads();
  if (tg == 0) {
    float mm = red[0][tk];
    for (int g = 1; g < 16; ++g) mm = fmaxf(mm, red[g][tk]);
    colmax[tk] = mm;
  }
  __syncthreads();
  const float cm = colmax[tk];
  float s = 0.f;
  for (int i = 0; i < 32; ++i) { float e = __expf(Areg[i] - cm); Areg[i] = e; s += e; }
  __syncthreads();
  red[tg][tk] = s;
  __syncthreads();
  if (tg == 0) {
    float ss = 0.f;
    for (int g = 0; g < 16; ++g) ss += red[g][tk];
    colsum[tk] = ss;
  }
  __syncthreads();
  const float inv = 1.0f / colsum[tk];
  for (int i = 0; i < 32; ++i) { int n = tg + 16 * i; S[n][tk] = Areg[i] * inv; }
  __syncthreads();
  #pragma unroll
  for (int rr = 0; rr < 2; ++rr) {
    int n = tid * 2 + rr;
    float t = 0.f;
    #pragma unroll
    for (int k = 0; k < 16; ++k) t += S[n][k];
    rs[n] = t;
  }
  __syncthreads();
  float w1r[16];
  #pragma unroll
  for (int k = 0; k < 16; ++k) w1r[k] = W1[tk * 16 + k];
  const float b1v = b1[tk];
  for (int i = 0; i < 32; ++i) {
    int n = tg + 16 * i;
    float rinv = 1.0f / (1e-10f + rs[n]);
    float acc = b1v;
    #pragma unroll
    for (int k = 0; k < 16; ++k) acc = fmaf(S[n][k] * rinv, w1r[k], acc);
    slice[n * 16 + tk] = f2bf(acc);
  }
}

// ---------------- fused row dots: a_o (8192 rows) then a_m (512 rows) ----------------
__global__ void rowdot2(const float* __restrict__ X1, const float* __restrict__ a1,
                        float* __restrict__ o1, int R1,
                        const float* __restrict__ X2, const float* __restrict__ a2,
                        float* __restrict__ o2, int R2) {
  int wid = (blockIdx.x * blockDim.x + threadIdx.x) >> 6;
  int lane = threadIdx.x & 63;
  const float* X; const float* al; float* out; int r;
  if (wid < R1)            { X = X1; al = a1; out = o1; r = wid; }
  else if (wid < R1 + R2)  { X = X2; al = a2; out = o2; r = wid - R1; }
  else return;
  const float* row = X + (long)r * 128;
  float v = fmaf(row[lane], al[lane], row[lane + 64] * al[lane + 64]);
  #pragma unroll
  for (int off = 32; off; off >>= 1) v += __shfl_down(v, off);
  if (lane == 0) out[r] = v;
}

// ---------------- GAT per (b,m): 512 threads, one o per thread; 4-way agg split ----------------
__global__ __launch_bounds__(512) void gat_kernel(
    const float* __restrict__ adj, const float* __restrict__ ao,
    const float* __restrict__ am, const float* __restrict__ hopeG,
    const float* __restrict__ hmac, float* __restrict__ hmacs) {
  __shared__ float al[NO];
  __shared__ float red8[8];
  __shared__ float part[4][128];
  const int b = blockIdx.y, m = blockIdx.x;
  const int tid = threadIdx.x;            // 512 = 8 waves; o = tid
  const int lane = tid & 63, w = tid >> 6;
  const float amv = am[b * NM + m];
  const float a = adj[(b * NO + tid) * NM + m];
  float e = ao[b * NO + tid] + amv;
  e = (e >= 0.f) ? e : 0.2f * e;
  float mx = (a == 1.0f) ? e : -1e30f;
  #pragma unroll
  for (int off = 32; off; off >>= 1) mx = fmaxf(mx, __shfl_down(mx, off));
  if (lane == 0) red8[w] = mx;
  __syncthreads();
  if (tid == 0) {
    float mm2 = red8[0];
    #pragma unroll
    for (int k = 1; k < 8; ++k) mm2 = fmaxf(mm2, red8[k]);
    red8[0] = mm2;
  }
  __syncthreads();
  mx = red8[0];
  __syncthreads();
  const float p = (a == 1.0f) ? __expf(e - mx) : 0.f;
  float s = p;
  #pragma unroll
  for (int off = 32; off; off >>= 1) s += __shfl_down(s, off);
  if (lane == 0) red8[w] = s;
  __syncthreads();
  if (tid == 0) {
    float ss = 0.f;
    #pragma unroll
    for (int k = 0; k < 8; ++k) ss += red8[k];
    red8[0] = ss;
  }
  __syncthreads();
  s = red8[0];
  const float sinv = (s > 0.f) ? 1.0f / s : 0.f;
  al[tid] = p * sinv;
  __syncthreads();
  const int d = tid & 127, og = tid >> 7;
  float acc = 0.f;
  const float* hb = hopeG + ((long)(b * NO) + og * 128) * DOC + d;
  #pragma unroll 4
  for (int i = 0; i < 128; ++i)
    acc = fmaf(al[og * 128 + i], hb[(long)i * DOC], acc);
  part[og][d] = acc;
  __syncthreads();
  if (og == 0)
    hmacs[(b * NM + m) * DOC + d] = part[0][d] + part[1][d] + part[2][d] + part[3][d]
                                   + hmac[(b * NM + m) * DOC + d];
}

// ---------------- fused mean-pools (blocks 0-15: hopes->po, 16-31: hmacs->pm) ----------------
__global__ __launch_bounds__(512) void pool2_kernel(const float* __restrict__ hopes,
                                                    const float* __restrict__ hmacs,
                                                    float* __restrict__ po,
                                                    float* __restrict__ pm) {
  __shared__ float part[4][128];
  int bb = blockIdx.x;
  const float* X; float* out; int R; float inv;
  if (bb < 16) { X = hopes; out = po; R = 512; inv = 1.0f / 512.0f; }
  else         { X = hmacs; out = pm; R = 32;  inv = 1.0f / 32.0f; bb -= 16; }
  const int d = threadIdx.x & 127, g = threadIdx.x >> 7;
  const int per = R >> 2;
  float acc = 0.f;
  for (int r = g * per; r < (g + 1) * per; ++r) acc += X[(bb * R + r) * 128 + d];
  part[g][d] = acc;
  __syncthreads();
  if (g == 0)
    out[bb * 128 + d] = (part[0][d] + part[1][d] + part[2][d] + part[3][d]) * inv;
}

// ---------------- folded U_m ----------------
__global__ __launch_bounds__(128) void um_kernel(
    const float* __restrict__ hmacs, const float* __restrict__ po,
    const float* __restrict__ pm, const float* __restrict__ A0,
    const float* __restrict__ Ab0, float* __restrict__ um) {
  __shared__ float v[384];
  const int b = blockIdx.y, m = blockIdx.x;
  const int j = threadIdx.x;
  v[j] = hmacs[(b * NM + m) * 128 + j];
  v[128 + j] = po[b * 128 + j];
  v[256 + j] = pm[b * 128 + j];
  __syncthreads();
  const float* a = A0 + j * 512 + 128;
  float acc = Ab0[j];
  for (int k = 0; k < 384; ++k) acc = fmaf(a[k], v[k], acc);
  um[(b * NM + m) * 128 + j] = acc;
}

// ---------------- actor v6: 2-m interleave (r14: verified, 2048-block XCD locality) ----------------
__global__ __launch_bounds__(256) void actor_mfma6_kernel(
    const float* __restrict__ Uo, const float* __restrict__ Um,
    const short* __restrict__ A1p, const float* __restrict__ Ab1,
    const float* __restrict__ A2, const float* __restrict__ Ab2,
    float* __restrict__ logits) {
  const int tid = threadIdx.x;
  const int blk = blockIdx.x;
  const int oc = blk & 7;
  const int mp = (blk >> 3) & 15;
  const int b  = blk >> 7;
  const int obase = oc * 64;
  const int m0 = mp * 2;
  const int lane = tid & 63, w = tid >> 6;
  const int rowl = lane & 15, kg = lane >> 4;
  const float* uo = Uo + (long)(b * NO + obase + w * 16 + rowl) * 128;
  f32x4 uor[8];
  #pragma unroll
  for (int kk = 0; kk < 4; ++kk) {
    uor[kk * 2]     = *(const f32x4*)(uo + kk * 32 + kg * 8);
    uor[kk * 2 + 1] = *(const f32x4*)(uo + kk * 32 + kg * 8 + 4);
  }
  const float* um0 = Um + (b * NM + m0) * 128;
  const float* um1 = um0 + 128;
  bf16x8 af0[4], af1[4];
  #pragma unroll
  for (int kk = 0; kk < 4; ++kk) {
    int kb = kk * 32 + kg * 8;
    f32x4 a0 = *(const f32x4*)(um0 + kb);
    f32x4 a1 = *(const f32x4*)(um0 + kb + 4);
    f32x4 c0 = *(const f32x4*)(um1 + kb);
    f32x4 c1 = *(const f32x4*)(um1 + kb + 4);
    float t0[8], t1[8];
    #pragma unroll
    for (int e = 0; e < 4; ++e) {
      t0[e]     = fast_tanh(uor[kk * 2][e] + a0[e]);
      t1[e]     = fast_tanh(uor[kk * 2][e] + c0[e]);
      t0[4 + e] = fast_tanh(uor[kk * 2 + 1][e] + a1[e]);
      t1[4 + e] = fast_tanh(uor[kk * 2 + 1][e] + c1[e]);
    }
    af0[kk] = pack8f(t0);
    af1[kk] = pack8f(t1);
  }
  float pr0[4] = {0.f, 0.f, 0.f, 0.f};
  float pr1[4] = {0.f, 0.f, 0.f, 0.f};
  #pragma unroll
  for (int ct = 0; ct < 8; ++ct) {
    const int col = ct * 16 + rowl;
    bf16x8 bf[4];
    #pragma unroll
    for (int kk = 0; kk < 4; ++kk)
      bf[kk] = *(const bf16x8*)(A1p + ((kk * 4 + kg) * 128 + col) * 8);
    f32x4 ac0 = {0.f, 0.f, 0.f, 0.f};
    f32x4 ac1 = {0.f, 0.f, 0.f, 0.f};
    #pragma unroll
    for (int kk = 0; kk < 4; ++kk) {
      ac0 = __builtin_amdgcn_mfma_f32_16x16x32_bf16(af0[kk], bf[kk], ac0, 0, 0, 0);
      ac1 = __builtin_amdgcn_mfma_f32_16x16x32_bf16(af1[kk], bf[kk], ac1, 0, 0, 0);
    }
    const float ab = Ab1[col], a2c = A2[col];
    #pragma unroll
    for (int r = 0; r < 4; ++r) {
      float z0 = fast_tanh(ac0[r] + ab);
      float z1 = fast_tanh(ac1[r] + ab);
      pr0[r] = fmaf(a2c, z0, pr0[r]);
      pr1[r] = fmaf(a2c, z1, pr1[r]);
    }
  }
  const float ab2 = Ab2[0];
  const long base0 = ((long)b << 14) + (long)m0 * 512 + obase + w * 16 + kg * 4;
  #pragma unroll
  for (int r = 0; r < 4; ++r) {
    float v0 = pr0[r], v1 = pr1[r];
    #pragma unroll
    for (int off = 1; off < 16; off <<= 1) {
      v0 += __shfl_xor(v0, off);
      v1 += __shfl_xor(v1, off);
    }
    if (rowl == 0) {
      logits[base0 + r] = v0 + ab2;
      logits[base0 + 512 + r] = v1 + ab2;
    }
  }
}

// ---------------- masked softmax phase 1: per (b, chunk) partial {M, S, T} ----------------
__global__ __launch_bounds__(1024) void final_part1(
    const float* __restrict__ logits, const void* __restrict__ maskp,
    const int* __restrict__ flag, float* __restrict__ part) {
  __shared__ float sm[16];
  const int b = blockIdx.x, c = blockIdx.y;
  const int tid = threadIdx.x;
  const int lane = tid & 63, w = tid >> 6;
  const bool word_mode = (flag[0] == 0);
  const unsigned int* mw = (const unsigned int*)maskp;
  const unsigned char* mb = (const unsigned char*)maskp;
  const int i = c * 1024 + tid;
  const int o = i & 511, mm = i >> 9;
  const int mofs = (b * NO + o) * NM + mm;
  const bool msk = word_mode ? (mw[mofs] != 0u) : (mb[mofs] != 0);
  const float x = logits[b * (NM * NO) + i];
  float mx = msk ? x : -1e30f;
  #pragma unroll
  for (int off = 32; off; off >>= 1) mx = fmaxf(mx, __shfl_down(mx, off));
  if (lane == 0) sm[w] = mx;
  __syncthreads();
  if (tid == 0) {
    float m2 = sm[0];
    #pragma unroll
    for (int k = 1; k < 16; ++k) m2 = fmaxf(m2, sm[k]);
    sm[0] = m2;
  }
  __syncthreads();
  const float M = sm[0];
  float S = 0.f, T = 0.f;
  if (msk) {
    float d = x - M;
    float e = __expf(d);
    S = e; T = e * d;
  }
  #pragma unroll
  for (int off = 32; off; off >>= 1) { S += __shfl_down(S, off); T += __shfl_down(T, off); }
  __syncthreads();
  __shared__ float ss[16], st[16];
  if (lane == 0) { ss[w] = S; st[w] = T; }
  __syncthreads();
  if (tid == 0) {
    float St = 0.f, Tt = 0.f;
    #pragma unroll
    for (int k = 0; k < 16; ++k) { St += ss[k]; Tt += st[k]; }
    float* pp = part + (b * 16 + c) * 3;
    pp[0] = M; pp[1] = St; pp[2] = Tt;
  }
}

// ---------------- masked softmax phase 2: combine 16 partials per b ----------------
__global__ __launch_bounds__(64) void final_part2(
    const float* __restrict__ part, const float* __restrict__ logits,
    const int* __restrict__ aidx, float* __restrict__ out) {
  const int b = blockIdx.x;
  const int lane = threadIdx.x;
  float lm = -3e30f, lS = 0.f, lT = 0.f;
  if (lane < 16) {
    const float* pp = part + (b * 16 + lane) * 3;
    lm = pp[0]; lS = pp[1]; lT = pp[2];
  }
  float M = lm;
  #pragma unroll
  for (int off = 8; off; off >>= 1) M = fmaxf(M, __shfl_xor(M, off, 16));
  float wgt = (lane < 16) ? __expf(lm - M) : 0.f;
  float S = wgt * lS;
  float T = wgt * (lT + (lm - M) * lS);
  #pragma unroll
  for (int off = 8; off; off >>= 1) {
    S += __shfl_xor(S, off, 16);
    T += __shfl_xor(T, off, 16);
  }
  if (lane == 0) {
    float lSm = logf(S);
    out[b] = logits[b * (NM * NO) + aidx[b]] - M - lSm;   // action_logprobs
    out[32 + b] = lSm - T / S;                            // dist_entropys
  }
}

// ---------------- critic MLP (per batch) ----------------
__global__ __launch_bounds__(128) void critic_kernel(
    const float* __restrict__ po, const float* __restrict__ pm,
    const float* __restrict__ C0, const float* __restrict__ Cb0,
    const float* __restrict__ C1, const float* __restrict__ Cb1,
    const float* __restrict__ C2, const float* __restrict__ Cb2,
    float* __restrict__ out) {
  __shared__ float v[256];
  __shared__ float z[128];
  __shared__ float sc[2];
  const int b = blockIdx.x;
  const int j = threadIdx.x;
  v[j] = po[b * 128 + j];
  v[128 + j] = pm[b * 128 + j];
  __syncthreads();
  float acc = Cb0[j];
  for (int k = 0; k < 256; ++k) acc = fmaf(C0[j * 256 + k], v[k], acc);
  z[j] = fast_tanh(acc);
  __syncthreads();
  acc = Cb1[j];
  for (int k = 0; k < 128; ++k) acc = fmaf(C1[j * 128 + k], z[k], acc);
  float z2 = fast_tanh(acc);
  float p = C2[j] * z2;
  #pragma unroll
  for (int off = 32; off; off >>= 1) p += __shfl_down(p, off);
  const int lane = j & 63, w = j >> 6;
  if (lane == 0) sc[w] = p;
  __syncthreads();
  if (j == 0) out[16 + b] = sc[0] + sc[1] + Cb2[0];   // state_values
}

extern "C" void kernel_launch(void* const* d_in, const int* in_sizes, int n_in,
                              void* d_out, int out_size, void* d_ws, size_t ws_size,
                              hipStream_t stream) {
  (void)in_sizes; (void)n_in; (void)out_size; (void)ws_size;
  const float* adj  = (const float*)d_in[0];
  const float* nop  = (const float*)d_in[1];
  const float* nmac = (const float*)d_in[2];
  const void*  maskp = d_in[3];
  const int*   aidx = (const int*)d_in[4];
  const float* Wtr  = (const float*)d_in[5];
  const float* btr  = (const float*)d_in[6];
  const float* W0   = (const float*)d_in[7];
  const float* b0   = (const float*)d_in[8];
  const float* W1   = (const float*)d_in[9];
  const float* b1   = (const float*)d_in[10];
  const float* Wp   = (const float*)d_in[11];
  const float* bp   = (const float*)d_in[12];
  const float* Wo   = (const float*)d_in[13];
  const float* Wm   = (const float*)d_in[14];
  const float* alo  = (const float*)d_in[15];
  const float* alm  = (const float*)d_in[16];
  const float* A0   = (const float*)d_in[17];
  const float* Ab0  = (const float*)d_in[18];
  const float* A1   = (const float*)d_in[19];
  const float* Ab1  = (const float*)d_in[20];
  const float* A2   = (const float*)d_in[21];
  const float* Ab2  = (const float*)d_in[22];
  const float* C0   = (const float*)d_in[23];
  const float* Cb0  = (const float*)d_in[24];
  const float* C1   = (const float*)d_in[25];
  const float* Cb1  = (const float*)d_in[26];
  const float* C2   = (const float*)d_in[27];
  const float* Cb2  = (const float*)d_in[28];

  float* ws     = (float*)d_ws;        // needs ~41 MiB
  short* x12h   = (short*)(ws + OFF_X12);
  float* hopes  = ws + OFF_HOPES;
  float* hopeG  = ws + OFF_HOPEG;
  float* hmac   = ws + OFF_HMAC;
  float* hmacs  = ws + OFF_HMACS;
  float* ao     = ws + OFF_AO;
  float* am     = ws + OFF_AM;
  float* po     = ws + OFF_PO;
  float* pm     = ws + OFF_PM;
  float* Uo     = ws + OFF_UO;
  float* Um     = ws + OFF_UM;
  float* logits = ws + OFF_LOG;
  short* A1p    = (short*)(ws + OFF_A1P);
  int*   flag   = (int*)(ws + OFF_FLAG);
  float* partb  = ws + OFF_PART;
  float* outp   = (float*)d_out;

  probe_mask_kernel<<<1, 256, 0, stream>>>((const unsigned int*)maskp, flag);

  // external attention (x12 now bf16 h-sliced)
  gemm_ht<2><<<dim3(16, 64), 256, 0, stream>>>(nop, Wtr, btr, x12h, 128, 128, 128);
  attn2_kernel<<<dim3(NH, BB), 256, 0, stream>>>(x12h, W0, b0, W1, b1);
  gemm_hx<<<dim3(2, 128), 256, 0, stream>>>(x12h, Wp, bp, hopes);

  // A1 -> bf16 (after x12h's last read; A1p lives in dead x12h region)
  convert_a1_kernel<<<64, 256, 0, stream>>>(A1, A1p);

  // GAT
  gemm_wave<1><<<dim3(2, 128), 256, 0, stream>>>(nop, Wo, nullptr, hopeG, 128, 128, 128, 128);
  gemm_wave<1><<<dim3(2, 8), 256, 0, stream>>>(nmac, Wm, nullptr, hmac, 128, 64, 64, 64);
  rowdot2<<<2176, 256, 0, stream>>>(hopeG, alo, ao, 8192, hmac, alm, am, 512);
  gat_kernel<<<dim3(NM, BB), 512, 0, stream>>>(adj, ao, am, hopeG, hmac, hmacs);

  // pooling (fused)
  pool2_kernel<<<32, 512, 0, stream>>>(hopes, hmacs, po, pm);

  // actor (Uo aliases x12h's region — dead after proj)
  gemm_wave<1><<<dim3(2, 128), 256, 0, stream>>>(hopes, A0, nullptr, Uo, 128, 128, 128, 512);
  um_kernel<<<dim3(NM, BB), 128, 0, stream>>>(hmacs, po, pm, A0, Ab0, Um);
  actor_mfma6_kernel<<<2048, 256, 0, stream>>>(Uo, Um, A1p, Ab1, A2, Ab2, logits);
  final_part1<<<dim3(16, 16), 1024, 0, stream>>>(logits, maskp, flag, partb);
  final_part2<<<16, 64, 0, stream>>>(partb, logits, aidx, outp);

  // critic
  critic_kernel<<<16, 128, 0, stream>>>(po, pm, C0, Cb0, C1, Cb1, C2, Cb2, outp);
}

// Round 17
// 224.586 us; speedup vs baseline: 1.3868x; 1.0307x over previous
//
#include <hip/hip_runtime.h>

#define BB 16
#define NO 512
#define NM 32
#define DOC 128
#define C8 1024
#define NH 64
#define KD 16

// ---------------- ws layout (float offsets), ~44 MiB used ----------------
// x12h (bf16 h-sliced) spans float-slots [0, 4,194,304); dies after proj.
// Uo/logits alias inside it afterwards. A1p/Xcat live OUTSIDE it (A1p is
// written by mega1 while x12h is still live!).
#define OFF_X12   0          // [16][64][512][16] bf16 h-sliced x1/x2 (in-place)
#define OFF_UO    0          // [8192,128] f32 (alias: x12h dead by then)
#define OFF_LOG   1048576    // [16,16384] (alias, after Uo)
#define OFF_HOPES 8388608    // [8192,128] ext-attn output
#define OFF_HOPEG 9437184    // [8192,128] GAT h_ope
#define OFF_HMAC  10485760   // [512,128]  GAT h_mac (pre)
#define OFF_HMACS 10551296   // [512,128]  GAT output
#define OFF_AO    10616832   // [8192]
#define OFF_AM    10625024   // [512]
#define OFF_PO    10625536   // [16,128]
#define OFF_PM    10627584   // [16,128]
#define OFF_UM    10629632   // [512,128]  folded U_m + U_p + Ab0
#define OFF_FLAG  10695168   // int flag (mask dtype probe)
#define OFF_PART  10695680   // [16,16,3]  final-softmax partials
#define OFF_XCAT  10700000   // [512,384] f32 concat(hmacs,po,pm)
#define OFF_A1P   10900000   // [16384] bf16 A1 pre-converted (OUTSIDE x12h!)

using f32x4  = __attribute__((ext_vector_type(4))) float;
using s16x4  = __attribute__((ext_vector_type(4))) short;
using bf16x8 = __attribute__((ext_vector_type(8))) short;   // 8 bf16 (4 VGPRs)

// clamp-free: exp(2x)->{0,inf} at extremes gives exactly -1/+1 via rcp
__device__ __forceinline__ float fast_tanh(float x) {
  float e = __expf(2.0f * x);
  return 1.0f - 2.0f * __builtin_amdgcn_rcpf(e + 1.0f);
}

__device__ __forceinline__ short f2bf(float f) {          // RNE f32->bf16
  unsigned u = __builtin_bit_cast(unsigned, f);
  u += 0x7FFFu + ((u >> 16) & 1u);
  return (short)(u >> 16);
}

__device__ __forceinline__ float bf2f(short s) {
  return __builtin_bit_cast(float, ((unsigned)(unsigned short)s) << 16);
}

__device__ __forceinline__ unsigned cvtpk(float a, float b) {
  unsigned r;
  asm("v_cvt_pk_bf16_f32 %0, %1, %2" : "=v"(r) : "v"(a), "v"(b));
  return r;
}

__device__ __forceinline__ bf16x8 pack8(f32x4 u0, f32x4 u1) {
  union { unsigned u[4]; bf16x8 v; } cv;
  cv.u[0] = cvtpk(u0[0], u0[1]);
  cv.u[1] = cvtpk(u0[2], u0[3]);
  cv.u[2] = cvtpk(u1[0], u1[1]);
  cv.u[3] = cvtpk(u1[2], u1[3]);
  return cv.v;
}

__device__ __forceinline__ bf16x8 pack8f(const float* t) {
  union { unsigned u[4]; bf16x8 v; } cv;
  cv.u[0] = cvtpk(t[0], t[1]);
  cv.u[1] = cvtpk(t[2], t[3]);
  cv.u[2] = cvtpk(t[4], t[5]);
  cv.u[3] = cvtpk(t[6], t[7]);
  return cv.v;
}

// ---------------- mask dtype probe ----------------
__global__ void probe_mask_kernel(const unsigned int* __restrict__ mask,
                                  int* __restrict__ flag) {
  __shared__ int s[4];
  int bad = 0;
  for (int i = threadIdx.x; i < 4096; i += 256) {
    unsigned int v = mask[i];
    if (!(v == 0u || v == 1u || v == 0x3f800000u)) bad = 1;
  }
  unsigned long long any = __ballot(bad);
  int lane = threadIdx.x & 63, w = threadIdx.x >> 6;
  if (lane == 0) s[w] = (any != 0ull) ? 1 : 0;
  __syncthreads();
  if (threadIdx.x == 0) flag[0] = s[0] | s[1] | s[2] | s[3];
}

// ---------------- GEMM bodies (verbatim from verified kernels, bx/by params) ----------------
template<int MT>
__device__ __forceinline__ void loadk(const float* xb, const float* wb,
                                      long sx, long sw, int k0,
                                      f32x4 (&xa)[MT][2], f32x4 (&wa)[4][2]) {
  #pragma unroll
  for (int mi = 0; mi < MT; ++mi) {
    xa[mi][0] = *(const f32x4*)(xb + mi * sx + k0);
    xa[mi][1] = *(const f32x4*)(xb + mi * sx + k0 + 4);
  }
  #pragma unroll
  for (int ni = 0; ni < 4; ++ni) {
    wa[ni][0] = *(const f32x4*)(wb + ni * sw + k0);
    wa[ni][1] = *(const f32x4*)(wb + ni * sw + k0 + 4);
  }
}

template<int MT>
__device__ __forceinline__ void consume(f32x4 (&xa)[MT][2], f32x4 (&wa)[4][2],
                                        f32x4 (&acc)[MT][4]) {
  bf16x8 bfr[4];
  #pragma unroll
  for (int ni = 0; ni < 4; ++ni) bfr[ni] = pack8(wa[ni][0], wa[ni][1]);
  #pragma unroll
  for (int mi = 0; mi < MT; ++mi) {
    bf16x8 af = pack8(xa[mi][0], xa[mi][1]);
    #pragma unroll
    for (int ni = 0; ni < 4; ++ni)
      acc[mi][ni] = __builtin_amdgcn_mfma_f32_16x16x32_bf16(af, bfr[ni], acc[mi][ni], 0, 0, 0);
  }
}

template<int MT>
__device__ void gemm_wave_body(int bx, int by, int tid,
    const float* __restrict__ X, const float* __restrict__ W,
    const float* __restrict__ bias, float* __restrict__ C,
    int N, int Kdim, int ldx, int ldw) {
  const int lane = tid & 63, w = tid >> 6;
  const int rowl = lane & 15, kg = lane >> 4;
  const int n0 = bx * 64;
  const int m0 = (by * 4 + w) * (MT * 16);
  const float* xb = X + (long)(m0 + rowl) * ldx + kg * 8;
  const float* wb = W + (long)(n0 + rowl) * ldw + kg * 8;
  const long sx = (long)16 * ldx, sw = (long)16 * ldw;
  f32x4 acc[MT][4] = {};
  f32x4 A0[MT][2], B0[4][2], A1[MT][2], B1[4][2];
  loadk<MT>(xb, wb, sx, sw, 0, A0, B0);
  for (int k = 0; k < Kdim; k += 64) {
    loadk<MT>(xb, wb, sx, sw, k + 32, A1, B1);
    consume<MT>(A0, B0, acc);
    if (k + 64 < Kdim) loadk<MT>(xb, wb, sx, sw, k + 64, A0, B0);
    consume<MT>(A1, B1, acc);
  }
  #pragma unroll
  for (int mi = 0; mi < MT; ++mi) {
    #pragma unroll
    for (int ni = 0; ni < 4; ++ni) {
      int col = n0 + ni * 16 + rowl;
      float bv = bias ? bias[col] : 0.0f;
      int rb = m0 + mi * 16 + kg * 4;
      #pragma unroll
      for (int r = 0; r < 4; ++r)
        C[(long)(rb + r) * N + col] = acc[mi][ni][r] + bv;
    }
  }
}

template<int MT>
__global__ __launch_bounds__(256) void gemm_wave(
    const float* __restrict__ X, const float* __restrict__ W,
    const float* __restrict__ bias, float* __restrict__ C,
    int N, int Kdim, int ldx, int ldw) {
  gemm_wave_body<MT>(blockIdx.x, blockIdx.y, threadIdx.x, X, W, bias, C, N, Kdim, ldx, ldw);
}

// trans GEMM body: f32 in, bf16 h-sliced out.
template<int MT>
__device__ void gemm_ht_body(int bx, int by, int tid,
    const float* __restrict__ X, const float* __restrict__ W,
    const float* __restrict__ bias, short* __restrict__ Ch,
    int Kdim, int ldx, int ldw) {
  const int lane = tid & 63, w = tid >> 6;
  const int rowl = lane & 15, kg = lane >> 4;
  const int n0 = bx * 64;
  const int m0 = (by * 4 + w) * (MT * 16);
  const float* xb = X + (long)(m0 + rowl) * ldx + kg * 8;
  const float* wb = W + (long)(n0 + rowl) * ldw + kg * 8;
  const long sx = (long)16 * ldx, sw = (long)16 * ldw;
  f32x4 acc[MT][4] = {};
  f32x4 A0[MT][2], B0[4][2], A1[MT][2], B1[4][2];
  loadk<MT>(xb, wb, sx, sw, 0, A0, B0);
  for (int k = 0; k < Kdim; k += 64) {
    loadk<MT>(xb, wb, sx, sw, k + 32, A1, B1);
    consume<MT>(A0, B0, acc);
    if (k + 64 < Kdim) loadk<MT>(xb, wb, sx, sw, k + 64, A0, B0);
    consume<MT>(A1, B1, acc);
  }
  #pragma unroll
  for (int mi = 0; mi < MT; ++mi) {
    #pragma unroll
    for (int ni = 0; ni < 4; ++ni) {
      int col = n0 + ni * 16 + rowl;
      float bv = bias ? bias[col] : 0.0f;
      int h = col >> 4, e = col & 15;
      int rb = m0 + mi * 16 + kg * 4;
      #pragma unroll
      for (int r = 0; r < 4; ++r) {
        int rowI = rb + r;
        int b = rowI >> 9, n = rowI & 511;
        Ch[((long)(b * 64 + h) * 512 + n) * 16 + e] = f2bf(acc[mi][ni][r] + bv);
      }
    }
  }
}

__device__ void convert_a1_body(int blk, int tid,
    const float* __restrict__ A1, short* __restrict__ A1p) {
  int i = blk * 256 + tid;
  int col = i >> 7, k = i & 127;
  A1p[((k >> 3) * 128 + col) * 8 + (k & 7)] = f2bf(A1[i]);
}

// ---------------- mega1: trans(1024) + hopeG(256) + hmac(16) + convertA1(64) ----------------
__global__ __launch_bounds__(256) void mega1_kernel(
    const float* __restrict__ nop, const float* __restrict__ Wtr,
    const float* __restrict__ btr, short* __restrict__ x12h,
    const float* __restrict__ Wo, float* __restrict__ hopeG,
    const float* __restrict__ nmac, const float* __restrict__ Wm,
    float* __restrict__ hmac,
    const float* __restrict__ A1, short* __restrict__ A1p) {
  const int blk = blockIdx.x, tid = threadIdx.x;
  if (blk < 1024) {
    gemm_ht_body<2>(blk & 15, blk >> 4, tid, nop, Wtr, btr, x12h, 128, 128, 128);
  } else if (blk < 1280) {
    int t = blk - 1024;
    gemm_wave_body<1>(t & 1, t >> 1, tid, nop, Wo, nullptr, hopeG, 128, 128, 128, 128);
  } else if (blk < 1296) {
    int t = blk - 1280;
    gemm_wave_body<1>(t & 1, t >> 1, tid, nmac, Wm, nullptr, hmac, 128, 64, 64, 64);
  } else {
    convert_a1_body(blk - 1296, tid, A1, A1p);
  }
}

// ---------------- attn body (verbatim attn2, b/h params) ----------------
__device__ void attn2_body(int b, int h, int tid, short* __restrict__ x12h,
    const float* __restrict__ W0, const float* __restrict__ b0,
    const float* __restrict__ W1, const float* __restrict__ b1) {
  __shared__ float S[NO][KD + 1];
  __shared__ float red[16][17];
  __shared__ float colmax[16], colsum[16];
  __shared__ float rs[NO];
  const int tk = tid & 15, tg = tid >> 4;
  short* slice = x12h + (long)(b * 64 + h) * 8192;
  #pragma unroll
  for (int it = 0; it < 4; ++it) {
    int idx = it * 2048 + tid * 8;
    bf16x8 v = *(const bf16x8*)(slice + idx);
    int n = idx >> 4, k = idx & 15;
    #pragma unroll
    for (int j = 0; j < 8; ++j) S[n][k + j] = bf2f(v[j]);
  }
  __syncthreads();
  float w0r[16];
  #pragma unroll
  for (int k = 0; k < 16; ++k) w0r[k] = W0[tk * 16 + k];
  const float b0v = b0[tk];
  float Areg[32];
  for (int i = 0; i < 32; ++i) {
    int n = tg + 16 * i;
    float acc = b0v;
    #pragma unroll
    for (int k = 0; k < 16; ++k) acc = fmaf(S[n][k], w0r[k], acc);
    Areg[i] = acc;
  }
  __syncthreads();
  for (int i = 0; i < 32; ++i) { int n = tg + 16 * i; S[n][tk] = Areg[i]; }
  __syncthreads();
  float mx = -1e30f;
  for (int i = 0; i < 32; ++i) mx = fmaxf(mx, Areg[i]);
  red[tg][tk] = mx;
  __syncthreads();
  if (tg == 0) {
    float mm = red[0][tk];
    for (int g = 1; g < 16; ++g) mm = fmaxf(mm, red[g][tk]);
    colmax[tk] = mm;
  }
  __syncthreads();
  const float cm = colmax[tk];
  float s = 0.f;
  for (int i = 0; i < 32; ++i) { float e = __expf(Areg[i] - cm); Areg[i] = e; s += e; }
  __syncthreads();
  red[tg][tk] = s;
  __syncthreads();
  if (tg == 0) {
    float ss = 0.f;
    for (int g = 0; g < 16; ++g) ss += red[g][tk];
    colsum[tk] = ss;
  }
  __syncthreads();
  const float inv = 1.0f / colsum[tk];
  for (int i = 0; i < 32; ++i) { int n = tg + 16 * i; S[n][tk] = Areg[i] * inv; }
  __syncthreads();
  #pragma unroll
  for (int rr = 0; rr < 2; ++rr) {
    int n = tid * 2 + rr;
    float t = 0.f;
    #pragma unroll
    for (int k = 0; k < 16; ++k) t += S[n][k];
    rs[n] = t;
  }
  __syncthreads();
  float w1r[16];
  #pragma unroll
  for (int k = 0; k < 16; ++k) w1r[k] = W1[tk * 16 + k];
  const float b1v = b1[tk];
  for (int i = 0; i < 32; ++i) {
    int n = tg + 16 * i;
    float rinv = 1.0f / (1e-10f + rs[n]);
    float acc = b1v;
    #pragma unroll
    for (int k = 0; k < 16; ++k) acc = fmaf(S[n][k] * rinv, w1r[k], acc);
    slice[n * 16 + tk] = f2bf(acc);
  }
}

// ---------------- mega2: attn2(1024) + rowdot2(2176) ----------------
__global__ __launch_bounds__(256) void mega2_kernel(
    short* __restrict__ x12h,
    const float* __restrict__ W0, const float* __restrict__ b0,
    const float* __restrict__ W1, const float* __restrict__ b1,
    const float* __restrict__ hopeG, const float* __restrict__ alo,
    float* __restrict__ ao,
    const float* __restrict__ hmac, const float* __restrict__ alm,
    float* __restrict__ am) {
  const int blk = blockIdx.x, tid = threadIdx.x;
  if (blk < 1024) {
    attn2_body(blk >> 6, blk & 63, tid, x12h, W0, b0, W1, b1);
  } else {
    int t = blk - 1024;
    int wid = t * 4 + (tid >> 6);
    int lane = tid & 63;
    const float* X; const float* al; float* out; int r;
    if (wid < 8192)       { X = hopeG; al = alo; out = ao; r = wid; }
    else if (wid < 8704)  { X = hmac;  al = alm; out = am; r = wid - 8192; }
    else return;
    const float* row = X + (long)r * 128;
    float v = fmaf(row[lane], al[lane], row[lane + 64] * al[lane + 64]);
    #pragma unroll
    for (int off = 32; off; off >>= 1) v += __shfl_down(v, off);
    if (lane == 0) out[r] = v;
  }
}

// ---------------- proj GEMM: bf16 h-sliced X in, f32 out ----------------
__global__ __launch_bounds__(256) void gemm_hx(
    const short* __restrict__ Xh, const float* __restrict__ W,
    const float* __restrict__ bias, float* __restrict__ C) {
  const int tid = threadIdx.x;
  const int lane = tid & 63, w = tid >> 6;
  const int rowl = lane & 15, kg = lane >> 4;
  const int n0 = blockIdx.x * 64;
  const int m0 = (blockIdx.y * 4 + w) * 16;
  const int row = m0 + rowl, b = row >> 9, n = row & 511;
  const short* xb = Xh + (long)b * 524288 + (long)n * 16 + (kg & 1) * 8;
  const long hofs = kg >> 1;
  const float* wb = W + (long)(n0 + rowl) * 1024 + kg * 8;
  const long sw = 16 * 1024L;
  f32x4 acc[4] = {};
  bf16x8 A0, A1;
  f32x4 Wb0[4][2], Wb1[4][2];
  A0 = *(const bf16x8*)(xb + hofs * 8192);
  #pragma unroll
  for (int ni = 0; ni < 4; ++ni) {
    Wb0[ni][0] = *(const f32x4*)(wb + ni * sw);
    Wb0[ni][1] = *(const f32x4*)(wb + ni * sw + 4);
  }
  for (int k = 0; k < 1024; k += 64) {
    A1 = *(const bf16x8*)(xb + (((k + 32) >> 4) + hofs) * 8192);
    #pragma unroll
    for (int ni = 0; ni < 4; ++ni) {
      Wb1[ni][0] = *(const f32x4*)(wb + ni * sw + k + 32);
      Wb1[ni][1] = *(const f32x4*)(wb + ni * sw + k + 36);
    }
    #pragma unroll
    for (int ni = 0; ni < 4; ++ni) {
      bf16x8 bfr = pack8(Wb0[ni][0], Wb0[ni][1]);
      acc[ni] = __builtin_amdgcn_mfma_f32_16x16x32_bf16(A0, bfr, acc[ni], 0, 0, 0);
    }
    if (k + 64 < 1024) {
      A0 = *(const bf16x8*)(xb + (((k + 64) >> 4) + hofs) * 8192);
      #pragma unroll
      for (int ni = 0; ni < 4; ++ni) {
        Wb0[ni][0] = *(const f32x4*)(wb + ni * sw + k + 64);
        Wb0[ni][1] = *(const f32x4*)(wb + ni * sw + k + 68);
      }
    }
    #pragma unroll
    for (int ni = 0; ni < 4; ++ni) {
      bf16x8 bfr = pack8(Wb1[ni][0], Wb1[ni][1]);
      acc[ni] = __builtin_amdgcn_mfma_f32_16x16x32_bf16(A1, bfr, acc[ni], 0, 0, 0);
    }
  }
  #pragma unroll
  for (int ni = 0; ni < 4; ++ni) {
    int col = n0 + ni * 16 + rowl;
    float bv = bias ? bias[col] : 0.0f;
    int rb = m0 + kg * 4;
    #pragma unroll
    for (int r = 0; r < 4; ++r)
      C[(long)(rb + r) * 128 + col] = acc[ni][r] + bv;
  }
}

// ---------------- GAT per (b,m): 512 threads (verified r12-r15) ----------------
__global__ __launch_bounds__(512) void gat_kernel(
    const float* __restrict__ adj, const float* __restrict__ ao,
    const float* __restrict__ am, const float* __restrict__ hopeG,
    const float* __restrict__ hmac, float* __restrict__ hmacs) {
  __shared__ float al[NO];
  __shared__ float red8[8];
  __shared__ float part[4][128];
  const int b = blockIdx.y, m = blockIdx.x;
  const int tid = threadIdx.x;
  const int lane = tid & 63, w = tid >> 6;
  const float amv = am[b * NM + m];
  const float a = adj[(b * NO + tid) * NM + m];
  float e = ao[b * NO + tid] + amv;
  e = (e >= 0.f) ? e : 0.2f * e;
  float mx = (a == 1.0f) ? e : -1e30f;
  #pragma unroll
  for (int off = 32; off; off >>= 1) mx = fmaxf(mx, __shfl_down(mx, off));
  if (lane == 0) red8[w] = mx;
  __syncthreads();
  if (tid == 0) {
    float mm2 = red8[0];
    #pragma unroll
    for (int k = 1; k < 8; ++k) mm2 = fmaxf(mm2, red8[k]);
    red8[0] = mm2;
  }
  __syncthreads();
  mx = red8[0];
  __syncthreads();
  const float p = (a == 1.0f) ? __expf(e - mx) : 0.f;
  float s = p;
  #pragma unroll
  for (int off = 32; off; off >>= 1) s += __shfl_down(s, off);
  if (lane == 0) red8[w] = s;
  __syncthreads();
  if (tid == 0) {
    float ss = 0.f;
    #pragma unroll
    for (int k = 0; k < 8; ++k) ss += red8[k];
    red8[0] = ss;
  }
  __syncthreads();
  s = red8[0];
  const float sinv = (s > 0.f) ? 1.0f / s : 0.f;
  al[tid] = p * sinv;
  __syncthreads();
  const int d = tid & 127, og = tid >> 7;
  float acc = 0.f;
  const float* hb = hopeG + ((long)(b * NO) + og * 128) * DOC + d;
  #pragma unroll 4
  for (int i = 0; i < 128; ++i)
    acc = fmaf(al[og * 128 + i], hb[(long)i * DOC], acc);
  part[og][d] = acc;
  __syncthreads();
  if (og == 0)
    hmacs[(b * NM + m) * DOC + d] = part[0][d] + part[1][d] + part[2][d] + part[3][d]
                                   + hmac[(b * NM + m) * DOC + d];
}

// ---------------- fused mean-pools ----------------
__global__ __launch_bounds__(512) void pool2_kernel(const float* __restrict__ hopes,
                                                    const float* __restrict__ hmacs,
                                                    float* __restrict__ po,
                                                    float* __restrict__ pm) {
  __shared__ float part[4][128];
  int bb = blockIdx.x;
  const float* X; float* out; int R; float inv;
  if (bb < 16) { X = hopes; out = po; R = 512; inv = 1.0f / 512.0f; }
  else         { X = hmacs; out = pm; R = 32;  inv = 1.0f / 32.0f; bb -= 16; }
  const int d = threadIdx.x & 127, g = threadIdx.x >> 7;
  const int per = R >> 2;
  float acc = 0.f;
  for (int r = g * per; r < (g + 1) * per; ++r) acc += X[(bb * R + r) * 128 + d];
  part[g][d] = acc;
  __syncthreads();
  if (g == 0)
    out[bb * 128 + d] = (part[0][d] + part[1][d] + part[2][d] + part[3][d]) * inv;
}

// ---------------- Xcat build: [512][384] = concat(hmacs, po, pm) ----------------
__global__ void xcat_kernel(const float* __restrict__ hmacs,
                            const float* __restrict__ po,
                            const float* __restrict__ pm,
                            float* __restrict__ xc) {
  int g = blockIdx.x * 256 + threadIdx.x;     // 49152 float4 groups
  int row = g / 96, c4 = g % 96;
  int b = row >> 5;
  f32x4 v;
  if (c4 < 32)      v = *(const f32x4*)(hmacs + (long)row * 128 + c4 * 4);
  else if (c4 < 64) v = *(const f32x4*)(po + b * 128 + (c4 - 32) * 4);
  else              v = *(const f32x4*)(pm + b * 128 + (c4 - 64) * 4);
  *(f32x4*)(xc + (long)row * 384 + c4 * 4) = v;
}

// ---------------- actor v6 (verified r14/r15) ----------------
__global__ __launch_bounds__(256) void actor_mfma6_kernel(
    const float* __restrict__ Uo, const float* __restrict__ Um,
    const short* __restrict__ A1p, const float* __restrict__ Ab1,
    const float* __restrict__ A2, const float* __restrict__ Ab2,
    float* __restrict__ logits) {
  const int tid = threadIdx.x;
  const int blk = blockIdx.x;
  const int oc = blk & 7;
  const int mp = (blk >> 3) & 15;
  const int b  = blk >> 7;
  const int obase = oc * 64;
  const int m0 = mp * 2;
  const int lane = tid & 63, w = tid >> 6;
  const int rowl = lane & 15, kg = lane >> 4;
  const float* uo = Uo + (long)(b * NO + obase + w * 16 + rowl) * 128;
  f32x4 uor[8];
  #pragma unroll
  for (int kk = 0; kk < 4; ++kk) {
    uor[kk * 2]     = *(const f32x4*)(uo + kk * 32 + kg * 8);
    uor[kk * 2 + 1] = *(const f32x4*)(uo + kk * 32 + kg * 8 + 4);
  }
  const float* um0 = Um + (b * NM + m0) * 128;
  const float* um1 = um0 + 128;
  bf16x8 af0[4], af1[4];
  #pragma unroll
  for (int kk = 0; kk < 4; ++kk) {
    int kb = kk * 32 + kg * 8;
    f32x4 a0 = *(const f32x4*)(um0 + kb);
    f32x4 a1 = *(const f32x4*)(um0 + kb + 4);
    f32x4 c0 = *(const f32x4*)(um1 + kb);
    f32x4 c1 = *(const f32x4*)(um1 + kb + 4);
    float t0[8], t1[8];
    #pragma unroll
    for (int e = 0; e < 4; ++e) {
      t0[e]     = fast_tanh(uor[kk * 2][e] + a0[e]);
      t1[e]     = fast_tanh(uor[kk * 2][e] + c0[e]);
      t0[4 + e] = fast_tanh(uor[kk * 2 + 1][e] + a1[e]);
      t1[4 + e] = fast_tanh(uor[kk * 2 + 1][e] + c1[e]);
    }
    af0[kk] = pack8f(t0);
    af1[kk] = pack8f(t1);
  }
  float pr0[4] = {0.f, 0.f, 0.f, 0.f};
  float pr1[4] = {0.f, 0.f, 0.f, 0.f};
  #pragma unroll
  for (int ct = 0; ct < 8; ++ct) {
    const int col = ct * 16 + rowl;
    bf16x8 bf[4];
    #pragma unroll
    for (int kk = 0; kk < 4; ++kk)
      bf[kk] = *(const bf16x8*)(A1p + ((kk * 4 + kg) * 128 + col) * 8);
    f32x4 ac0 = {0.f, 0.f, 0.f, 0.f};
    f32x4 ac1 = {0.f, 0.f, 0.f, 0.f};
    #pragma unroll
    for (int kk = 0; kk < 4; ++kk) {
      ac0 = __builtin_amdgcn_mfma_f32_16x16x32_bf16(af0[kk], bf[kk], ac0, 0, 0, 0);
      ac1 = __builtin_amdgcn_mfma_f32_16x16x32_bf16(af1[kk], bf[kk], ac1, 0, 0, 0);
    }
    const float ab = Ab1[col], a2c = A2[col];
    #pragma unroll
    for (int r = 0; r < 4; ++r) {
      float z0 = fast_tanh(ac0[r] + ab);
      float z1 = fast_tanh(ac1[r] + ab);
      pr0[r] = fmaf(a2c, z0, pr0[r]);
      pr1[r] = fmaf(a2c, z1, pr1[r]);
    }
  }
  const float ab2 = Ab2[0];
  const long base0 = ((long)b << 14) + (long)m0 * 512 + obase + w * 16 + kg * 4;
  #pragma unroll
  for (int r = 0; r < 4; ++r) {
    float v0 = pr0[r], v1 = pr1[r];
    #pragma unroll
    for (int off = 1; off < 16; off <<= 1) {
      v0 += __shfl_xor(v0, off);
      v1 += __shfl_xor(v1, off);
    }
    if (rowl == 0) {
      logits[base0 + r] = v0 + ab2;
      logits[base0 + 512 + r] = v1 + ab2;
    }
  }
}

// ---------------- masked softmax phase 1 (verified r14/r15) ----------------
__global__ __launch_bounds__(1024) void final_part1(
    const float* __restrict__ logits, const void* __restrict__ maskp,
    const int* __restrict__ flag, float* __restrict__ part) {
  __shared__ float sm[16];
  const int b = blockIdx.x, c = blockIdx.y;
  const int tid = threadIdx.x;
  const int lane = tid & 63, w = tid >> 6;
  const bool word_mode = (flag[0] == 0);
  const unsigned int* mw = (const unsigned int*)maskp;
  const unsigned char* mb = (const unsigned char*)maskp;
  const int i = c * 1024 + tid;
  const int o = i & 511, mm = i >> 9;
  const int mofs = (b * NO + o) * NM + mm;
  const bool msk = word_mode ? (mw[mofs] != 0u) : (mb[mofs] != 0);
  const float x = logits[b * (NM * NO) + i];
  float mx = msk ? x : -1e30f;
  #pragma unroll
  for (int off = 32; off; off >>= 1) mx = fmaxf(mx, __shfl_down(mx, off));
  if (lane == 0) sm[w] = mx;
  __syncthreads();
  if (tid == 0) {
    float m2 = sm[0];
    #pragma unroll
    for (int k = 1; k < 16; ++k) m2 = fmaxf(m2, sm[k]);
    sm[0] = m2;
  }
  __syncthreads();
  const float M = sm[0];
  float S = 0.f, T = 0.f;
  if (msk) {
    float d = x - M;
    float e = __expf(d);
    S = e; T = e * d;
  }
  #pragma unroll
  for (int off = 32; off; off >>= 1) { S += __shfl_down(S, off); T += __shfl_down(T, off); }
  __syncthreads();
  __shared__ float ss[16], st[16];
  if (lane == 0) { ss[w] = S; st[w] = T; }
  __syncthreads();
  if (tid == 0) {
    float St = 0.f, Tt = 0.f;
    #pragma unroll
    for (int k = 0; k < 16; ++k) { St += ss[k]; Tt += st[k]; }
    float* pp = part + (b * 16 + c) * 3;
    pp[0] = M; pp[1] = St; pp[2] = Tt;
  }
}

// ---------------- masked softmax phase 2 ----------------
__global__ __launch_bounds__(64) void final_part2(
    const float* __restrict__ part, const float* __restrict__ logits,
    const int* __restrict__ aidx, float* __restrict__ out) {
  const int b = blockIdx.x;
  const int lane = threadIdx.x;
  float lm = -3e30f, lS = 0.f, lT = 0.f;
  if (lane < 16) {
    const float* pp = part + (b * 16 + lane) * 3;
    lm = pp[0]; lS = pp[1]; lT = pp[2];
  }
  float M = lm;
  #pragma unroll
  for (int off = 8; off; off >>= 1) M = fmaxf(M, __shfl_xor(M, off, 16));
  float wgt = (lane < 16) ? __expf(lm - M) : 0.f;
  float S = wgt * lS;
  float T = wgt * (lT + (lm - M) * lS);
  #pragma unroll
  for (int off = 8; off; off >>= 1) {
    S += __shfl_xor(S, off, 16);
    T += __shfl_xor(T, off, 16);
  }
  if (lane == 0) {
    float lSm = logf(S);
    out[b] = logits[b * (NM * NO) + aidx[b]] - M - lSm;   // action_logprobs
    out[32 + b] = lSm - T / S;                            // dist_entropys
  }
}

// ---------------- critic MLP ----------------
__global__ __launch_bounds__(128) void critic_kernel(
    const float* __restrict__ po, const float* __restrict__ pm,
    const float* __restrict__ C0, const float* __restrict__ Cb0,
    const float* __restrict__ C1, const float* __restrict__ Cb1,
    const float* __restrict__ C2, const float* __restrict__ Cb2,
    float* __restrict__ out) {
  __shared__ float v[256];
  __shared__ float z[128];
  __shared__ float sc[2];
  const int b = blockIdx.x;
  const int j = threadIdx.x;
  v[j] = po[b * 128 + j];
  v[128 + j] = pm[b * 128 + j];
  __syncthreads();
  float acc = Cb0[j];
  for (int k = 0; k < 256; ++k) acc = fmaf(C0[j * 256 + k], v[k], acc);
  z[j] = fast_tanh(acc);
  __syncthreads();
  acc = Cb1[j];
  for (int k = 0; k < 128; ++k) acc = fmaf(C1[j * 128 + k], z[k], acc);
  float z2 = fast_tanh(acc);
  float p = C2[j] * z2;
  #pragma unroll
  for (int off = 32; off; off >>= 1) p += __shfl_down(p, off);
  const int lane = j & 63, w = j >> 6;
  if (lane == 0) sc[w] = p;
  __syncthreads();
  if (j == 0) out[16 + b] = sc[0] + sc[1] + Cb2[0];   // state_values
}

extern "C" void kernel_launch(void* const* d_in, const int* in_sizes, int n_in,
                              void* d_out, int out_size, void* d_ws, size_t ws_size,
                              hipStream_t stream) {
  (void)in_sizes; (void)n_in; (void)out_size; (void)ws_size;
  const float* adj  = (const float*)d_in[0];
  const float* nop  = (const float*)d_in[1];
  const float* nmac = (const float*)d_in[2];
  const void*  maskp = d_in[3];
  const int*   aidx = (const int*)d_in[4];
  const float* Wtr  = (const float*)d_in[5];
  const float* btr  = (const float*)d_in[6];
  const float* W0   = (const float*)d_in[7];
  const float* b0   = (const float*)d_in[8];
  const float* W1   = (const float*)d_in[9];
  const float* b1   = (const float*)d_in[10];
  const float* Wp   = (const float*)d_in[11];
  const float* bp   = (const float*)d_in[12];
  const float* Wo   = (const float*)d_in[13];
  const float* Wm   = (const float*)d_in[14];
  const float* alo  = (const float*)d_in[15];
  const float* alm  = (const float*)d_in[16];
  const float* A0   = (const float*)d_in[17];
  const float* Ab0  = (const float*)d_in[18];
  const float* A1   = (const float*)d_in[19];
  const float* Ab1  = (const float*)d_in[20];
  const float* A2   = (const float*)d_in[21];
  const float* Ab2  = (const float*)d_in[22];
  const float* C0   = (const float*)d_in[23];
  const float* Cb0  = (const float*)d_in[24];
  const float* C1   = (const float*)d_in[25];
  const float* Cb1  = (const float*)d_in[26];
  const float* C2   = (const float*)d_in[27];
  const float* Cb2  = (const float*)d_in[28];

  float* ws     = (float*)d_ws;        // needs ~44 MiB
  short* x12h   = (short*)(ws + OFF_X12);
  float* hopes  = ws + OFF_HOPES;
  float* hopeG  = ws + OFF_HOPEG;
  float* hmac   = ws + OFF_HMAC;
  float* hmacs  = ws + OFF_HMACS;
  float* ao     = ws + OFF_AO;
  float* am     = ws + OFF_AM;
  float* po     = ws + OFF_PO;
  float* pm     = ws + OFF_PM;
  float* Uo     = ws + OFF_UO;
  float* Um     = ws + OFF_UM;
  float* logits = ws + OFF_LOG;
  float* xcat   = ws + OFF_XCAT;
  short* A1p    = (short*)(ws + OFF_A1P);
  int*   flag   = (int*)(ws + OFF_FLAG);
  float* partb  = ws + OFF_PART;
  float* outp   = (float*)d_out;

  probe_mask_kernel<<<1, 256, 0, stream>>>((const unsigned int*)maskp, flag);

  // phase 1 (fused): trans GEMM + hopeG GEMM + hmac GEMM + A1 convert
  mega1_kernel<<<1360, 256, 0, stream>>>(nop, Wtr, btr, x12h, Wo, hopeG,
                                         nmac, Wm, hmac, A1, A1p);
  // phase 2 (fused): attention middle + rowdots
  mega2_kernel<<<3200, 256, 0, stream>>>(x12h, W0, b0, W1, b1,
                                         hopeG, alo, ao, hmac, alm, am);
  // phase 3: proj + gat
  gemm_hx<<<dim3(2, 128), 256, 0, stream>>>(x12h, Wp, bp, hopes);
  gat_kernel<<<dim3(NM, BB), 512, 0, stream>>>(adj, ao, am, hopeG, hmac, hmacs);

  // phase 4: pooling, Xcat, Uo/Um GEMMs
  pool2_kernel<<<32, 512, 0, stream>>>(hopes, hmacs, po, pm);
  xcat_kernel<<<192, 256, 0, stream>>>(hmacs, po, pm, xcat);
  gemm_wave<1><<<dim3(2, 128), 256, 0, stream>>>(hopes, A0, nullptr, Uo, 128, 128, 128, 512);
  gemm_wave<1><<<dim3(2, 8), 256, 0, stream>>>(xcat, A0 + 128, Ab0, Um, 128, 384, 384, 512);

  // phase 5: actor + final softmax + critic
  actor_mfma6_kernel<<<2048, 256, 0, stream>>>(Uo, Um, A1p, Ab1, A2, Ab2, logits);
  final_part1<<<dim3(16, 16), 1024, 0, stream>>>(logits, maskp, flag, partb);
  final_part2<<<16, 64, 0, stream>>>(partb, logits, aidx, outp);
  critic_kernel<<<16, 128, 0, stream>>>(po, pm, C0, Cb0, C1, Cb1, C2, Cb2, outp);
}